// Round 15
// baseline (3456.709 us; speedup 1.0000x reference)
//
#include <hip/hip_runtime.h>
#include <math.h>

// B=64, LAT=512, HC=HD=1024, NB=16, S=16, E=128, NOTES=128, OUT=384, L=2
// Split-bf16 MFMA GEMMs (x ~= hi+lo; A@W ~= Ah@Wh + Al@Wh + Ah@Wl).
// Round 15: phase-split inner loop (hi-reads -> hh MFMAs -> lo-reads ->
// lh/hl MFMAs) + s_setprio around MFMA clusters. Per-acc order unchanged
// (hh, lh, hl) -> bit-identical.

typedef __attribute__((ext_vector_type(8))) short s16x8;
typedef __attribute__((ext_vector_type(4))) float f32x4;

__device__ inline unsigned short f2bu(float f) {   // RNE f32->bf16
    unsigned u = __float_as_uint(f);
    unsigned r = u + 0x7fff + ((u >> 16) & 1);
    return (unsigned short)(r >> 16);
}
__device__ inline float bu2f(unsigned short h) { return __uint_as_float(((unsigned)h) << 16); }

// async global->LDS, 16B per lane; LDS dest = wave-uniform base + lane*16
__device__ __forceinline__ void gload16(const unsigned short* g, char* l) {
    const unsigned int* gu = (const unsigned int*)g;
    unsigned int* lu = (unsigned int*)l;
    __builtin_amdgcn_global_load_lds(
        (const __attribute__((address_space(1))) unsigned int*)gu,
        (__attribute__((address_space(3))) unsigned int*)lu, 16, 0, 0);
}

// ---------------------------------------------------------------------------
// 64x128 tile, BK=32, 256 thr = 4 waves. 3-buffer LDS pipeline; swizzle on
// global source (LDS dest linear per-wave via global_load_lds).
// mode: 0 = fp32 C; 1 = split store Chi/Clo; 2 = per-step decoder scatter;
//       3 = batched-proj scatter; 4 = fused LSTM cell (gate-interleaved cols:
//           C=c-state fp32 [M][1024], Chi/Clo = h split out, cpy = optional h copy).
__global__ __launch_bounds__(256) void gemm_mfma(
    int M, int N,
    const unsigned short* __restrict__ A1h, const unsigned short* __restrict__ A1l, int K1, int lda1,
    const unsigned short* __restrict__ W1h, const unsigned short* __restrict__ W1l, int ldw1,
    const unsigned short* __restrict__ A2h, const unsigned short* __restrict__ A2l, int K2, int lda2,
    const unsigned short* __restrict__ W2h, const unsigned short* __restrict__ W2l, int ldw2,
    const float* __restrict__ Add, int ldadd,
    const float* __restrict__ b1, const float* __restrict__ b2,
    float* __restrict__ C, int ldc,
    unsigned short* __restrict__ Chi, unsigned short* __restrict__ Clo,
    unsigned short* __restrict__ cpyh, unsigned short* __restrict__ cpyl,
    int mode, int scatter_s)
{
    __shared__ __align__(16) char ldsb[73728];   // 3 buffers x 24576 B

    const int tid = threadIdx.x;
    const int lane = tid & 63;
    const int wv = tid >> 6;

    // XCD-aware bijective swizzle (all grids used here have nwg % 8 == 0)
    const int gx = gridDim.x;
    const int l = blockIdx.y * gx + blockIdx.x;
    const int nwg = gx * gridDim.y;
    const int l2 = (l & 7) * (nwg >> 3) + (l >> 3);
    const int bm = (l2 % gx) * 64;
    const int bn = (l2 / gx) * 128;

    // per-lane async-staging constants (swizzle folded into global source addr)
    const int j = (lane & 7) ^ (lane >> 3);
    const bool isLo = j >= 4;
    const int koff = (j & 3) * 8;
    const int rsub = lane >> 3;
    const int aR0 = bm + wv * 8 + rsub;
    const int bR0 = bn + wv * 8 + rsub;

    f32x4 acc[4][2];
#pragma unroll
    for (int m = 0; m < 4; ++m)
#pragma unroll
        for (int n = 0; n < 2; ++n) acc[m][n] = (f32x4)0.0f;

    const int fr = lane & 15;
    const int kc = lane >> 4;

    const int NT = (K1 + K2) >> 5;   // always >= 4 for our shapes (min K = 128)

#define STAGE(dstp, t) {                                                        \
        const int k0_ = (t) << 5;                                               \
        const bool ph2_ = (k0_ >= K1);                                          \
        const unsigned short* Ab_ = ph2_ ? (isLo ? A2l : A2h)                   \
                                         : (isLo ? A1l : A1h);                  \
        const unsigned short* Wb_ = ph2_ ? (isLo ? W2l : W2h)                   \
                                         : (isLo ? W1l : W1h);                  \
        const int lda_ = ph2_ ? lda2 : lda1;                                    \
        const int ldw_ = ph2_ ? ldw2 : ldw1;                                    \
        const int kk_ = (ph2_ ? (k0_ - K1) : k0_) + koff;                       \
        char* dst_ = (dstp);                                                    \
        gload16(Ab_ + (size_t)aR0 * lda_ + kk_,        dst_ + (wv     ) * 1024);\
        gload16(Ab_ + (size_t)(aR0 + 32) * lda_ + kk_, dst_ + (wv +  4) * 1024);\
        gload16(Wb_ + (size_t)(bR0 +  0) * ldw_ + kk_, dst_ + (wv +  8) * 1024);\
        gload16(Wb_ + (size_t)(bR0 + 32) * ldw_ + kk_, dst_ + (wv + 12) * 1024);\
        gload16(Wb_ + (size_t)(bR0 + 64) * ldw_ + kk_, dst_ + (wv + 16) * 1024);\
        gload16(Wb_ + (size_t)(bR0 + 96) * ldw_ + kk_, dst_ + (wv + 20) * 1024);\
    }

    char* bcur  = ldsb;              // holds tile t
    char* bnext = ldsb + 24576;      // holds tile t+1 (in flight or landed)
    char* bfar  = ldsb + 49152;      // staging target for tile t+2

    STAGE(bcur, 0);
    STAGE(bnext, 1);
    asm volatile("s_waitcnt vmcnt(6)" ::: "memory");   // tile 0 landed (own-wave)
    __builtin_amdgcn_s_barrier();                      // all waves' tile 0 visible

    for (int t = 0; t < NT; ++t) {
        const bool more = (t + 2 < NT);
        if (more) STAGE(bfar, t + 2);
        {
            s16x8 ah[4], al[4], bh[2], bl[2];
            // ---- phase 1: hi fragments, hh MFMAs ----
#pragma unroll
            for (int m = 0; m < 4; ++m) {
                const int row = m * 16 + fr;
                const int sw = (row & 7) << 4;
                char* base = bcur + row * 128;
                ah[m] = *(const s16x8*)(base + ((kc * 16) ^ sw));
            }
#pragma unroll
            for (int n = 0; n < 2; ++n) {
                const int row = wv * 32 + n * 16 + fr;
                const int sw = (row & 7) << 4;
                char* base = bcur + 8192 + row * 128;
                bh[n] = *(const s16x8*)(base + ((kc * 16) ^ sw));
            }
            __builtin_amdgcn_s_setprio(1);
#pragma unroll
            for (int m = 0; m < 4; ++m)
#pragma unroll
                for (int n = 0; n < 2; ++n)
                    acc[m][n] = __builtin_amdgcn_mfma_f32_16x16x32_bf16(ah[m], bh[n], acc[m][n], 0, 0, 0);
            __builtin_amdgcn_s_setprio(0);
            // ---- phase 2: lo fragments, lh then hl MFMAs ----
#pragma unroll
            for (int m = 0; m < 4; ++m) {
                const int row = m * 16 + fr;
                const int sw = (row & 7) << 4;
                char* base = bcur + row * 128;
                al[m] = *(const s16x8*)(base + (((kc + 4) * 16) ^ sw));
            }
#pragma unroll
            for (int n = 0; n < 2; ++n) {
                const int row = wv * 32 + n * 16 + fr;
                const int sw = (row & 7) << 4;
                char* base = bcur + 8192 + row * 128;
                bl[n] = *(const s16x8*)(base + (((kc + 4) * 16) ^ sw));
            }
            __builtin_amdgcn_s_setprio(1);
#pragma unroll
            for (int m = 0; m < 4; ++m)
#pragma unroll
                for (int n = 0; n < 2; ++n) {
                    acc[m][n] = __builtin_amdgcn_mfma_f32_16x16x32_bf16(al[m], bh[n], acc[m][n], 0, 0, 0);
                    acc[m][n] = __builtin_amdgcn_mfma_f32_16x16x32_bf16(ah[m], bl[n], acc[m][n], 0, 0, 0);
                }
            __builtin_amdgcn_s_setprio(0);
        }
        // wait for own-wave tile-(t+1) loads (6 newest may stay in flight),
        // then barrier: after it, every wave's t+1 writes are in LDS.
        if (more) { asm volatile("s_waitcnt vmcnt(6)" ::: "memory"); }
        else      { asm volatile("s_waitcnt vmcnt(0)" ::: "memory"); }
        __builtin_amdgcn_s_barrier();
        char* tmp = bcur; bcur = bnext; bnext = bfar; bfar = tmp;
    }
#undef STAGE

    if (mode == 4) {
        // fused LSTM cell: gate-interleaved cols (col = 4k+g). Stage fp32 gates
        // to LDS [64][132], then each thread handles 8 (row,k) cells.
        float* ldsf = (float*)ldsb;
#pragma unroll
        for (int m = 0; m < 4; ++m)
#pragma unroll
            for (int n = 0; n < 2; ++n) {
                f32x4 v4 = acc[m][n];
#pragma unroll
                for (int q = 0; q < 4; ++q) {
                    const int rl = m * 16 + kc * 4 + q;
                    const int cl = wv * 32 + n * 16 + fr;
                    const int col = bn + cl;
                    float v = v4[q];
                    if (b1) v += b1[col];
                    if (Add) v += Add[(size_t)(bm + rl) * ldadd + col];
                    ldsf[rl * 132 + cl] = v;
                }
            }
        __syncthreads();
        const int kb = bn >> 2;
#pragma unroll
        for (int e = 0; e < 8; ++e) {
            const int idx2 = tid * 8 + e;          // 0..2047
            const int row = idx2 >> 5, kk = idx2 & 31;
            const float4 g4 = *(const float4*)(ldsf + row * 132 + kk * 4);
            const size_t ci = (((size_t)(bm + row)) << 10) + kb + kk;
            const float si = 1.f / (1.f + expf(-g4.x));
            const float sf = 1.f / (1.f + expf(-g4.y));
            const float so = 1.f / (1.f + expf(-g4.w));
            const float cn = sf * C[ci] + si * tanhf(g4.z);
            const float hn = so * tanhf(cn);
            C[ci] = cn;
            const unsigned short hh = f2bu(hn);
            const unsigned short hl = f2bu(hn - bu2f(hh));
            Chi[ci] = hh; Clo[ci] = hl;
            if (cpyh) { cpyh[ci] = hh; cpyl[ci] = hl; }
        }
        return;
    }

#pragma unroll
    for (int m = 0; m < 4; ++m)
#pragma unroll
        for (int n = 0; n < 2; ++n) {
            f32x4 v4 = acc[m][n];
#pragma unroll
            for (int q = 0; q < 4; ++q) {
                const int rl = m * 16 + kc * 4 + q;
                const int cl = wv * 32 + n * 16 + fr;
                const int r = bm + rl, col = bn + cl;
                float v = v4[q];
                if (b1) v += b1[col];
                if (b2) v += b2[col];
                if (Add) v += Add[(size_t)r * ldadd + col];
                if (mode == 0) {
                    C[(size_t)r * ldc + col] = v;
                } else if (mode == 1) {
                    unsigned short h = f2bu(v);
                    Chi[(size_t)r * ldc + col] = h;
                    Clo[(size_t)r * ldc + col] = f2bu(v - bu2f(h));
                } else if (mode == 2) {
                    const int bb = r & 63, nb = r >> 6;
                    C[(size_t)(((bb * 16 + nb) * 16 + scatter_s)) * 384 + col] = v;
                } else {
                    const int bb = r & 63, nb = (r >> 6) & 15, s = r >> 10;
                    C[(size_t)(((bb * 16 + nb) * 16 + s)) * 384 + col] = v;
                }
            }
        }
}

// ---------------------------------------------------------------------------
__global__ __launch_bounds__(256) void split_pack(
    const float* __restrict__ src, int ldsrc, int c0, long total, int C,
    unsigned short* __restrict__ hi, unsigned short* __restrict__ lo)
{
    long i = ((long)blockIdx.x * 256 + threadIdx.x) * 4;
    if (i >= total) return;
    int r = (int)(i / C), c = (int)(i % C);
    float4 v = *(const float4*)(src + (size_t)r * ldsrc + c0 + c);
#pragma unroll
    for (int j = 0; j < 4; ++j) {
        float x = (&v.x)[j];
        unsigned short h = f2bu(x);
        hi[i + j] = h;
        lo[i + j] = f2bu(x - bu2f(h));
    }
}

// gate-permuted split: dst row j (0..4095) <- src row (j&3)*1024 + (j>>2)
__global__ __launch_bounds__(256) void split_pack_perm(
    const float* __restrict__ src, int ldsrc, int c0, long total, int C,
    unsigned short* __restrict__ hi, unsigned short* __restrict__ lo)
{
    long i = ((long)blockIdx.x * 256 + threadIdx.x) * 4;
    if (i >= total) return;
    int r = (int)(i / C), c = (int)(i % C);
    int sr = (r & 3) * 1024 + (r >> 2);
    float4 v = *(const float4*)(src + (size_t)sr * ldsrc + c0 + c);
#pragma unroll
    for (int j = 0; j < 4; ++j) {
        float x = (&v.x)[j];
        unsigned short h = f2bu(x);
        hi[i + j] = h;
        lo[i + j] = f2bu(x - bu2f(h));
    }
}

// dst[j] = a[old(j)] + b[old(j)], old(j) = (j&3)*1024 + (j>>2)
__global__ __launch_bounds__(256) void bias_perm(
    const float* __restrict__ a, const float* __restrict__ b, float* __restrict__ dst)
{
    const int j = blockIdx.x * 256 + threadIdx.x;
    if (j >= 4096) return;
    const int o = (j & 3) * 1024 + (j >> 2);
    dst[j] = a[o] + b[o];
}

__global__ __launch_bounds__(256) void scatter_ini_split(
    const float* __restrict__ I, unsigned short* __restrict__ hchi,
    unsigned short* __restrict__ hclo, float* __restrict__ cc)
{
    const int idx = blockIdx.x * blockDim.x + threadIdx.x;
    if (idx >= 131072) return;
    const int k = idx & 1023, b = (idx >> 10) & 63, l = idx >> 16;
    const float* row = I + (size_t)b * 4096;
    float hv = row[(l << 10) + k];
    unsigned short h = f2bu(hv);
    hchi[idx] = h; hclo[idx] = f2bu(hv - bu2f(h));
    cc[idx] = row[2048 + (l << 10) + k];
}

__global__ __launch_bounds__(256) void scatter_di_split(
    const float* __restrict__ D,
    unsigned short* __restrict__ h0h, unsigned short* __restrict__ h0l,
    unsigned short* __restrict__ h1h, unsigned short* __restrict__ h1l,
    float* __restrict__ cd0, float* __restrict__ cd1)
{
    const int idx = blockIdx.x * blockDim.x + threadIdx.x;
    if (idx >= 1048576) return;
    const int k = idx & 1023, r = idx >> 10;
    const float* row = D + ((size_t)r << 12);
    float v0 = row[k], v1 = row[1024 + k];
    unsigned short a = f2bu(v0); h0h[idx] = a; h0l[idx] = f2bu(v0 - bu2f(a));
    unsigned short b = f2bu(v1); h1h[idx] = b; h1l[idx] = f2bu(v1 - bu2f(b));
    cd0[idx] = row[2048 + k];
    cd1[idx] = row[3072 + k];
}

__global__ __launch_bounds__(256) void build_prev_b(
    const int* __restrict__ tp, unsigned short* __restrict__ ph, unsigned short* __restrict__ pl)
{
    const int idx = blockIdx.x * blockDim.x + threadIdx.x;
    if (idx >= 2097152) return;
    const int n = idx & 127;
    const int r = (idx >> 7) & 1023;
    const int s = idx >> 17;
    const int nb = r >> 6, bb = r & 63;
    const int t = nb * 16 + s;
    float v = 0.f;
    if (t > 0) v = (float)tp[(size_t)bb * 32768 + (size_t)(t - 1) * 128 + n];
    ph[idx] = f2bu(v);
    pl[idx] = 0;
}

// ===========================================================================
// Fallback fp32 path (proven baseline)
#define BM 64
#define BN 64
#define BK 16

__global__ __launch_bounds__(256) void gemm_f32(
    int M, int N,
    const float* __restrict__ A1, int K1, int lda1,
    const float* __restrict__ W1, int ldw1,
    const float* __restrict__ A2, int K2, int lda2,
    const float* __restrict__ W2, int ldw2,
    const float* __restrict__ Add, int ldadd,
    const float* __restrict__ bias1, const float* __restrict__ bias2,
    float* __restrict__ C, int ldc, int scatter_s)
{
    __shared__ float As[BK][BM];
    __shared__ float Ws[BK][BN];
    const int bm = blockIdx.x * BM;
    const int bn = blockIdx.y * BN;
    const int tid = threadIdx.x;
    const int ty = tid >> 4;
    const int tx = tid & 15;
    const int lr = tid >> 2;
    const int lc = (tid & 3) << 2;

    float acc[4][4] = {{0.f,0.f,0.f,0.f},{0.f,0.f,0.f,0.f},{0.f,0.f,0.f,0.f},{0.f,0.f,0.f,0.f}};

    for (int phase = 0; phase < 2; ++phase) {
        const float* Ap = phase ? A2 : A1;
        const float* Wp = phase ? W2 : W1;
        const int K   = phase ? K2 : K1;
        const int lda = phase ? lda2 : lda1;
        const int ldw = phase ? ldw2 : ldw1;
        if (Ap == nullptr || K <= 0) continue;
        for (int k0 = 0; k0 < K; k0 += BK) {
            float4 av = *(const float4*)(Ap + (size_t)(bm + lr) * lda + k0 + lc);
            float4 wv = *(const float4*)(Wp + (size_t)(bn + lr) * ldw + k0 + lc);
            __syncthreads();
            As[lc+0][lr] = av.x; As[lc+1][lr] = av.y; As[lc+2][lr] = av.z; As[lc+3][lr] = av.w;
            Ws[lc+0][lr] = wv.x; Ws[lc+1][lr] = wv.y; Ws[lc+2][lr] = wv.z; Ws[lc+3][lr] = wv.w;
            __syncthreads();
            #pragma unroll
            for (int k = 0; k < BK; ++k) {
                float4 a = *(const float4*)&As[k][ty << 2];
                float4 w = *(const float4*)&Ws[k][tx << 2];
                acc[0][0] = fmaf(a.x, w.x, acc[0][0]);
                acc[0][1] = fmaf(a.x, w.y, acc[0][1]);
                acc[0][2] = fmaf(a.x, w.z, acc[0][2]);
                acc[0][3] = fmaf(a.x, w.w, acc[0][3]);
                acc[1][0] = fmaf(a.y, w.x, acc[1][0]);
                acc[1][1] = fmaf(a.y, w.y, acc[1][1]);
                acc[1][2] = fmaf(a.y, w.z, acc[1][2]);
                acc[1][3] = fmaf(a.y, w.w, acc[1][3]);
                acc[2][0] = fmaf(a.z, w.x, acc[2][0]);
                acc[2][1] = fmaf(a.z, w.y, acc[2][1]);
                acc[2][2] = fmaf(a.z, w.z, acc[2][2]);
                acc[2][3] = fmaf(a.z, w.w, acc[2][3]);
                acc[3][0] = fmaf(a.w, w.x, acc[3][0]);
                acc[3][1] = fmaf(a.w, w.y, acc[3][1]);
                acc[3][2] = fmaf(a.w, w.z, acc[3][2]);
                acc[3][3] = fmaf(a.w, w.w, acc[3][3]);
            }
        }
    }

    #pragma unroll
    for (int i = 0; i < 4; ++i) {
        const int row = bm + (ty << 2) + i;
        #pragma unroll
        for (int j = 0; j < 4; ++j) {
            const int col = bn + (tx << 2) + j;
            float v = acc[i][j];
            if (bias1) v += bias1[col];
            if (bias2) v += bias2[col];
            if (Add)   v += Add[(size_t)row * ldadd + col];
            if (scatter_s >= 0) {
                const int bb = row & 63, nb = row >> 6;
                C[(size_t)(((bb * 16 + nb) * 16 + scatter_s)) * 384 + col] = v;
            } else {
                C[(size_t)row * ldc + col] = v;
            }
        }
    }
}

__global__ __launch_bounds__(256) void lstm_cell(
    const float* __restrict__ g, float* __restrict__ c,
    float* __restrict__ h, float* __restrict__ hcopy, int M)
{
    const int idx = blockIdx.x * blockDim.x + threadIdx.x;
    if (idx >= (M << 10)) return;
    const int r = idx >> 10, k = idx & 1023;
    const float* gr = g + ((size_t)r << 12);
    const float gi = gr[k], gf = gr[k + 1024], gg = gr[k + 2048], go = gr[k + 3072];
    const float si = 1.f / (1.f + expf(-gi));
    const float sf = 1.f / (1.f + expf(-gf));
    const float so = 1.f / (1.f + expf(-go));
    const float cn = sf * c[idx] + si * tanhf(gg);
    const float hn = so * tanhf(cn);
    c[idx] = cn;
    h[idx] = hn;
    if (hcopy) hcopy[idx] = hn;
}

__global__ __launch_bounds__(256) void scatter_ini(
    const float* __restrict__ I, float* __restrict__ hc, float* __restrict__ cc)
{
    const int idx = blockIdx.x * blockDim.x + threadIdx.x;
    if (idx >= 131072) return;
    const int k = idx & 1023, b = (idx >> 10) & 63, l = idx >> 16;
    const float* row = I + (size_t)b * 4096;
    hc[idx] = row[(l << 10) + k];
    cc[idx] = row[2048 + (l << 10) + k];
}

__global__ __launch_bounds__(256) void scatter_di(
    const float* __restrict__ D, float* __restrict__ hd0, float* __restrict__ cd0,
    float* __restrict__ hd1, float* __restrict__ cd1)
{
    const int idx = blockIdx.x * blockDim.x + threadIdx.x;
    if (idx >= 1048576) return;
    const int k = idx & 1023, r = idx >> 10;
    const float* row = D + ((size_t)r << 12);
    hd0[idx] = row[k];
    hd1[idx] = row[1024 + k];
    cd0[idx] = row[2048 + k];
    cd1[idx] = row[3072 + k];
}

__global__ __launch_bounds__(256) void build_prev(
    const int* __restrict__ tp, float* __restrict__ prevf)
{
    const int idx = blockIdx.x * blockDim.x + threadIdx.x;
    if (idx >= 2097152) return;
    const int n = idx & 127;
    const int r = (idx >> 7) & 1023;
    const int s = idx >> 17;
    const int nb = r >> 6, bb = r & 63;
    const int t = nb * 16 + s;
    float v = 0.f;
    if (t > 0) v = (float)tp[(size_t)bb * 32768 + (size_t)(t - 1) * 128 + n];
    prevf[idx] = v;
}

// ===========================================================================
extern "C" void kernel_launch(void* const* d_in, const int* in_sizes, int n_in,
                              void* d_out, int out_size, void* d_ws, size_t ws_size,
                              hipStream_t stream)
{
    (void)in_sizes; (void)n_in; (void)out_size;
    const float* z      = (const float*)d_in[0];
    const int*   tp     = (const int*)  d_in[1];
    const float* w_zc   = (const float*)d_in[2];
    const float* b_zc   = (const float*)d_in[3];
    const float* c_whh0 = (const float*)d_in[5];
    const float* c_bih0 = (const float*)d_in[6];
    const float* c_bhh0 = (const float*)d_in[7];
    const float* c_wih1 = (const float*)d_in[8];
    const float* c_whh1 = (const float*)d_in[9];
    const float* c_bih1 = (const float*)d_in[10];
    const float* c_bhh1 = (const float*)d_in[11];
    const float* np_w   = (const float*)d_in[12];
    const float* np_b   = (const float*)d_in[13];
    const float* cd_w   = (const float*)d_in[14];
    const float* cd_b   = (const float*)d_in[15];
    const float* d_wih0 = (const float*)d_in[16];
    const float* d_whh0 = (const float*)d_in[17];
    const float* d_bih0 = (const float*)d_in[18];
    const float* d_bhh0 = (const float*)d_in[19];
    const float* d_wih1 = (const float*)d_in[20];
    const float* d_whh1 = (const float*)d_in[21];
    const float* d_bih1 = (const float*)d_in[22];
    const float* d_bhh1 = (const float*)d_in[23];
    const float* op_w   = (const float*)d_in[24];
    const float* op_b   = (const float*)d_in[25];
    float* out = (float*)d_out;

    // ---- workspace layout for MFMA path (bytes) ----
    size_t o = 0;
    auto alloc = [&](size_t bytes) { size_t r = o; o = (o + bytes + 255) & ~(size_t)255; return r; };
    const size_t oCW0 = alloc((size_t)4096*1024*4);
    const size_t oCW1 = alloc((size_t)4096*1024*4);
    const size_t oCW2 = alloc((size_t)4096*1024*4);
    const size_t oWZC = alloc((size_t)4096*512*4);     // later reused: D0E + OPW
    const size_t oNPW = alloc((size_t)128*128*4);
    const size_t oZS  = alloc((size_t)64*512*4);
    const size_t oCDW = alloc((size_t)4096*1024*4);
    const size_t oD0R = alloc((size_t)4096*1024*4);
    const size_t oCG  = alloc((size_t)64*4096*4);
    const size_t oCC  = alloc((size_t)2*64*1024*4);
    const size_t oHCa = alloc((size_t)2*64*1024*4);    // h ping (hi[2][64][1024], lo)
    const size_t oHCb = alloc((size_t)2*64*1024*4);    // h pong
    const size_t oCND = alloc((size_t)1024*1024*4);
    const size_t oEMB = alloc((size_t)16*1024*128*4);
    const size_t oBRP = alloc((size_t)1024*4096*4);
    const size_t oDG  = alloc((size_t)1024*4096*4);    // PRV aliases this (PRV dead before DG live)
    const size_t oHD0a= alloc((size_t)1024*1024*4);
    const size_t oHD0b= alloc((size_t)1024*1024*4);
    const size_t oHD1a= alloc((size_t)1024*1024*4);
    const size_t oHD1b= alloc((size_t)1024*1024*4);
    const size_t oCD0 = alloc((size_t)1024*1024*4);
    const size_t oCD1 = alloc((size_t)1024*1024*4);
    const size_t oBS  = alloc((size_t)4*4096*4);
    const size_t need = o;
    const size_t oH1S = alloc((size_t)16*1024*1024*4);
    const size_t need_batched = o;

    if (ws_size >= need) {
        const bool batched = (ws_size >= need_batched);
        char* ws = (char*)d_ws;
        unsigned short* CW0 = (unsigned short*)(ws + oCW0);
        unsigned short* CW1 = (unsigned short*)(ws + oCW1);
        unsigned short* CW2 = (unsigned short*)(ws + oCW2);
        unsigned short* WZC = (unsigned short*)(ws + oWZC);
        unsigned short* NPW = (unsigned short*)(ws + oNPW);
        unsigned short* ZS  = (unsigned short*)(ws + oZS);
        unsigned short* CDW = (unsigned short*)(ws + oCDW);
        unsigned short* D0R = (unsigned short*)(ws + oD0R);
        float* CG  = (float*)(ws + oCG);
        float* CC  = (float*)(ws + oCC);
        unsigned short* HCa = (unsigned short*)(ws + oHCa);
        unsigned short* HCb = (unsigned short*)(ws + oHCb);
        unsigned short* CND = (unsigned short*)(ws + oCND);
        unsigned short* PRV = (unsigned short*)(ws + oDG);   // alias: dead before DG live
        unsigned short* EMB = (unsigned short*)(ws + oEMB);
        float* BRP = (float*)(ws + oBRP);
        float* DG  = (float*)(ws + oDG);
        unsigned short* HD0a = (unsigned short*)(ws + oHD0a);
        unsigned short* HD0b = (unsigned short*)(ws + oHD0b);
        unsigned short* HD1a = (unsigned short*)(ws + oHD1a);
        unsigned short* HD1b = (unsigned short*)(ws + oHD1b);
        float* CD0 = (float*)(ws + oCD0);
        float* CD1 = (float*)(ws + oCD1);
        float* BSC0 = (float*)(ws + oBS);
        float* BSC1 = BSC0 + 4096;
        float* BSB0 = BSC1 + 4096;
        float* BSD1 = BSB0 + 4096;
        unsigned short* H1S  = (unsigned short*)(ws + oH1S);
        unsigned short* H1Sl = H1S + (size_t)16*1048576;
        unsigned short* DWHH0 = CW0;      // aliases, filled after conductor
        unsigned short* DWIH1 = CW1;
        unsigned short* DWHH1 = CW2;
        unsigned short* D0E   = WZC;
        unsigned short* OPW   = WZC + (size_t)2*4096*128;

        auto split = [&](const float* src, int ldsrc, int c0, long R, long C, unsigned short* dst) {
            long total = R * C;
            split_pack<<<(unsigned)((total/4 + 255) / 256), 256, 0, stream>>>(
                src, ldsrc, c0, total, (int)C, dst, dst + total);
        };
        auto splitP = [&](const float* src, int ldsrc, int c0, long C, unsigned short* dst) {
            long total = 4096 * C;
            split_pack_perm<<<(unsigned)((total/4 + 255) / 256), 256, 0, stream>>>(
                src, ldsrc, c0, total, (int)C, dst, dst + total);
        };
        auto gemm2 = [&](int M, int N,
                         const unsigned short* A1h, const unsigned short* A1l, int K1, int lda1,
                         const unsigned short* W1, int ldw1,
                         const unsigned short* A2h, const unsigned short* A2l, int K2, int lda2,
                         const unsigned short* W2, int ldw2,
                         const float* Addp, int ldadd, const float* bb1, const float* bb2,
                         float* Cp, int ldc, unsigned short* Chi, unsigned short* Clo,
                         unsigned short* cpyh, unsigned short* cpyl,
                         int mode, int ss) {
            const unsigned short* W1l = W1 ? W1 + (size_t)N*ldw1 : nullptr;
            const unsigned short* W2l = W2 ? W2 + (size_t)N*ldw2 : nullptr;
            dim3 grid(M / 64, N / 128);
            gemm_mfma<<<grid, 256, 0, stream>>>(M, N, A1h, A1l, K1, lda1, W1, W1l, ldw1,
                                                A2h, A2l, K2, lda2, W2, W2l, ldw2,
                                                Addp, ldadd, bb1, bb2, Cp, ldc, Chi, Clo,
                                                cpyh, cpyl, mode, ss);
        };

        // h-state pointer helpers (hi at base, lo at +count)
        auto hc0h = [&](int b){ return (b ? HCb : HCa); };
        auto hc0l = [&](int b){ return (b ? HCb : HCa) + 131072; };
        auto hc1h = [&](int b){ return (b ? HCb : HCa) + 65536; };
        auto hc1l = [&](int b){ return (b ? HCb : HCa) + 131072 + 65536; };
        auto hd0h = [&](int b){ return (b ? HD0b : HD0a); };
        auto hd0l = [&](int b){ return (b ? HD0b : HD0a) + 1048576; };
        auto hd1h = [&](int b){ return (b ? HD1b : HD1a); };
        auto hd1l = [&](int b){ return (b ? HD1b : HD1a) + 1048576; };

        // 0) conversions (conductor weights gate-permuted) + permuted bias sums
        split(z, 512, 0, 64, 512, ZS);
        split(w_zc, 512, 0, 4096, 512, WZC);
        splitP(c_whh0, 1024, 0, 1024, CW0);
        splitP(c_wih1, 1024, 0, 1024, CW1);
        splitP(c_whh1, 1024, 0, 1024, CW2);
        split(np_w, 128, 0, 128, 128, NPW);
        split(cd_w, 1024, 0, 4096, 1024, CDW);
        splitP(d_wih0, 1152, 128, 1024, D0R);
        bias_perm<<<16, 256, 0, stream>>>(c_bih0, c_bhh0, BSC0);
        bias_perm<<<16, 256, 0, stream>>>(c_bih1, c_bhh1, BSC1);
        bias_perm<<<16, 256, 0, stream>>>(d_bih0, d_bhh0, BSB0);
        bias_perm<<<16, 256, 0, stream>>>(d_bih1, d_bhh1, BSD1);
        build_prev_b<<<8192, 256, 0, stream>>>(tp, PRV, PRV + 2097152);

        // 1) ini = z @ w_zc.T + b_zc -> CG -> split-scatter into HCa (ping 0)
        gemm2(64, 4096, ZS, ZS + 32768, 512, 512, WZC, 512,
              nullptr, nullptr, 0, 0, nullptr, 0,
              nullptr, 0, b_zc, nullptr, CG, 4096, nullptr, nullptr, nullptr, nullptr, 0, -1);
        scatter_ini_split<<<512, 256, 0, stream>>>(CG, HCa, HCa + 131072, CC);

        // 2) emb = prev @ np_w.T + np_b (split out); PRV aliases DG (dead after this)
        gemm2(16384, 128, PRV, PRV + 2097152, 128, 128, NPW, 128,
              nullptr, nullptr, 0, 0, nullptr, 0,
              nullptr, 0, np_b, nullptr, nullptr, 128, EMB, EMB + 2097152, nullptr, nullptr, 1, -1);

        // 3) conductor: fused-cell GEMMs, h ping-pong
        for (int t = 0; t < 16; ++t) {
            const int p = t & 1;
            gemm2(64, 4096, hc0h(p), hc0l(p), 1024, 1024, CW0, 1024,
                  nullptr, nullptr, 0, 0, nullptr, 0,
                  nullptr, 0, BSC0, nullptr, CC, 0, hc0h(p ^ 1), hc0l(p ^ 1),
                  nullptr, nullptr, 4, -1);
            gemm2(64, 4096, hc0h(p ^ 1), hc0l(p ^ 1), 1024, 1024, CW1, 1024,
                  hc1h(p), hc1l(p), 1024, 1024, CW2, 1024,
                  nullptr, 0, BSC1, nullptr, CC + 65536, 0, hc1h(p ^ 1), hc1l(p ^ 1),
                  CND + t * 65536, CND + 1048576 + t * 65536, 4, -1);
        }

        // 4) decoder weights (aliases, stream-ordered after conductor)
        splitP(d_whh0, 1024, 0, 1024, DWHH0);
        splitP(d_wih1, 1024, 0, 1024, DWIH1);
        splitP(d_whh1, 1024, 0, 1024, DWHH1);
        splitP(d_wih0, 1152, 0, 128, D0E);
        split(op_w, 1024, 0, 384, 1024, OPW);

        // 5) di = cond @ cd_w.T + cd_b -> DG -> split scatter into ping 0
        gemm2(1024, 4096, CND, CND + 1048576, 1024, 1024, CDW, 1024,
              nullptr, nullptr, 0, 0, nullptr, 0,
              nullptr, 0, cd_b, nullptr, DG, 4096, nullptr, nullptr, nullptr, nullptr, 0, -1);
        scatter_di_split<<<4096, 256, 0, stream>>>(DG, HD0a, HD0a + 1048576,
                                                   HD1a, HD1a + 1048576, CD0, CD1);

        // 6) barpart = cond @ d_wih0[:,128:].T + (bih0+bhh0), permuted cols
        gemm2(1024, 4096, CND, CND + 1048576, 1024, 1024, D0R, 1024,
              nullptr, nullptr, 0, 0, nullptr, 0,
              nullptr, 0, BSB0, nullptr, BRP, 4096, nullptr, nullptr, nullptr, nullptr, 0, -1);

        // 7) decoder: fused-cell GEMMs, h ping-pong
        for (int s = 0; s < 16; ++s) {
            const int p = s & 1;
            gemm2(1024, 4096, EMB + (size_t)s * 131072, EMB + 2097152 + (size_t)s * 131072, 128, 128,
                  D0E, 128,
                  hd0h(p), hd0l(p), 1024, 1024, DWHH0, 1024,
                  BRP, 4096, nullptr, nullptr, CD0, 0, hd0h(p ^ 1), hd0l(p ^ 1),
                  nullptr, nullptr, 4, -1);
            gemm2(1024, 4096, hd0h(p ^ 1), hd0l(p ^ 1), 1024, 1024, DWIH1, 1024,
                  hd1h(p), hd1l(p), 1024, 1024, DWHH1, 1024,
                  nullptr, 0, BSD1, nullptr, CD1, 0, hd1h(p ^ 1), hd1l(p ^ 1),
                  batched ? H1S + (size_t)s * 1048576 : nullptr,
                  batched ? H1Sl + (size_t)s * 1048576 : nullptr, 4, -1);
            if (!batched) {
                gemm2(1024, 384, hd1h(p ^ 1), hd1l(p ^ 1), 1024, 1024, OPW, 1024,
                      nullptr, nullptr, 0, 0, nullptr, 0,
                      nullptr, 0, op_b, nullptr, out, 384, nullptr, nullptr, nullptr, nullptr, 2, s);
            }
        }
        if (batched) {
            gemm2(16384, 384, H1S, H1Sl, 1024, 1024, OPW, 1024,
                  nullptr, nullptr, 0, 0, nullptr, 0,
                  nullptr, 0, op_b, nullptr, out, 384, nullptr, nullptr, nullptr, nullptr, 3, -1);
        }
        return;
    }

    // ================= fallback: proven fp32 path =================
    float* wsf     = (float*)d_ws;
    float* hc      = wsf;
    float* cc      = hc + 131072;
    float* cond    = cc + 131072;
    float* cg      = cond + 1048576;
    float* barpart = cg + 262144;
    float* emb     = barpart + 4194304;
    float* prevf   = emb + 2097152;
    float* hd0     = prevf + 2097152;
    float* cd0     = hd0 + 1048576;
    float* hd1     = cd0 + 1048576;
    float* cd1     = hd1 + 1048576;
    float* dg      = cd1 + 1048576;

    auto gemmf = [&](int M, int N,
                     const float* A1, int K1, int lda1, const float* W1, int ldw1,
                     const float* A2, int K2, int lda2, const float* W2, int ldw2,
                     const float* Addp, int ldadd, const float* bb1, const float* bb2,
                     float* Cp, int ldc, int ss) {
        dim3 grid(M / BM, N / BN);
        gemm_f32<<<grid, dim3(256), 0, stream>>>(M, N, A1, K1, lda1, W1, ldw1,
                                                 A2, K2, lda2, W2, ldw2,
                                                 Addp, ldadd, bb1, bb2, Cp, ldc, ss);
    };

    gemmf(64, 4096, z, 512, 512, w_zc, 512, nullptr, 0, 0, nullptr, 0,
          nullptr, 0, b_zc, nullptr, cg, 4096, -1);
    scatter_ini<<<512, 256, 0, stream>>>(cg, hc, cc);

    build_prev<<<8192, 256, 0, stream>>>(tp, prevf);
    gemmf(16384, 128, prevf, 128, 128, np_w, 128, nullptr, 0, 0, nullptr, 0,
          nullptr, 0, np_b, nullptr, emb, 128, -1);

    for (int t = 0; t < 16; ++t) {
        gemmf(64, 4096, hc, 1024, 1024, c_whh0, 1024, nullptr, 0, 0, nullptr, 0,
              nullptr, 0, c_bih0, c_bhh0, cg, 4096, -1);
        lstm_cell<<<256, 256, 0, stream>>>(cg, cc, hc, nullptr, 64);
        gemmf(64, 4096, hc, 1024, 1024, c_wih1, 1024,
              hc + 65536, 1024, 1024, c_whh1, 1024,
              nullptr, 0, c_bih1, c_bhh1, cg, 4096, -1);
        lstm_cell<<<256, 256, 0, stream>>>(cg, cc + 65536, hc + 65536, cond + t * 65536, 64);
    }

    gemmf(1024, 4096, cond, 1024, 1024, cd_w, 1024, nullptr, 0, 0, nullptr, 0,
          nullptr, 0, cd_b, nullptr, dg, 4096, -1);
    scatter_di<<<4096, 256, 0, stream>>>(dg, hd0, cd0, hd1, cd1);

    gemmf(1024, 4096, cond, 1024, 1024, d_wih0 + 128, 1152, nullptr, 0, 0, nullptr, 0,
          nullptr, 0, d_bih0, d_bhh0, barpart, 4096, -1);

    for (int s = 0; s < 16; ++s) {
        gemmf(1024, 4096, emb + (size_t)s * 131072, 128, 128, d_wih0, 1152,
              hd0, 1024, 1024, d_whh0, 1024,
              barpart, 4096, nullptr, nullptr, dg, 4096, -1);
        lstm_cell<<<4096, 256, 0, stream>>>(dg, cd0, hd0, nullptr, 1024);
        gemmf(1024, 4096, hd0, 1024, 1024, d_wih1, 1024,
              hd1, 1024, 1024, d_whh1, 1024,
              nullptr, 0, d_bih1, d_bhh1, dg, 4096, -1);
        lstm_cell<<<4096, 256, 0, stream>>>(dg, cd1, hd1, nullptr, 1024);
        gemmf(1024, 384, hd1, 1024, 1024, op_w, 1024, nullptr, 0, 0, nullptr, 0,
              nullptr, 0, op_b, nullptr, out, 384, s);
    }
}

// Round 17
// 3079.150 us; speedup vs baseline: 1.1226x; 1.1226x over previous
//
#include <hip/hip_runtime.h>
#include <math.h>

// B=64, LAT=512, HC=HD=1024, NB=16, S=16, E=128, NOTES=128, OUT=384, L=2
// Split-bf16 MFMA GEMMs (x ~= hi+lo; A@W ~= Ah@Wh + Al@Wh + Ah@Wl).
// Round 16: new BN=64 kernel (gemm_mfma_n64) for M=64 GEMMs (ini+conductor):
// 2x blocks (64 vs 32), 16KB/buffer LDS, vmcnt(4). Decoder path unchanged.

typedef __attribute__((ext_vector_type(8))) short s16x8;
typedef __attribute__((ext_vector_type(4))) float f32x4;

__device__ inline unsigned short f2bu(float f) {   // RNE f32->bf16
    unsigned u = __float_as_uint(f);
    unsigned r = u + 0x7fff + ((u >> 16) & 1);
    return (unsigned short)(r >> 16);
}
__device__ inline float bu2f(unsigned short h) { return __uint_as_float(((unsigned)h) << 16); }

// async global->LDS, 16B per lane; LDS dest = wave-uniform base + lane*16
__device__ __forceinline__ void gload16(const unsigned short* g, char* l) {
    const unsigned int* gu = (const unsigned int*)g;
    unsigned int* lu = (unsigned int*)l;
    __builtin_amdgcn_global_load_lds(
        (const __attribute__((address_space(1))) unsigned int*)gu,
        (__attribute__((address_space(3))) unsigned int*)lu, 16, 0, 0);
}

// ---------------------------------------------------------------------------
// 64x128 tile, BK=32, 256 thr = 4 waves. 3-buffer LDS pipeline; swizzle on
// global source (LDS dest linear per-wave via global_load_lds).
// mode: 0 = fp32 C; 1 = split store Chi/Clo; 2 = per-step decoder scatter;
//       3 = batched-proj scatter; 4 = fused LSTM cell (gate-interleaved cols).
__global__ __launch_bounds__(256) void gemm_mfma(
    int M, int N,
    const unsigned short* __restrict__ A1h, const unsigned short* __restrict__ A1l, int K1, int lda1,
    const unsigned short* __restrict__ W1h, const unsigned short* __restrict__ W1l, int ldw1,
    const unsigned short* __restrict__ A2h, const unsigned short* __restrict__ A2l, int K2, int lda2,
    const unsigned short* __restrict__ W2h, const unsigned short* __restrict__ W2l, int ldw2,
    const float* __restrict__ Add, int ldadd,
    const float* __restrict__ b1, const float* __restrict__ b2,
    float* __restrict__ C, int ldc,
    unsigned short* __restrict__ Chi, unsigned short* __restrict__ Clo,
    unsigned short* __restrict__ cpyh, unsigned short* __restrict__ cpyl,
    int mode, int scatter_s)
{
    __shared__ __align__(16) char ldsb[73728];   // 3 buffers x 24576 B

    const int tid = threadIdx.x;
    const int lane = tid & 63;
    const int wv = tid >> 6;

    const int gx = gridDim.x;
    const int l = blockIdx.y * gx + blockIdx.x;
    const int nwg = gx * gridDim.y;
    const int l2 = (l & 7) * (nwg >> 3) + (l >> 3);
    const int bm = (l2 % gx) * 64;
    const int bn = (l2 / gx) * 128;

    const int j = (lane & 7) ^ (lane >> 3);
    const bool isLo = j >= 4;
    const int koff = (j & 3) * 8;
    const int rsub = lane >> 3;
    const int aR0 = bm + wv * 8 + rsub;
    const int bR0 = bn + wv * 8 + rsub;

    f32x4 acc[4][2];
#pragma unroll
    for (int m = 0; m < 4; ++m)
#pragma unroll
        for (int n = 0; n < 2; ++n) acc[m][n] = (f32x4)0.0f;

    const int fr = lane & 15;
    const int kc = lane >> 4;

    const int NT = (K1 + K2) >> 5;

#define STAGE(dstp, t) {                                                        \
        const int k0_ = (t) << 5;                                               \
        const bool ph2_ = (k0_ >= K1);                                          \
        const unsigned short* Ab_ = ph2_ ? (isLo ? A2l : A2h)                   \
                                         : (isLo ? A1l : A1h);                  \
        const unsigned short* Wb_ = ph2_ ? (isLo ? W2l : W2h)                   \
                                         : (isLo ? W1l : W1h);                  \
        const int lda_ = ph2_ ? lda2 : lda1;                                    \
        const int ldw_ = ph2_ ? ldw2 : ldw1;                                    \
        const int kk_ = (ph2_ ? (k0_ - K1) : k0_) + koff;                       \
        char* dst_ = (dstp);                                                    \
        gload16(Ab_ + (size_t)aR0 * lda_ + kk_,        dst_ + (wv     ) * 1024);\
        gload16(Ab_ + (size_t)(aR0 + 32) * lda_ + kk_, dst_ + (wv +  4) * 1024);\
        gload16(Wb_ + (size_t)(bR0 +  0) * ldw_ + kk_, dst_ + (wv +  8) * 1024);\
        gload16(Wb_ + (size_t)(bR0 + 32) * ldw_ + kk_, dst_ + (wv + 12) * 1024);\
        gload16(Wb_ + (size_t)(bR0 + 64) * ldw_ + kk_, dst_ + (wv + 16) * 1024);\
        gload16(Wb_ + (size_t)(bR0 + 96) * ldw_ + kk_, dst_ + (wv + 20) * 1024);\
    }

    char* bcur  = ldsb;
    char* bnext = ldsb + 24576;
    char* bfar  = ldsb + 49152;

    STAGE(bcur, 0);
    STAGE(bnext, 1);
    asm volatile("s_waitcnt vmcnt(6)" ::: "memory");
    __builtin_amdgcn_s_barrier();

    for (int t = 0; t < NT; ++t) {
        const bool more = (t + 2 < NT);
        if (more) STAGE(bfar, t + 2);
        {
            s16x8 ah[4], al[4], bh[2], bl[2];
#pragma unroll
            for (int m = 0; m < 4; ++m) {
                const int row = m * 16 + fr;
                const int sw = (row & 7) << 4;
                char* base = bcur + row * 128;
                ah[m] = *(const s16x8*)(base + ((kc * 16) ^ sw));
            }
#pragma unroll
            for (int n = 0; n < 2; ++n) {
                const int row = wv * 32 + n * 16 + fr;
                const int sw = (row & 7) << 4;
                char* base = bcur + 8192 + row * 128;
                bh[n] = *(const s16x8*)(base + ((kc * 16) ^ sw));
            }
            __builtin_amdgcn_s_setprio(1);
#pragma unroll
            for (int m = 0; m < 4; ++m)
#pragma unroll
                for (int n = 0; n < 2; ++n)
                    acc[m][n] = __builtin_amdgcn_mfma_f32_16x16x32_bf16(ah[m], bh[n], acc[m][n], 0, 0, 0);
            __builtin_amdgcn_s_setprio(0);
#pragma unroll
            for (int m = 0; m < 4; ++m) {
                const int row = m * 16 + fr;
                const int sw = (row & 7) << 4;
                char* base = bcur + row * 128;
                al[m] = *(const s16x8*)(base + (((kc + 4) * 16) ^ sw));
            }
#pragma unroll
            for (int n = 0; n < 2; ++n) {
                const int row = wv * 32 + n * 16 + fr;
                const int sw = (row & 7) << 4;
                char* base = bcur + 8192 + row * 128;
                bl[n] = *(const s16x8*)(base + (((kc + 4) * 16) ^ sw));
            }
            __builtin_amdgcn_s_setprio(1);
#pragma unroll
            for (int m = 0; m < 4; ++m)
#pragma unroll
                for (int n = 0; n < 2; ++n) {
                    acc[m][n] = __builtin_amdgcn_mfma_f32_16x16x32_bf16(al[m], bh[n], acc[m][n], 0, 0, 0);
                    acc[m][n] = __builtin_amdgcn_mfma_f32_16x16x32_bf16(ah[m], bl[n], acc[m][n], 0, 0, 0);
                }
            __builtin_amdgcn_s_setprio(0);
        }
        if (more) { asm volatile("s_waitcnt vmcnt(6)" ::: "memory"); }
        else      { asm volatile("s_waitcnt vmcnt(0)" ::: "memory"); }
        __builtin_amdgcn_s_barrier();
        char* tmp = bcur; bcur = bnext; bnext = bfar; bfar = tmp;
    }
#undef STAGE

    if (mode == 4) {
        float* ldsf = (float*)ldsb;
#pragma unroll
        for (int m = 0; m < 4; ++m)
#pragma unroll
            for (int n = 0; n < 2; ++n) {
                f32x4 v4 = acc[m][n];
#pragma unroll
                for (int q = 0; q < 4; ++q) {
                    const int rl = m * 16 + kc * 4 + q;
                    const int cl = wv * 32 + n * 16 + fr;
                    const int col = bn + cl;
                    float v = v4[q];
                    if (b1) v += b1[col];
                    if (Add) v += Add[(size_t)(bm + rl) * ldadd + col];
                    ldsf[rl * 132 + cl] = v;
                }
            }
        __syncthreads();
        const int kb = bn >> 2;
#pragma unroll
        for (int e = 0; e < 8; ++e) {
            const int idx2 = tid * 8 + e;
            const int row = idx2 >> 5, kk = idx2 & 31;
            const float4 g4 = *(const float4*)(ldsf + row * 132 + kk * 4);
            const size_t ci = (((size_t)(bm + row)) << 10) + kb + kk;
            const float si = 1.f / (1.f + expf(-g4.x));
            const float sf = 1.f / (1.f + expf(-g4.y));
            const float so = 1.f / (1.f + expf(-g4.w));
            const float cn = sf * C[ci] + si * tanhf(g4.z);
            const float hn = so * tanhf(cn);
            C[ci] = cn;
            const unsigned short hh = f2bu(hn);
            const unsigned short hl = f2bu(hn - bu2f(hh));
            Chi[ci] = hh; Clo[ci] = hl;
            if (cpyh) { cpyh[ci] = hh; cpyl[ci] = hl; }
        }
        return;
    }

#pragma unroll
    for (int m = 0; m < 4; ++m)
#pragma unroll
        for (int n = 0; n < 2; ++n) {
            f32x4 v4 = acc[m][n];
#pragma unroll
            for (int q = 0; q < 4; ++q) {
                const int rl = m * 16 + kc * 4 + q;
                const int cl = wv * 32 + n * 16 + fr;
                const int r = bm + rl, col = bn + cl;
                float v = v4[q];
                if (b1) v += b1[col];
                if (b2) v += b2[col];
                if (Add) v += Add[(size_t)r * ldadd + col];
                if (mode == 0) {
                    C[(size_t)r * ldc + col] = v;
                } else if (mode == 1) {
                    unsigned short h = f2bu(v);
                    Chi[(size_t)r * ldc + col] = h;
                    Clo[(size_t)r * ldc + col] = f2bu(v - bu2f(h));
                } else if (mode == 2) {
                    const int bb = r & 63, nb = r >> 6;
                    C[(size_t)(((bb * 16 + nb) * 16 + scatter_s)) * 384 + col] = v;
                } else {
                    const int bb = r & 63, nb = (r >> 6) & 15, s = r >> 10;
                    C[(size_t)(((bb * 16 + nb) * 16 + s)) * 384 + col] = v;
                }
            }
        }
}

// ---------------------------------------------------------------------------
// BN=64 variant for M=64 GEMMs (ini + conductor): 64x64 tile, 4 waves each
// 64x16, 4 loads/iter, 16KB/buffer. modes: 0 (fp32 C + b1) and 4 (fused cell).
__global__ __launch_bounds__(256) void gemm_mfma_n64(
    int M, int N,
    const unsigned short* __restrict__ A1h, const unsigned short* __restrict__ A1l, int K1, int lda1,
    const unsigned short* __restrict__ W1h, const unsigned short* __restrict__ W1l, int ldw1,
    const unsigned short* __restrict__ A2h, const unsigned short* __restrict__ A2l, int K2, int lda2,
    const unsigned short* __restrict__ W2h, const unsigned short* __restrict__ W2l, int ldw2,
    const float* __restrict__ b1,
    float* __restrict__ C, int ldc,
    unsigned short* __restrict__ Chi, unsigned short* __restrict__ Clo,
    unsigned short* __restrict__ cpyh, unsigned short* __restrict__ cpyl,
    int mode)
{
    __shared__ __align__(16) char ldsb[49152];   // 3 buffers x 16384 B

    const int tid = threadIdx.x;
    const int lane = tid & 63;
    const int wv = tid >> 6;

    const int gx = gridDim.x;
    const int l = blockIdx.y * gx + blockIdx.x;
    const int nwg = gx * gridDim.y;
    const int l2 = (l & 7) * (nwg >> 3) + (l >> 3);
    const int bm = (l2 % gx) * 64;
    const int bn = (l2 / gx) * 64;

    const int j = (lane & 7) ^ (lane >> 3);
    const bool isLo = j >= 4;
    const int koff = (j & 3) * 8;
    const int rsub = lane >> 3;
    const int aR0 = bm + wv * 8 + rsub;
    const int bR0 = bn + wv * 8 + rsub;

    f32x4 acc[4];
#pragma unroll
    for (int m = 0; m < 4; ++m) acc[m] = (f32x4)0.0f;

    const int fr = lane & 15;
    const int kc = lane >> 4;

    const int NT = (K1 + K2) >> 5;

#define STAGE64(dstp, t) {                                                      \
        const int k0_ = (t) << 5;                                               \
        const bool ph2_ = (k0_ >= K1);                                          \
        const unsigned short* Ab_ = ph2_ ? (isLo ? A2l : A2h)                   \
                                         : (isLo ? A1l : A1h);                  \
        const unsigned short* Wb_ = ph2_ ? (isLo ? W2l : W2h)                   \
                                         : (isLo ? W1l : W1h);                  \
        const int lda_ = ph2_ ? lda2 : lda1;                                    \
        const int ldw_ = ph2_ ? ldw2 : ldw1;                                    \
        const int kk_ = (ph2_ ? (k0_ - K1) : k0_) + koff;                       \
        char* dst_ = (dstp);                                                    \
        gload16(Ab_ + (size_t)aR0 * lda_ + kk_,        dst_ + (wv    ) * 1024); \
        gload16(Ab_ + (size_t)(aR0 + 32) * lda_ + kk_, dst_ + (wv + 4) * 1024); \
        gload16(Wb_ + (size_t)bR0 * ldw_ + kk_,        dst_ + 8192 + (wv    ) * 1024); \
        gload16(Wb_ + (size_t)(bR0 + 32) * ldw_ + kk_, dst_ + 8192 + (wv + 4) * 1024); \
    }

    char* bcur  = ldsb;
    char* bnext = ldsb + 16384;
    char* bfar  = ldsb + 32768;

    STAGE64(bcur, 0);
    STAGE64(bnext, 1);
    asm volatile("s_waitcnt vmcnt(4)" ::: "memory");
    __builtin_amdgcn_s_barrier();

    for (int t = 0; t < NT; ++t) {
        const bool more = (t + 2 < NT);
        if (more) STAGE64(bfar, t + 2);
        {
            s16x8 ah[4], al[4], bh, bl;
            const int brow = wv * 16 + fr;
            const int bsw = (brow & 7) << 4;
            char* bbase = bcur + 8192 + brow * 128;
#pragma unroll
            for (int m = 0; m < 4; ++m) {
                const int row = m * 16 + fr;
                const int sw = (row & 7) << 4;
                char* base = bcur + row * 128;
                ah[m] = *(const s16x8*)(base + ((kc * 16) ^ sw));
            }
            bh = *(const s16x8*)(bbase + ((kc * 16) ^ bsw));
            __builtin_amdgcn_s_setprio(1);
#pragma unroll
            for (int m = 0; m < 4; ++m)
                acc[m] = __builtin_amdgcn_mfma_f32_16x16x32_bf16(ah[m], bh, acc[m], 0, 0, 0);
            __builtin_amdgcn_s_setprio(0);
#pragma unroll
            for (int m = 0; m < 4; ++m) {
                const int row = m * 16 + fr;
                const int sw = (row & 7) << 4;
                char* base = bcur + row * 128;
                al[m] = *(const s16x8*)(base + (((kc + 4) * 16) ^ sw));
            }
            bl = *(const s16x8*)(bbase + (((kc + 4) * 16) ^ bsw));
            __builtin_amdgcn_s_setprio(1);
#pragma unroll
            for (int m = 0; m < 4; ++m) {
                acc[m] = __builtin_amdgcn_mfma_f32_16x16x32_bf16(al[m], bh, acc[m], 0, 0, 0);
                acc[m] = __builtin_amdgcn_mfma_f32_16x16x32_bf16(ah[m], bl, acc[m], 0, 0, 0);
            }
            __builtin_amdgcn_s_setprio(0);
        }
        if (more) { asm volatile("s_waitcnt vmcnt(4)" ::: "memory"); }
        else      { asm volatile("s_waitcnt vmcnt(0)" ::: "memory"); }
        __builtin_amdgcn_s_barrier();
        char* tmp = bcur; bcur = bnext; bnext = bfar; bfar = tmp;
    }
#undef STAGE64

    if (mode == 4) {
        // gate-interleaved fused cell; block covers 64 rows x 16 k's
        float* ldsf = (float*)ldsb;
#pragma unroll
        for (int m = 0; m < 4; ++m) {
            f32x4 v4 = acc[m];
#pragma unroll
            for (int q = 0; q < 4; ++q) {
                const int rl = m * 16 + kc * 4 + q;
                const int cl = wv * 16 + fr;
                float v = v4[q];
                if (b1) v += b1[bn + cl];
                ldsf[rl * 68 + cl] = v;
            }
        }
        __syncthreads();
        const int kb = bn >> 2;
#pragma unroll
        for (int e = 0; e < 4; ++e) {
            const int idx2 = tid * 4 + e;          // 0..1023
            const int row = idx2 >> 4, kk = idx2 & 15;
            const float4 g4 = *(const float4*)(ldsf + row * 68 + kk * 4);
            const size_t ci = (((size_t)(bm + row)) << 10) + kb + kk;
            const float si = 1.f / (1.f + expf(-g4.x));
            const float sf = 1.f / (1.f + expf(-g4.y));
            const float so = 1.f / (1.f + expf(-g4.w));
            const float cn = sf * C[ci] + si * tanhf(g4.z);
            const float hn = so * tanhf(cn);
            C[ci] = cn;
            const unsigned short hh = f2bu(hn);
            const unsigned short hl = f2bu(hn - bu2f(hh));
            Chi[ci] = hh; Clo[ci] = hl;
            if (cpyh) { cpyh[ci] = hh; cpyl[ci] = hl; }
        }
        return;
    }

    // mode 0: fp32 C + b1
#pragma unroll
    for (int m = 0; m < 4; ++m) {
        f32x4 v4 = acc[m];
#pragma unroll
        for (int q = 0; q < 4; ++q) {
            const int rl = m * 16 + kc * 4 + q;
            const int cl = wv * 16 + fr;
            const int r = bm + rl, col = bn + cl;
            float v = v4[q];
            if (b1) v += b1[col];
            C[(size_t)r * ldc + col] = v;
        }
    }
}

// ---------------------------------------------------------------------------
__global__ __launch_bounds__(256) void split_pack(
    const float* __restrict__ src, int ldsrc, int c0, long total, int C,
    unsigned short* __restrict__ hi, unsigned short* __restrict__ lo)
{
    long i = ((long)blockIdx.x * 256 + threadIdx.x) * 4;
    if (i >= total) return;
    int r = (int)(i / C), c = (int)(i % C);
    float4 v = *(const float4*)(src + (size_t)r * ldsrc + c0 + c);
#pragma unroll
    for (int j = 0; j < 4; ++j) {
        float x = (&v.x)[j];
        unsigned short h = f2bu(x);
        hi[i + j] = h;
        lo[i + j] = f2bu(x - bu2f(h));
    }
}

// gate-permuted split: dst row j (0..4095) <- src row (j&3)*1024 + (j>>2)
__global__ __launch_bounds__(256) void split_pack_perm(
    const float* __restrict__ src, int ldsrc, int c0, long total, int C,
    unsigned short* __restrict__ hi, unsigned short* __restrict__ lo)
{
    long i = ((long)blockIdx.x * 256 + threadIdx.x) * 4;
    if (i >= total) return;
    int r = (int)(i / C), c = (int)(i % C);
    int sr = (r & 3) * 1024 + (r >> 2);
    float4 v = *(const float4*)(src + (size_t)sr * ldsrc + c0 + c);
#pragma unroll
    for (int j = 0; j < 4; ++j) {
        float x = (&v.x)[j];
        unsigned short h = f2bu(x);
        hi[i + j] = h;
        lo[i + j] = f2bu(x - bu2f(h));
    }
}

// dst[j] = a[old(j)] + b[old(j)], old(j) = (j&3)*1024 + (j>>2)
__global__ __launch_bounds__(256) void bias_perm(
    const float* __restrict__ a, const float* __restrict__ b, float* __restrict__ dst)
{
    const int j = blockIdx.x * 256 + threadIdx.x;
    if (j >= 4096) return;
    const int o = (j & 3) * 1024 + (j >> 2);
    dst[j] = a[o] + b[o];
}

__global__ __launch_bounds__(256) void scatter_ini_split(
    const float* __restrict__ I, unsigned short* __restrict__ hchi,
    unsigned short* __restrict__ hclo, float* __restrict__ cc)
{
    const int idx = blockIdx.x * blockDim.x + threadIdx.x;
    if (idx >= 131072) return;
    const int k = idx & 1023, b = (idx >> 10) & 63, l = idx >> 16;
    const float* row = I + (size_t)b * 4096;
    float hv = row[(l << 10) + k];
    unsigned short h = f2bu(hv);
    hchi[idx] = h; hclo[idx] = f2bu(hv - bu2f(h));
    cc[idx] = row[2048 + (l << 10) + k];
}

__global__ __launch_bounds__(256) void scatter_di_split(
    const float* __restrict__ D,
    unsigned short* __restrict__ h0h, unsigned short* __restrict__ h0l,
    unsigned short* __restrict__ h1h, unsigned short* __restrict__ h1l,
    float* __restrict__ cd0, float* __restrict__ cd1)
{
    const int idx = blockIdx.x * blockDim.x + threadIdx.x;
    if (idx >= 1048576) return;
    const int k = idx & 1023, r = idx >> 10;
    const float* row = D + ((size_t)r << 12);
    float v0 = row[k], v1 = row[1024 + k];
    unsigned short a = f2bu(v0); h0h[idx] = a; h0l[idx] = f2bu(v0 - bu2f(a));
    unsigned short b = f2bu(v1); h1h[idx] = b; h1l[idx] = f2bu(v1 - bu2f(b));
    cd0[idx] = row[2048 + k];
    cd1[idx] = row[3072 + k];
}

__global__ __launch_bounds__(256) void build_prev_b(
    const int* __restrict__ tp, unsigned short* __restrict__ ph, unsigned short* __restrict__ pl)
{
    const int idx = blockIdx.x * blockDim.x + threadIdx.x;
    if (idx >= 2097152) return;
    const int n = idx & 127;
    const int r = (idx >> 7) & 1023;
    const int s = idx >> 17;
    const int nb = r >> 6, bb = r & 63;
    const int t = nb * 16 + s;
    float v = 0.f;
    if (t > 0) v = (float)tp[(size_t)bb * 32768 + (size_t)(t - 1) * 128 + n];
    ph[idx] = f2bu(v);
    pl[idx] = 0;
}

// ===========================================================================
// Fallback fp32 path (proven baseline)
#define BM 64
#define BN 64
#define BK 16

__global__ __launch_bounds__(256) void gemm_f32(
    int M, int N,
    const float* __restrict__ A1, int K1, int lda1,
    const float* __restrict__ W1, int ldw1,
    const float* __restrict__ A2, int K2, int lda2,
    const float* __restrict__ W2, int ldw2,
    const float* __restrict__ Add, int ldadd,
    const float* __restrict__ bias1, const float* __restrict__ bias2,
    float* __restrict__ C, int ldc, int scatter_s)
{
    __shared__ float As[BK][BM];
    __shared__ float Ws[BK][BN];
    const int bm = blockIdx.x * BM;
    const int bn = blockIdx.y * BN;
    const int tid = threadIdx.x;
    const int ty = tid >> 4;
    const int tx = tid & 15;
    const int lr = tid >> 2;
    const int lc = (tid & 3) << 2;

    float acc[4][4] = {{0.f,0.f,0.f,0.f},{0.f,0.f,0.f,0.f},{0.f,0.f,0.f,0.f},{0.f,0.f,0.f,0.f}};

    for (int phase = 0; phase < 2; ++phase) {
        const float* Ap = phase ? A2 : A1;
        const float* Wp = phase ? W2 : W1;
        const int K   = phase ? K2 : K1;
        const int lda = phase ? lda2 : lda1;
        const int ldw = phase ? ldw2 : ldw1;
        if (Ap == nullptr || K <= 0) continue;
        for (int k0 = 0; k0 < K; k0 += BK) {
            float4 av = *(const float4*)(Ap + (size_t)(bm + lr) * lda + k0 + lc);
            float4 wv = *(const float4*)(Wp + (size_t)(bn + lr) * ldw + k0 + lc);
            __syncthreads();
            As[lc+0][lr] = av.x; As[lc+1][lr] = av.y; As[lc+2][lr] = av.z; As[lc+3][lr] = av.w;
            Ws[lc+0][lr] = wv.x; Ws[lc+1][lr] = wv.y; Ws[lc+2][lr] = wv.z; Ws[lc+3][lr] = wv.w;
            __syncthreads();
            #pragma unroll
            for (int k = 0; k < BK; ++k) {
                float4 a = *(const float4*)&As[k][ty << 2];
                float4 w = *(const float4*)&Ws[k][tx << 2];
                acc[0][0] = fmaf(a.x, w.x, acc[0][0]);
                acc[0][1] = fmaf(a.x, w.y, acc[0][1]);
                acc[0][2] = fmaf(a.x, w.z, acc[0][2]);
                acc[0][3] = fmaf(a.x, w.w, acc[0][3]);
                acc[1][0] = fmaf(a.y, w.x, acc[1][0]);
                acc[1][1] = fmaf(a.y, w.y, acc[1][1]);
                acc[1][2] = fmaf(a.y, w.z, acc[1][2]);
                acc[1][3] = fmaf(a.y, w.w, acc[1][3]);
                acc[2][0] = fmaf(a.z, w.x, acc[2][0]);
                acc[2][1] = fmaf(a.z, w.y, acc[2][1]);
                acc[2][2] = fmaf(a.z, w.z, acc[2][2]);
                acc[2][3] = fmaf(a.z, w.w, acc[2][3]);
                acc[3][0] = fmaf(a.w, w.x, acc[3][0]);
                acc[3][1] = fmaf(a.w, w.y, acc[3][1]);
                acc[3][2] = fmaf(a.w, w.z, acc[3][2]);
                acc[3][3] = fmaf(a.w, w.w, acc[3][3]);
            }
        }
    }

    #pragma unroll
    for (int i = 0; i < 4; ++i) {
        const int row = bm + (ty << 2) + i;
        #pragma unroll
        for (int j = 0; j < 4; ++j) {
            const int col = bn + (tx << 2) + j;
            float v = acc[i][j];
            if (bias1) v += bias1[col];
            if (bias2) v += bias2[col];
            if (Add)   v += Add[(size_t)row * ldadd + col];
            if (scatter_s >= 0) {
                const int bb = row & 63, nb = row >> 6;
                C[(size_t)(((bb * 16 + nb) * 16 + scatter_s)) * 384 + col] = v;
            } else {
                C[(size_t)row * ldc + col] = v;
            }
        }
    }
}

__global__ __launch_bounds__(256) void lstm_cell(
    const float* __restrict__ g, float* __restrict__ c,
    float* __restrict__ h, float* __restrict__ hcopy, int M)
{
    const int idx = blockIdx.x * blockDim.x + threadIdx.x;
    if (idx >= (M << 10)) return;
    const int r = idx >> 10, k = idx & 1023;
    const float* gr = g + ((size_t)r << 12);
    const float gi = gr[k], gf = gr[k + 1024], gg = gr[k + 2048], go = gr[k + 3072];
    const float si = 1.f / (1.f + expf(-gi));
    const float sf = 1.f / (1.f + expf(-gf));
    const float so = 1.f / (1.f + expf(-go));
    const float cn = sf * c[idx] + si * tanhf(gg);
    const float hn = so * tanhf(cn);
    c[idx] = cn;
    h[idx] = hn;
    if (hcopy) hcopy[idx] = hn;
}

__global__ __launch_bounds__(256) void scatter_ini(
    const float* __restrict__ I, float* __restrict__ hc, float* __restrict__ cc)
{
    const int idx = blockIdx.x * blockDim.x + threadIdx.x;
    if (idx >= 131072) return;
    const int k = idx & 1023, b = (idx >> 10) & 63, l = idx >> 16;
    const float* row = I + (size_t)b * 4096;
    hc[idx] = row[(l << 10) + k];
    cc[idx] = row[2048 + (l << 10) + k];
}

__global__ __launch_bounds__(256) void scatter_di(
    const float* __restrict__ D, float* __restrict__ hd0, float* __restrict__ cd0,
    float* __restrict__ hd1, float* __restrict__ cd1)
{
    const int idx = blockIdx.x * blockDim.x + threadIdx.x;
    if (idx >= 1048576) return;
    const int k = idx & 1023, r = idx >> 10;
    const float* row = D + ((size_t)r << 12);
    hd0[idx] = row[k];
    hd1[idx] = row[1024 + k];
    cd0[idx] = row[2048 + k];
    cd1[idx] = row[3072 + k];
}

__global__ __launch_bounds__(256) void build_prev(
    const int* __restrict__ tp, float* __restrict__ prevf)
{
    const int idx = blockIdx.x * blockDim.x + threadIdx.x;
    if (idx >= 2097152) return;
    const int n = idx & 127;
    const int r = (idx >> 7) & 1023;
    const int s = idx >> 17;
    const int nb = r >> 6, bb = r & 63;
    const int t = nb * 16 + s;
    float v = 0.f;
    if (t > 0) v = (float)tp[(size_t)bb * 32768 + (size_t)(t - 1) * 128 + n];
    prevf[idx] = v;
}

// ===========================================================================
extern "C" void kernel_launch(void* const* d_in, const int* in_sizes, int n_in,
                              void* d_out, int out_size, void* d_ws, size_t ws_size,
                              hipStream_t stream)
{
    (void)in_sizes; (void)n_in; (void)out_size;
    const float* z      = (const float*)d_in[0];
    const int*   tp     = (const int*)  d_in[1];
    const float* w_zc   = (const float*)d_in[2];
    const float* b_zc   = (const float*)d_in[3];
    const float* c_whh0 = (const float*)d_in[5];
    const float* c_bih0 = (const float*)d_in[6];
    const float* c_bhh0 = (const float*)d_in[7];
    const float* c_wih1 = (const float*)d_in[8];
    const float* c_whh1 = (const float*)d_in[9];
    const float* c_bih1 = (const float*)d_in[10];
    const float* c_bhh1 = (const float*)d_in[11];
    const float* np_w   = (const float*)d_in[12];
    const float* np_b   = (const float*)d_in[13];
    const float* cd_w   = (const float*)d_in[14];
    const float* cd_b   = (const float*)d_in[15];
    const float* d_wih0 = (const float*)d_in[16];
    const float* d_whh0 = (const float*)d_in[17];
    const float* d_bih0 = (const float*)d_in[18];
    const float* d_bhh0 = (const float*)d_in[19];
    const float* d_wih1 = (const float*)d_in[20];
    const float* d_whh1 = (const float*)d_in[21];
    const float* d_bih1 = (const float*)d_in[22];
    const float* d_bhh1 = (const float*)d_in[23];
    const float* op_w   = (const float*)d_in[24];
    const float* op_b   = (const float*)d_in[25];
    float* out = (float*)d_out;

    // ---- workspace layout for MFMA path (bytes) ----
    size_t o = 0;
    auto alloc = [&](size_t bytes) { size_t r = o; o = (o + bytes + 255) & ~(size_t)255; return r; };
    const size_t oCW0 = alloc((size_t)4096*1024*4);
    const size_t oCW1 = alloc((size_t)4096*1024*4);
    const size_t oCW2 = alloc((size_t)4096*1024*4);
    const size_t oWZC = alloc((size_t)4096*512*4);     // later reused: D0E + OPW
    const size_t oNPW = alloc((size_t)128*128*4);
    const size_t oZS  = alloc((size_t)64*512*4);
    const size_t oCDW = alloc((size_t)4096*1024*4);
    const size_t oD0R = alloc((size_t)4096*1024*4);
    const size_t oCG  = alloc((size_t)64*4096*4);
    const size_t oCC  = alloc((size_t)2*64*1024*4);
    const size_t oHCa = alloc((size_t)2*64*1024*4);    // h ping (hi[2][64][1024], lo)
    const size_t oHCb = alloc((size_t)2*64*1024*4);    // h pong
    const size_t oCND = alloc((size_t)1024*1024*4);
    const size_t oEMB = alloc((size_t)16*1024*128*4);
    const size_t oBRP = alloc((size_t)1024*4096*4);
    const size_t oDG  = alloc((size_t)1024*4096*4);    // PRV aliases this (PRV dead before DG live)
    const size_t oHD0a= alloc((size_t)1024*1024*4);
    const size_t oHD0b= alloc((size_t)1024*1024*4);
    const size_t oHD1a= alloc((size_t)1024*1024*4);
    const size_t oHD1b= alloc((size_t)1024*1024*4);
    const size_t oCD0 = alloc((size_t)1024*1024*4);
    const size_t oCD1 = alloc((size_t)1024*1024*4);
    const size_t oBS  = alloc((size_t)4*4096*4);
    const size_t need = o;
    const size_t oH1S = alloc((size_t)16*1024*1024*4);
    const size_t need_batched = o;

    if (ws_size >= need) {
        const bool batched = (ws_size >= need_batched);
        char* ws = (char*)d_ws;
        unsigned short* CW0 = (unsigned short*)(ws + oCW0);
        unsigned short* CW1 = (unsigned short*)(ws + oCW1);
        unsigned short* CW2 = (unsigned short*)(ws + oCW2);
        unsigned short* WZC = (unsigned short*)(ws + oWZC);
        unsigned short* NPW = (unsigned short*)(ws + oNPW);
        unsigned short* ZS  = (unsigned short*)(ws + oZS);
        unsigned short* CDW = (unsigned short*)(ws + oCDW);
        unsigned short* D0R = (unsigned short*)(ws + oD0R);
        float* CG  = (float*)(ws + oCG);
        float* CC  = (float*)(ws + oCC);
        unsigned short* HCa = (unsigned short*)(ws + oHCa);
        unsigned short* HCb = (unsigned short*)(ws + oHCb);
        unsigned short* CND = (unsigned short*)(ws + oCND);
        unsigned short* PRV = (unsigned short*)(ws + oDG);   // alias: dead before DG live
        unsigned short* EMB = (unsigned short*)(ws + oEMB);
        float* BRP = (float*)(ws + oBRP);
        float* DG  = (float*)(ws + oDG);
        unsigned short* HD0a = (unsigned short*)(ws + oHD0a);
        unsigned short* HD0b = (unsigned short*)(ws + oHD0b);
        unsigned short* HD1a = (unsigned short*)(ws + oHD1a);
        unsigned short* HD1b = (unsigned short*)(ws + oHD1b);
        float* CD0 = (float*)(ws + oCD0);
        float* CD1 = (float*)(ws + oCD1);
        float* BSC0 = (float*)(ws + oBS);
        float* BSC1 = BSC0 + 4096;
        float* BSB0 = BSC1 + 4096;
        float* BSD1 = BSB0 + 4096;
        unsigned short* H1S  = (unsigned short*)(ws + oH1S);
        unsigned short* H1Sl = H1S + (size_t)16*1048576;
        unsigned short* DWHH0 = CW0;      // aliases, filled after conductor
        unsigned short* DWIH1 = CW1;
        unsigned short* DWHH1 = CW2;
        unsigned short* D0E   = WZC;
        unsigned short* OPW   = WZC + (size_t)2*4096*128;

        auto split = [&](const float* src, int ldsrc, int c0, long R, long C, unsigned short* dst) {
            long total = R * C;
            split_pack<<<(unsigned)((total/4 + 255) / 256), 256, 0, stream>>>(
                src, ldsrc, c0, total, (int)C, dst, dst + total);
        };
        auto splitP = [&](const float* src, int ldsrc, int c0, long C, unsigned short* dst) {
            long total = 4096 * C;
            split_pack_perm<<<(unsigned)((total/4 + 255) / 256), 256, 0, stream>>>(
                src, ldsrc, c0, total, (int)C, dst, dst + total);
        };
        auto gemm2 = [&](int M, int N,
                         const unsigned short* A1h, const unsigned short* A1l, int K1, int lda1,
                         const unsigned short* W1, int ldw1,
                         const unsigned short* A2h, const unsigned short* A2l, int K2, int lda2,
                         const unsigned short* W2, int ldw2,
                         const float* Addp, int ldadd, const float* bb1, const float* bb2,
                         float* Cp, int ldc, unsigned short* Chi, unsigned short* Clo,
                         unsigned short* cpyh, unsigned short* cpyl,
                         int mode, int ss) {
            const unsigned short* W1l = W1 ? W1 + (size_t)N*ldw1 : nullptr;
            const unsigned short* W2l = W2 ? W2 + (size_t)N*ldw2 : nullptr;
            dim3 grid(M / 64, N / 128);
            gemm_mfma<<<grid, 256, 0, stream>>>(M, N, A1h, A1l, K1, lda1, W1, W1l, ldw1,
                                                A2h, A2l, K2, lda2, W2, W2l, ldw2,
                                                Addp, ldadd, bb1, bb2, Cp, ldc, Chi, Clo,
                                                cpyh, cpyl, mode, ss);
        };
        auto gemmN64 = [&](int M, int N,
                           const unsigned short* A1h, const unsigned short* A1l, int K1, int lda1,
                           const unsigned short* W1, int ldw1,
                           const unsigned short* A2h, const unsigned short* A2l, int K2, int lda2,
                           const unsigned short* W2, int ldw2,
                           const float* bb1, float* Cp, int ldc,
                           unsigned short* Chi, unsigned short* Clo,
                           unsigned short* cpyh, unsigned short* cpyl, int mode) {
            const unsigned short* W1l = W1 ? W1 + (size_t)N*ldw1 : nullptr;
            const unsigned short* W2l = W2 ? W2 + (size_t)N*ldw2 : nullptr;
            dim3 grid(M / 64, N / 64);
            gemm_mfma_n64<<<grid, 256, 0, stream>>>(M, N, A1h, A1l, K1, lda1, W1, W1l, ldw1,
                                                    A2h, A2l, K2, lda2, W2, W2l, ldw2,
                                                    bb1, Cp, ldc, Chi, Clo, cpyh, cpyl, mode);
        };

        // h-state pointer helpers (hi at base, lo at +count)
        auto hc0h = [&](int b){ return (b ? HCb : HCa); };
        auto hc0l = [&](int b){ return (b ? HCb : HCa) + 131072; };
        auto hc1h = [&](int b){ return (b ? HCb : HCa) + 65536; };
        auto hc1l = [&](int b){ return (b ? HCb : HCa) + 131072 + 65536; };
        auto hd0h = [&](int b){ return (b ? HD0b : HD0a); };
        auto hd0l = [&](int b){ return (b ? HD0b : HD0a) + 1048576; };
        auto hd1h = [&](int b){ return (b ? HD1b : HD1a); };
        auto hd1l = [&](int b){ return (b ? HD1b : HD1a) + 1048576; };

        // 0) conversions (conductor weights gate-permuted) + permuted bias sums
        split(z, 512, 0, 64, 512, ZS);
        split(w_zc, 512, 0, 4096, 512, WZC);
        splitP(c_whh0, 1024, 0, 1024, CW0);
        splitP(c_wih1, 1024, 0, 1024, CW1);
        splitP(c_whh1, 1024, 0, 1024, CW2);
        split(np_w, 128, 0, 128, 128, NPW);
        split(cd_w, 1024, 0, 4096, 1024, CDW);
        splitP(d_wih0, 1152, 128, 1024, D0R);
        bias_perm<<<16, 256, 0, stream>>>(c_bih0, c_bhh0, BSC0);
        bias_perm<<<16, 256, 0, stream>>>(c_bih1, c_bhh1, BSC1);
        bias_perm<<<16, 256, 0, stream>>>(d_bih0, d_bhh0, BSB0);
        bias_perm<<<16, 256, 0, stream>>>(d_bih1, d_bhh1, BSD1);
        build_prev_b<<<8192, 256, 0, stream>>>(tp, PRV, PRV + 2097152);

        // 1) ini = z @ w_zc.T + b_zc -> CG -> split-scatter into HCa (ping 0)
        gemmN64(64, 4096, ZS, ZS + 32768, 512, 512, WZC, 512,
                nullptr, nullptr, 0, 0, nullptr, 0,
                b_zc, CG, 4096, nullptr, nullptr, nullptr, nullptr, 0);
        scatter_ini_split<<<512, 256, 0, stream>>>(CG, HCa, HCa + 131072, CC);

        // 2) emb = prev @ np_w.T + np_b (split out); PRV aliases DG (dead after this)
        gemm2(16384, 128, PRV, PRV + 2097152, 128, 128, NPW, 128,
              nullptr, nullptr, 0, 0, nullptr, 0,
              nullptr, 0, np_b, nullptr, nullptr, 128, EMB, EMB + 2097152, nullptr, nullptr, 1, -1);

        // 3) conductor: fused-cell N64 GEMMs, h ping-pong
        for (int t = 0; t < 16; ++t) {
            const int p = t & 1;
            gemmN64(64, 4096, hc0h(p), hc0l(p), 1024, 1024, CW0, 1024,
                    nullptr, nullptr, 0, 0, nullptr, 0,
                    BSC0, CC, 0, hc0h(p ^ 1), hc0l(p ^ 1), nullptr, nullptr, 4);
            gemmN64(64, 4096, hc0h(p ^ 1), hc0l(p ^ 1), 1024, 1024, CW1, 1024,
                    hc1h(p), hc1l(p), 1024, 1024, CW2, 1024,
                    BSC1, CC + 65536, 0, hc1h(p ^ 1), hc1l(p ^ 1),
                    CND + t * 65536, CND + 1048576 + t * 65536, 4);
        }

        // 4) decoder weights (aliases, stream-ordered after conductor)
        splitP(d_whh0, 1024, 0, 1024, DWHH0);
        splitP(d_wih1, 1024, 0, 1024, DWIH1);
        splitP(d_whh1, 1024, 0, 1024, DWHH1);
        splitP(d_wih0, 1152, 0, 128, D0E);
        split(op_w, 1024, 0, 384, 1024, OPW);

        // 5) di = cond @ cd_w.T + cd_b -> DG -> split scatter into ping 0
        gemm2(1024, 4096, CND, CND + 1048576, 1024, 1024, CDW, 1024,
              nullptr, nullptr, 0, 0, nullptr, 0,
              nullptr, 0, cd_b, nullptr, DG, 4096, nullptr, nullptr, nullptr, nullptr, 0, -1);
        scatter_di_split<<<4096, 256, 0, stream>>>(DG, HD0a, HD0a + 1048576,
                                                   HD1a, HD1a + 1048576, CD0, CD1);

        // 6) barpart = cond @ d_wih0[:,128:].T + (bih0+bhh0), permuted cols
        gemm2(1024, 4096, CND, CND + 1048576, 1024, 1024, D0R, 1024,
              nullptr, nullptr, 0, 0, nullptr, 0,
              nullptr, 0, BSB0, nullptr, BRP, 4096, nullptr, nullptr, nullptr, nullptr, 0, -1);

        // 7) decoder: fused-cell GEMMs, h ping-pong
        for (int s = 0; s < 16; ++s) {
            const int p = s & 1;
            gemm2(1024, 4096, EMB + (size_t)s * 131072, EMB + 2097152 + (size_t)s * 131072, 128, 128,
                  D0E, 128,
                  hd0h(p), hd0l(p), 1024, 1024, DWHH0, 1024,
                  BRP, 4096, nullptr, nullptr, CD0, 0, hd0h(p ^ 1), hd0l(p ^ 1),
                  nullptr, nullptr, 4, -1);
            gemm2(1024, 4096, hd0h(p ^ 1), hd0l(p ^ 1), 1024, 1024, DWIH1, 1024,
                  hd1h(p), hd1l(p), 1024, 1024, DWHH1, 1024,
                  nullptr, 0, BSD1, nullptr, CD1, 0, hd1h(p ^ 1), hd1l(p ^ 1),
                  batched ? H1S + (size_t)s * 1048576 : nullptr,
                  batched ? H1Sl + (size_t)s * 1048576 : nullptr, 4, -1);
            if (!batched) {
                gemm2(1024, 384, hd1h(p ^ 1), hd1l(p ^ 1), 1024, 1024, OPW, 1024,
                      nullptr, nullptr, 0, 0, nullptr, 0,
                      nullptr, 0, op_b, nullptr, out, 384, nullptr, nullptr, nullptr, nullptr, 2, s);
            }
        }
        if (batched) {
            gemm2(16384, 384, H1S, H1Sl, 1024, 1024, OPW, 1024,
                  nullptr, nullptr, 0, 0, nullptr, 0,
                  nullptr, 0, op_b, nullptr, out, 384, nullptr, nullptr, nullptr, nullptr, 3, -1);
        }
        return;
    }

    // ================= fallback: proven fp32 path =================
    float* wsf     = (float*)d_ws;
    float* hc      = wsf;
    float* cc      = hc + 131072;
    float* cond    = cc + 131072;
    float* cg      = cond + 1048576;
    float* barpart = cg + 262144;
    float* emb     = barpart + 4194304;
    float* prevf   = emb + 2097152;
    float* hd0     = prevf + 2097152;
    float* cd0     = hd0 + 1048576;
    float* hd1     = cd0 + 1048576;
    float* cd1     = hd1 + 1048576;
    float* dg      = cd1 + 1048576;

    auto gemmf = [&](int M, int N,
                     const float* A1, int K1, int lda1, const float* W1, int ldw1,
                     const float* A2, int K2, int lda2, const float* W2, int ldw2,
                     const float* Addp, int ldadd, const float* bb1, const float* bb2,
                     float* Cp, int ldc, int ss) {
        dim3 grid(M / BM, N / BN);
        gemm_f32<<<grid, dim3(256), 0, stream>>>(M, N, A1, K1, lda1, W1, ldw1,
                                                 A2, K2, lda2, W2, ldw2,
                                                 Addp, ldadd, bb1, bb2, Cp, ldc, ss);
    };

    gemmf(64, 4096, z, 512, 512, w_zc, 512, nullptr, 0, 0, nullptr, 0,
          nullptr, 0, b_zc, nullptr, cg, 4096, -1);
    scatter_ini<<<512, 256, 0, stream>>>(cg, hc, cc);

    build_prev<<<8192, 256, 0, stream>>>(tp, prevf);
    gemmf(16384, 128, prevf, 128, 128, np_w, 128, nullptr, 0, 0, nullptr, 0,
          nullptr, 0, np_b, nullptr, emb, 128, -1);

    for (int t = 0; t < 16; ++t) {
        gemmf(64, 4096, hc, 1024, 1024, c_whh0, 1024, nullptr, 0, 0, nullptr, 0,
              nullptr, 0, c_bih0, c_bhh0, cg, 4096, -1);
        lstm_cell<<<256, 256, 0, stream>>>(cg, cc, hc, nullptr, 64);
        gemmf(64, 4096, hc, 1024, 1024, c_wih1, 1024,
              hc + 65536, 1024, 1024, c_whh1, 1024,
              nullptr, 0, c_bih1, c_bhh1, cg, 4096, -1);
        lstm_cell<<<256, 256, 0, stream>>>(cg, cc + 65536, hc + 65536, cond + t * 65536, 64);
    }

    gemmf(1024, 4096, cond, 1024, 1024, cd_w, 1024, nullptr, 0, 0, nullptr, 0,
          nullptr, 0, cd_b, nullptr, dg, 4096, -1);
    scatter_di<<<4096, 256, 0, stream>>>(dg, hd0, cd0, hd1, cd1);

    gemmf(1024, 4096, cond, 1024, 1024, d_wih0 + 128, 1152, nullptr, 0, 0, nullptr, 0,
          nullptr, 0, d_bih0, d_bhh0, barpart, 4096, -1);

    for (int s = 0; s < 16; ++s) {
        gemmf(1024, 4096, emb + (size_t)s * 131072, 128, 128, d_wih0, 1152,
              hd0, 1024, 1024, d_whh0, 1024,
              barpart, 4096, nullptr, nullptr, dg, 4096, -1);
        lstm_cell<<<4096, 256, 0, stream>>>(dg, cd0, hd0, nullptr, 1024);
        gemmf(1024, 4096, hd0, 1024, 1024, d_wih1, 1024,
              hd1, 1024, 1024, d_whh1, 1024,
              nullptr, 0, d_bih1, d_bhh1, dg, 4096, -1);
        lstm_cell<<<4096, 256, 0, stream>>>(dg, cd1, hd1, nullptr, 1024);
        gemmf(1024, 384, hd1, 1024, 1024, op_w, 1024, nullptr, 0, 0, nullptr, 0,
              nullptr, 0, op_b, nullptr, out, 384, s);
    }
}

// Round 18
// 2446.953 us; speedup vs baseline: 1.4127x; 1.2584x over previous
//
#include <hip/hip_runtime.h>
#include <math.h>

// B=64, LAT=512, HC=HD=1024, NB=16, S=16, E=128, NOTES=128, OUT=384, L=2
// Round 18: fp16 2-term split GEMMs. A ~= Ah+Al (fp16 pair, 22 mantissa bits),
// W ~= Wh (single fp16). A@W ~= Ah@Wh + Al@Wh. Dropped term A*dW, |dW|<=|W|*2^-12.
// B-LDS rows shrink to 64B (hi only) with slot swizzle j2 = p ^ ((row>>1)&3);
// staging 4 loads/wave (decoder) / 3 (conductor), 3-buffer counted-vmcnt pipeline.

typedef __attribute__((ext_vector_type(8))) short s16x8;
typedef __attribute__((ext_vector_type(8))) _Float16 f16x8;
typedef __attribute__((ext_vector_type(4))) float f32x4;

__device__ inline unsigned short f2h(float f) {
    _Float16 h = (_Float16)f;
    return __builtin_bit_cast(unsigned short, h);
}
__device__ inline float h2f(unsigned short u) {
    _Float16 h = __builtin_bit_cast(_Float16, u);
    return (float)h;
}

// async global->LDS, 16B per lane; LDS dest = wave-uniform base + lane*16
__device__ __forceinline__ void gload16(const unsigned short* g, char* l) {
    const unsigned int* gu = (const unsigned int*)g;
    unsigned int* lu = (unsigned int*)l;
    __builtin_amdgcn_global_load_lds(
        (const __attribute__((address_space(1))) unsigned int*)gu,
        (__attribute__((address_space(3))) unsigned int*)lu, 16, 0, 0);
}

// ---------------------------------------------------------------------------
// 64x128 tile, BK=32, 256 thr = 4 waves. 3-buffer pipeline, counted vmcnt(4).
// LDS buffer 16KB: A 64 rows x 128B (hi|lo fp16) at 0; B 128 rows x 64B (hi) at 8192.
// mode: 0 = fp32 C; 1 = split store Chi/Clo; 2 = per-step decoder scatter;
//       3 = batched-proj scatter; 4 = fused LSTM cell (gate-interleaved cols).
__global__ __launch_bounds__(256) void gemm_mfma(
    int M, int N,
    const unsigned short* __restrict__ A1h, const unsigned short* __restrict__ A1l, int K1, int lda1,
    const unsigned short* __restrict__ W1h, int ldw1,
    const unsigned short* __restrict__ A2h, const unsigned short* __restrict__ A2l, int K2, int lda2,
    const unsigned short* __restrict__ W2h, int ldw2,
    const float* __restrict__ Add, int ldadd,
    const float* __restrict__ b1, const float* __restrict__ b2,
    float* __restrict__ C, int ldc,
    unsigned short* __restrict__ Chi, unsigned short* __restrict__ Clo,
    unsigned short* __restrict__ cpyh, unsigned short* __restrict__ cpyl,
    int mode, int scatter_s)
{
    __shared__ __align__(16) char ldsb[49152];   // 3 buffers x 16384 B

    const int tid = threadIdx.x;
    const int lane = tid & 63;
    const int wv = tid >> 6;

    // XCD-aware bijective swizzle (all grids used here have nwg % 8 == 0)
    const int gx = gridDim.x;
    const int l = blockIdx.y * gx + blockIdx.x;
    const int nwg = gx * gridDim.y;
    const int l2 = (l & 7) * (nwg >> 3) + (l >> 3);
    const int bm = (l2 % gx) * 64;
    const int bn = (l2 / gx) * 128;

    // A staging (hi|lo 128B rows, slot swizzle (row&7)): per-lane constants
    const int j = (lane & 7) ^ (lane >> 3);
    const bool isLo = j >= 4;
    const int koff = (j & 3) * 8;
    const int rsub = lane >> 3;
    const int aR0 = bm + wv * 8 + rsub;
    // B staging (hi-only 64B rows, slot swizzle (row>>1)&3): per-lane constants
    const int brs = lane >> 2;                       // row within 16-row window
    const int j2 = (lane & 3) ^ ((lane >> 3) & 3);   // logical k-chunk
    const int koffB = j2 * 8;

    f32x4 acc[4][2];
#pragma unroll
    for (int m = 0; m < 4; ++m)
#pragma unroll
        for (int n = 0; n < 2; ++n) acc[m][n] = (f32x4)0.0f;

    const int fr = lane & 15;
    const int kc = lane >> 4;

    const int NT = (K1 + K2) >> 5;

#define STAGE(dstp, t) {                                                        \
        const int k0_ = (t) << 5;                                               \
        const bool ph2_ = (k0_ >= K1);                                          \
        const unsigned short* Ab_ = ph2_ ? (isLo ? A2l : A2h)                   \
                                         : (isLo ? A1l : A1h);                  \
        const unsigned short* Wb_ = ph2_ ? W2h : W1h;                           \
        const int lda_ = ph2_ ? lda2 : lda1;                                    \
        const int ldw_ = ph2_ ? ldw2 : ldw1;                                    \
        const int kb_ = ph2_ ? (k0_ - K1) : k0_;                                \
        char* dst_ = (dstp);                                                    \
        gload16(Ab_ + (size_t)aR0 * lda_ + kb_ + koff,        dst_ + (wv    ) * 1024); \
        gload16(Ab_ + (size_t)(aR0 + 32) * lda_ + kb_ + koff, dst_ + (wv + 4) * 1024); \
        gload16(Wb_ + (size_t)(bn + wv * 16 + brs) * ldw_ + kb_ + koffB,        \
                dst_ + 8192 + wv * 1024);                                       \
        gload16(Wb_ + (size_t)(bn + 64 + wv * 16 + brs) * ldw_ + kb_ + koffB,   \
                dst_ + 8192 + 4096 + wv * 1024);                                \
    }

    char* bcur  = ldsb;
    char* bnext = ldsb + 16384;
    char* bfar  = ldsb + 32768;

    STAGE(bcur, 0);
    STAGE(bnext, 1);
    asm volatile("s_waitcnt vmcnt(4)" ::: "memory");
    __builtin_amdgcn_s_barrier();

    for (int t = 0; t < NT; ++t) {
        const bool more = (t + 2 < NT);
        if (more) STAGE(bfar, t + 2);
        {
            f16x8 ah[4], al[4], bh[2];
#pragma unroll
            for (int m = 0; m < 4; ++m) {
                const int row = m * 16 + fr;
                const int sw = (row & 7) << 4;
                char* base = bcur + row * 128;
                ah[m] = *(const f16x8*)(base + ((kc * 16) ^ sw));
                al[m] = *(const f16x8*)(base + (((kc + 4) * 16) ^ sw));
            }
#pragma unroll
            for (int n = 0; n < 2; ++n) {
                const int brow = wv * 32 + n * 16 + fr;
                bh[n] = *(const f16x8*)(bcur + 8192 + brow * 64 +
                                        ((kc ^ ((brow >> 1) & 3)) << 4));
            }
            __builtin_amdgcn_s_setprio(1);
#pragma unroll
            for (int m = 0; m < 4; ++m)
#pragma unroll
                for (int n = 0; n < 2; ++n) {
                    acc[m][n] = __builtin_amdgcn_mfma_f32_16x16x32_f16(ah[m], bh[n], acc[m][n], 0, 0, 0);
                    acc[m][n] = __builtin_amdgcn_mfma_f32_16x16x32_f16(al[m], bh[n], acc[m][n], 0, 0, 0);
                }
            __builtin_amdgcn_s_setprio(0);
        }
        if (more) { asm volatile("s_waitcnt vmcnt(4)" ::: "memory"); }
        else      { asm volatile("s_waitcnt vmcnt(0)" ::: "memory"); }
        __builtin_amdgcn_s_barrier();
        char* tmp = bcur; bcur = bnext; bnext = bfar; bfar = tmp;
    }
#undef STAGE

    if (mode == 4) {
        float* ldsf = (float*)ldsb;
#pragma unroll
        for (int m = 0; m < 4; ++m)
#pragma unroll
            for (int n = 0; n < 2; ++n) {
                f32x4 v4 = acc[m][n];
#pragma unroll
                for (int q = 0; q < 4; ++q) {
                    const int rl = m * 16 + kc * 4 + q;
                    const int cl = wv * 32 + n * 16 + fr;
                    const int col = bn + cl;
                    float v = v4[q];
                    if (b1) v += b1[col];
                    if (Add) v += Add[(size_t)(bm + rl) * ldadd + col];
                    ldsf[rl * 132 + cl] = v;
                }
            }
        __syncthreads();
        const int kb = bn >> 2;
#pragma unroll
        for (int e = 0; e < 8; ++e) {
            const int idx2 = tid * 8 + e;
            const int row = idx2 >> 5, kk = idx2 & 31;
            const float4 g4 = *(const float4*)(ldsf + row * 132 + kk * 4);
            const size_t ci = (((size_t)(bm + row)) << 10) + kb + kk;
            const float si = 1.f / (1.f + expf(-g4.x));
            const float sf = 1.f / (1.f + expf(-g4.y));
            const float so = 1.f / (1.f + expf(-g4.w));
            const float cn = sf * C[ci] + si * tanhf(g4.z);
            const float hn = so * tanhf(cn);
            C[ci] = cn;
            const unsigned short hh = f2h(hn);
            const unsigned short hl = f2h(hn - h2f(hh));
            Chi[ci] = hh; Clo[ci] = hl;
            if (cpyh) { cpyh[ci] = hh; cpyl[ci] = hl; }
        }
        return;
    }

#pragma unroll
    for (int m = 0; m < 4; ++m)
#pragma unroll
        for (int n = 0; n < 2; ++n) {
            f32x4 v4 = acc[m][n];
#pragma unroll
            for (int q = 0; q < 4; ++q) {
                const int rl = m * 16 + kc * 4 + q;
                const int cl = wv * 32 + n * 16 + fr;
                const int r = bm + rl, col = bn + cl;
                float v = v4[q];
                if (b1) v += b1[col];
                if (b2) v += b2[col];
                if (Add) v += Add[(size_t)r * ldadd + col];
                if (mode == 0) {
                    C[(size_t)r * ldc + col] = v;
                } else if (mode == 1) {
                    unsigned short h = f2h(v);
                    Chi[(size_t)r * ldc + col] = h;
                    Clo[(size_t)r * ldc + col] = f2h(v - h2f(h));
                } else if (mode == 2) {
                    const int bb = r & 63, nb = r >> 6;
                    C[(size_t)(((bb * 16 + nb) * 16 + scatter_s)) * 384 + col] = v;
                } else {
                    const int bb = r & 63, nb = (r >> 6) & 15, s = r >> 10;
                    C[(size_t)(((bb * 16 + nb) * 16 + s)) * 384 + col] = v;
                }
            }
        }
}

// ---------------------------------------------------------------------------
// BN=64 variant for M=64 GEMMs (ini + conductor). Buffer 12KB: A 8KB, B 4KB.
// 3 loads/wave, vmcnt(3). modes: 0 (fp32 C + b1) and 4 (fused cell).
__global__ __launch_bounds__(256) void gemm_mfma_n64(
    int M, int N,
    const unsigned short* __restrict__ A1h, const unsigned short* __restrict__ A1l, int K1, int lda1,
    const unsigned short* __restrict__ W1h, int ldw1,
    const unsigned short* __restrict__ A2h, const unsigned short* __restrict__ A2l, int K2, int lda2,
    const unsigned short* __restrict__ W2h, int ldw2,
    const float* __restrict__ b1,
    float* __restrict__ C, int ldc,
    unsigned short* __restrict__ Chi, unsigned short* __restrict__ Clo,
    unsigned short* __restrict__ cpyh, unsigned short* __restrict__ cpyl,
    int mode)
{
    __shared__ __align__(16) char ldsb[36864];   // 3 buffers x 12288 B

    const int tid = threadIdx.x;
    const int lane = tid & 63;
    const int wv = tid >> 6;

    const int gx = gridDim.x;
    const int l = blockIdx.y * gx + blockIdx.x;
    const int nwg = gx * gridDim.y;
    const int l2 = (l & 7) * (nwg >> 3) + (l >> 3);
    const int bm = (l2 % gx) * 64;
    const int bn = (l2 / gx) * 64;

    const int j = (lane & 7) ^ (lane >> 3);
    const bool isLo = j >= 4;
    const int koff = (j & 3) * 8;
    const int rsub = lane >> 3;
    const int aR0 = bm + wv * 8 + rsub;
    const int brs = lane >> 2;
    const int j2 = (lane & 3) ^ ((lane >> 3) & 3);
    const int koffB = j2 * 8;

    f32x4 acc[4];
#pragma unroll
    for (int m = 0; m < 4; ++m) acc[m] = (f32x4)0.0f;

    const int fr = lane & 15;
    const int kc = lane >> 4;

    const int NT = (K1 + K2) >> 5;

#define STAGE64(dstp, t) {                                                      \
        const int k0_ = (t) << 5;                                               \
        const bool ph2_ = (k0_ >= K1);                                          \
        const unsigned short* Ab_ = ph2_ ? (isLo ? A2l : A2h)                   \
                                         : (isLo ? A1l : A1h);                  \
        const unsigned short* Wb_ = ph2_ ? W2h : W1h;                           \
        const int lda_ = ph2_ ? lda2 : lda1;                                    \
        const int ldw_ = ph2_ ? ldw2 : ldw1;                                    \
        const int kb_ = ph2_ ? (k0_ - K1) : k0_;                                \
        char* dst_ = (dstp);                                                    \
        gload16(Ab_ + (size_t)aR0 * lda_ + kb_ + koff,        dst_ + (wv    ) * 1024); \
        gload16(Ab_ + (size_t)(aR0 + 32) * lda_ + kb_ + koff, dst_ + (wv + 4) * 1024); \
        gload16(Wb_ + (size_t)(bn + wv * 16 + brs) * ldw_ + kb_ + koffB,        \
                dst_ + 8192 + wv * 1024);                                       \
    }

    char* bcur  = ldsb;
    char* bnext = ldsb + 12288;
    char* bfar  = ldsb + 24576;

    STAGE64(bcur, 0);
    STAGE64(bnext, 1);
    asm volatile("s_waitcnt vmcnt(3)" ::: "memory");
    __builtin_amdgcn_s_barrier();

    for (int t = 0; t < NT; ++t) {
        const bool more = (t + 2 < NT);
        if (more) STAGE64(bfar, t + 2);
        {
            f16x8 ah[4], al[4], bh;
#pragma unroll
            for (int m = 0; m < 4; ++m) {
                const int row = m * 16 + fr;
                const int sw = (row & 7) << 4;
                char* base = bcur + row * 128;
                ah[m] = *(const f16x8*)(base + ((kc * 16) ^ sw));
                al[m] = *(const f16x8*)(base + (((kc + 4) * 16) ^ sw));
            }
            {
                const int brow = wv * 16 + fr;
                bh = *(const f16x8*)(bcur + 8192 + brow * 64 +
                                     ((kc ^ ((brow >> 1) & 3)) << 4));
            }
            __builtin_amdgcn_s_setprio(1);
#pragma unroll
            for (int m = 0; m < 4; ++m) {
                acc[m] = __builtin_amdgcn_mfma_f32_16x16x32_f16(ah[m], bh, acc[m], 0, 0, 0);
                acc[m] = __builtin_amdgcn_mfma_f32_16x16x32_f16(al[m], bh, acc[m], 0, 0, 0);
            }
            __builtin_amdgcn_s_setprio(0);
        }
        if (more) { asm volatile("s_waitcnt vmcnt(3)" ::: "memory"); }
        else      { asm volatile("s_waitcnt vmcnt(0)" ::: "memory"); }
        __builtin_amdgcn_s_barrier();
        char* tmp = bcur; bcur = bnext; bnext = bfar; bfar = tmp;
    }
#undef STAGE64

    if (mode == 4) {
        float* ldsf = (float*)ldsb;
#pragma unroll
        for (int m = 0; m < 4; ++m) {
            f32x4 v4 = acc[m];
#pragma unroll
            for (int q = 0; q < 4; ++q) {
                const int rl = m * 16 + kc * 4 + q;
                const int cl = wv * 16 + fr;
                float v = v4[q];
                if (b1) v += b1[bn + cl];
                ldsf[rl * 68 + cl] = v;
            }
        }
        __syncthreads();
        const int kb = bn >> 2;
#pragma unroll
        for (int e = 0; e < 4; ++e) {
            const int idx2 = tid * 4 + e;          // 0..1023
            const int row = idx2 >> 4, kk = idx2 & 15;
            const float4 g4 = *(const float4*)(ldsf + row * 68 + kk * 4);
            const size_t ci = (((size_t)(bm + row)) << 10) + kb + kk;
            const float si = 1.f / (1.f + expf(-g4.x));
            const float sf = 1.f / (1.f + expf(-g4.y));
            const float so = 1.f / (1.f + expf(-g4.w));
            const float cn = sf * C[ci] + si * tanhf(g4.z);
            const float hn = so * tanhf(cn);
            C[ci] = cn;
            const unsigned short hh = f2h(hn);
            const unsigned short hl = f2h(hn - h2f(hh));
            Chi[ci] = hh; Clo[ci] = hl;
            if (cpyh) { cpyh[ci] = hh; cpyl[ci] = hl; }
        }
        return;
    }

    // mode 0: fp32 C + b1
#pragma unroll
    for (int m = 0; m < 4; ++m) {
        f32x4 v4 = acc[m];
#pragma unroll
        for (int q = 0; q < 4; ++q) {
            const int rl = m * 16 + kc * 4 + q;
            const int cl = wv * 16 + fr;
            const int r = bm + rl, col = bn + cl;
            float v = v4[q];
            if (b1) v += b1[col];
            C[(size_t)r * ldc + col] = v;
        }
    }
}

// ---------------------------------------------------------------------------
__global__ __launch_bounds__(256) void split_pack(
    const float* __restrict__ src, int ldsrc, int c0, long total, int C,
    unsigned short* __restrict__ hi, unsigned short* __restrict__ lo)
{
    long i = ((long)blockIdx.x * 256 + threadIdx.x) * 4;
    if (i >= total) return;
    int r = (int)(i / C), c = (int)(i % C);
    float4 v = *(const float4*)(src + (size_t)r * ldsrc + c0 + c);
#pragma unroll
    for (int j = 0; j < 4; ++j) {
        float x = (&v.x)[j];
        unsigned short h = f2h(x);
        hi[i + j] = h;
        lo[i + j] = f2h(x - h2f(h));
    }
}

// gate-permuted split: dst row j (0..4095) <- src row (j&3)*1024 + (j>>2)
__global__ __launch_bounds__(256) void split_pack_perm(
    const float* __restrict__ src, int ldsrc, int c0, long total, int C,
    unsigned short* __restrict__ hi, unsigned short* __restrict__ lo)
{
    long i = ((long)blockIdx.x * 256 + threadIdx.x) * 4;
    if (i >= total) return;
    int r = (int)(i / C), c = (int)(i % C);
    int sr = (r & 3) * 1024 + (r >> 2);
    float4 v = *(const float4*)(src + (size_t)sr * ldsrc + c0 + c);
#pragma unroll
    for (int j = 0; j < 4; ++j) {
        float x = (&v.x)[j];
        unsigned short h = f2h(x);
        hi[i + j] = h;
        lo[i + j] = f2h(x - h2f(h));
    }
}

// dst[j] = a[old(j)] + b[old(j)], old(j) = (j&3)*1024 + (j>>2)
__global__ __launch_bounds__(256) void bias_perm(
    const float* __restrict__ a, const float* __restrict__ b, float* __restrict__ dst)
{
    const int j = blockIdx.x * 256 + threadIdx.x;
    if (j >= 4096) return;
    const int o = (j & 3) * 1024 + (j >> 2);
    dst[j] = a[o] + b[o];
}

__global__ __launch_bounds__(256) void scatter_ini_split(
    const float* __restrict__ I, unsigned short* __restrict__ hchi,
    unsigned short* __restrict__ hclo, float* __restrict__ cc)
{
    const int idx = blockIdx.x * blockDim.x + threadIdx.x;
    if (idx >= 131072) return;
    const int k = idx & 1023, b = (idx >> 10) & 63, l = idx >> 16;
    const float* row = I + (size_t)b * 4096;
    float hv = row[(l << 10) + k];
    unsigned short h = f2h(hv);
    hchi[idx] = h; hclo[idx] = f2h(hv - h2f(h));
    cc[idx] = row[2048 + (l << 10) + k];
}

__global__ __launch_bounds__(256) void scatter_di_split(
    const float* __restrict__ D,
    unsigned short* __restrict__ h0h, unsigned short* __restrict__ h0l,
    unsigned short* __restrict__ h1h, unsigned short* __restrict__ h1l,
    float* __restrict__ cd0, float* __restrict__ cd1)
{
    const int idx = blockIdx.x * blockDim.x + threadIdx.x;
    if (idx >= 1048576) return;
    const int k = idx & 1023, r = idx >> 10;
    const float* row = D + ((size_t)r << 12);
    float v0 = row[k], v1 = row[1024 + k];
    unsigned short a = f2h(v0); h0h[idx] = a; h0l[idx] = f2h(v0 - h2f(a));
    unsigned short b = f2h(v1); h1h[idx] = b; h1l[idx] = f2h(v1 - h2f(b));
    cd0[idx] = row[2048 + k];
    cd1[idx] = row[3072 + k];
}

__global__ __launch_bounds__(256) void build_prev_b(
    const int* __restrict__ tp, unsigned short* __restrict__ ph, unsigned short* __restrict__ pl)
{
    const int idx = blockIdx.x * blockDim.x + threadIdx.x;
    if (idx >= 2097152) return;
    const int n = idx & 127;
    const int r = (idx >> 7) & 1023;
    const int s = idx >> 17;
    const int nb = r >> 6, bb = r & 63;
    const int t = nb * 16 + s;
    float v = 0.f;
    if (t > 0) v = (float)tp[(size_t)bb * 32768 + (size_t)(t - 1) * 128 + n];
    ph[idx] = f2h(v);
    pl[idx] = 0;
}

// ===========================================================================
// Fallback fp32 path (proven baseline)
#define BM 64
#define BN 64
#define BK 16

__global__ __launch_bounds__(256) void gemm_f32(
    int M, int N,
    const float* __restrict__ A1, int K1, int lda1,
    const float* __restrict__ W1, int ldw1,
    const float* __restrict__ A2, int K2, int lda2,
    const float* __restrict__ W2, int ldw2,
    const float* __restrict__ Add, int ldadd,
    const float* __restrict__ bias1, const float* __restrict__ bias2,
    float* __restrict__ C, int ldc, int scatter_s)
{
    __shared__ float As[BK][BM];
    __shared__ float Ws[BK][BN];
    const int bm = blockIdx.x * BM;
    const int bn = blockIdx.y * BN;
    const int tid = threadIdx.x;
    const int ty = tid >> 4;
    const int tx = tid & 15;
    const int lr = tid >> 2;
    const int lc = (tid & 3) << 2;

    float acc[4][4] = {{0.f,0.f,0.f,0.f},{0.f,0.f,0.f,0.f},{0.f,0.f,0.f,0.f},{0.f,0.f,0.f,0.f}};

    for (int phase = 0; phase < 2; ++phase) {
        const float* Ap = phase ? A2 : A1;
        const float* Wp = phase ? W2 : W1;
        const int K   = phase ? K2 : K1;
        const int lda = phase ? lda2 : lda1;
        const int ldw = phase ? ldw2 : ldw1;
        if (Ap == nullptr || K <= 0) continue;
        for (int k0 = 0; k0 < K; k0 += BK) {
            float4 av = *(const float4*)(Ap + (size_t)(bm + lr) * lda + k0 + lc);
            float4 wv = *(const float4*)(Wp + (size_t)(bn + lr) * ldw + k0 + lc);
            __syncthreads();
            As[lc+0][lr] = av.x; As[lc+1][lr] = av.y; As[lc+2][lr] = av.z; As[lc+3][lr] = av.w;
            Ws[lc+0][lr] = wv.x; Ws[lc+1][lr] = wv.y; Ws[lc+2][lr] = wv.z; Ws[lc+3][lr] = wv.w;
            __syncthreads();
            #pragma unroll
            for (int k = 0; k < BK; ++k) {
                float4 a = *(const float4*)&As[k][ty << 2];
                float4 w = *(const float4*)&Ws[k][tx << 2];
                acc[0][0] = fmaf(a.x, w.x, acc[0][0]);
                acc[0][1] = fmaf(a.x, w.y, acc[0][1]);
                acc[0][2] = fmaf(a.x, w.z, acc[0][2]);
                acc[0][3] = fmaf(a.x, w.w, acc[0][3]);
                acc[1][0] = fmaf(a.y, w.x, acc[1][0]);
                acc[1][1] = fmaf(a.y, w.y, acc[1][1]);
                acc[1][2] = fmaf(a.y, w.z, acc[1][2]);
                acc[1][3] = fmaf(a.y, w.w, acc[1][3]);
                acc[2][0] = fmaf(a.z, w.x, acc[2][0]);
                acc[2][1] = fmaf(a.z, w.y, acc[2][1]);
                acc[2][2] = fmaf(a.z, w.z, acc[2][2]);
                acc[2][3] = fmaf(a.z, w.w, acc[2][3]);
                acc[3][0] = fmaf(a.w, w.x, acc[3][0]);
                acc[3][1] = fmaf(a.w, w.y, acc[3][1]);
                acc[3][2] = fmaf(a.w, w.z, acc[3][2]);
                acc[3][3] = fmaf(a.w, w.w, acc[3][3]);
            }
        }
    }

    #pragma unroll
    for (int i = 0; i < 4; ++i) {
        const int row = bm + (ty << 2) + i;
        #pragma unroll
        for (int j = 0; j < 4; ++j) {
            const int col = bn + (tx << 2) + j;
            float v = acc[i][j];
            if (bias1) v += bias1[col];
            if (bias2) v += bias2[col];
            if (Add)   v += Add[(size_t)row * ldadd + col];
            if (scatter_s >= 0) {
                const int bb = row & 63, nb = row >> 6;
                C[(size_t)(((bb * 16 + nb) * 16 + scatter_s)) * 384 + col] = v;
            } else {
                C[(size_t)row * ldc + col] = v;
            }
        }
    }
}

__global__ __launch_bounds__(256) void lstm_cell(
    const float* __restrict__ g, float* __restrict__ c,
    float* __restrict__ h, float* __restrict__ hcopy, int M)
{
    const int idx = blockIdx.x * blockDim.x + threadIdx.x;
    if (idx >= (M << 10)) return;
    const int r = idx >> 10, k = idx & 1023;
    const float* gr = g + ((size_t)r << 12);
    const float gi = gr[k], gf = gr[k + 1024], gg = gr[k + 2048], go = gr[k + 3072];
    const float si = 1.f / (1.f + expf(-gi));
    const float sf = 1.f / (1.f + expf(-gf));
    const float so = 1.f / (1.f + expf(-go));
    const float cn = sf * c[idx] + si * tanhf(gg);
    const float hn = so * tanhf(cn);
    c[idx] = cn;
    h[idx] = hn;
    if (hcopy) hcopy[idx] = hn;
}

__global__ __launch_bounds__(256) void scatter_ini(
    const float* __restrict__ I, float* __restrict__ hc, float* __restrict__ cc)
{
    const int idx = blockIdx.x * blockDim.x + threadIdx.x;
    if (idx >= 131072) return;
    const int k = idx & 1023, b = (idx >> 10) & 63, l = idx >> 16;
    const float* row = I + (size_t)b * 4096;
    hc[idx] = row[(l << 10) + k];
    cc[idx] = row[2048 + (l << 10) + k];
}

__global__ __launch_bounds__(256) void scatter_di(
    const float* __restrict__ D, float* __restrict__ hd0, float* __restrict__ cd0,
    float* __restrict__ hd1, float* __restrict__ cd1)
{
    const int idx = blockIdx.x * blockDim.x + threadIdx.x;
    if (idx >= 1048576) return;
    const int k = idx & 1023, r = idx >> 10;
    const float* row = D + ((size_t)r << 12);
    hd0[idx] = row[k];
    hd1[idx] = row[1024 + k];
    cd0[idx] = row[2048 + k];
    cd1[idx] = row[3072 + k];
}

__global__ __launch_bounds__(256) void build_prev(
    const int* __restrict__ tp, float* __restrict__ prevf)
{
    const int idx = blockIdx.x * blockDim.x + threadIdx.x;
    if (idx >= 2097152) return;
    const int n = idx & 127;
    const int r = (idx >> 7) & 1023;
    const int s = idx >> 17;
    const int nb = r >> 6, bb = r & 63;
    const int t = nb * 16 + s;
    float v = 0.f;
    if (t > 0) v = (float)tp[(size_t)bb * 32768 + (size_t)(t - 1) * 128 + n];
    prevf[idx] = v;
}

// ===========================================================================
extern "C" void kernel_launch(void* const* d_in, const int* in_sizes, int n_in,
                              void* d_out, int out_size, void* d_ws, size_t ws_size,
                              hipStream_t stream)
{
    (void)in_sizes; (void)n_in; (void)out_size;
    const float* z      = (const float*)d_in[0];
    const int*   tp     = (const int*)  d_in[1];
    const float* w_zc   = (const float*)d_in[2];
    const float* b_zc   = (const float*)d_in[3];
    const float* c_whh0 = (const float*)d_in[5];
    const float* c_bih0 = (const float*)d_in[6];
    const float* c_bhh0 = (const float*)d_in[7];
    const float* c_wih1 = (const float*)d_in[8];
    const float* c_whh1 = (const float*)d_in[9];
    const float* c_bih1 = (const float*)d_in[10];
    const float* c_bhh1 = (const float*)d_in[11];
    const float* np_w   = (const float*)d_in[12];
    const float* np_b   = (const float*)d_in[13];
    const float* cd_w   = (const float*)d_in[14];
    const float* cd_b   = (const float*)d_in[15];
    const float* d_wih0 = (const float*)d_in[16];
    const float* d_whh0 = (const float*)d_in[17];
    const float* d_bih0 = (const float*)d_in[18];
    const float* d_bhh0 = (const float*)d_in[19];
    const float* d_wih1 = (const float*)d_in[20];
    const float* d_whh1 = (const float*)d_in[21];
    const float* d_bih1 = (const float*)d_in[22];
    const float* d_bhh1 = (const float*)d_in[23];
    const float* op_w   = (const float*)d_in[24];
    const float* op_b   = (const float*)d_in[25];
    float* out = (float*)d_out;

    // ---- workspace layout for MFMA path (bytes) ----
    size_t o = 0;
    auto alloc = [&](size_t bytes) { size_t r = o; o = (o + bytes + 255) & ~(size_t)255; return r; };
    const size_t oCW0 = alloc((size_t)4096*1024*4);
    const size_t oCW1 = alloc((size_t)4096*1024*4);
    const size_t oCW2 = alloc((size_t)4096*1024*4);
    const size_t oWZC = alloc((size_t)4096*512*4);     // later reused: D0E + OPW
    const size_t oNPW = alloc((size_t)128*128*4);
    const size_t oZS  = alloc((size_t)64*512*4);
    const size_t oCDW = alloc((size_t)4096*1024*4);
    const size_t oD0R = alloc((size_t)4096*1024*4);
    const size_t oCG  = alloc((size_t)64*4096*4);
    const size_t oCC  = alloc((size_t)2*64*1024*4);
    const size_t oHCa = alloc((size_t)2*64*1024*4);    // h ping (hi[2][64][1024], lo)
    const size_t oHCb = alloc((size_t)2*64*1024*4);    // h pong
    const size_t oCND = alloc((size_t)1024*1024*4);
    const size_t oEMB = alloc((size_t)16*1024*128*4);
    const size_t oBRP = alloc((size_t)1024*4096*4);
    const size_t oDG  = alloc((size_t)1024*4096*4);    // PRV aliases this
    const size_t oHD0a= alloc((size_t)1024*1024*4);
    const size_t oHD0b= alloc((size_t)1024*1024*4);
    const size_t oHD1a= alloc((size_t)1024*1024*4);
    const size_t oHD1b= alloc((size_t)1024*1024*4);
    const size_t oCD0 = alloc((size_t)1024*1024*4);
    const size_t oCD1 = alloc((size_t)1024*1024*4);
    const size_t oBS  = alloc((size_t)4*4096*4);
    const size_t need = o;
    const size_t oH1S = alloc((size_t)16*1024*1024*4);
    const size_t need_batched = o;

    if (ws_size >= need) {
        const bool batched = (ws_size >= need_batched);
        char* ws = (char*)d_ws;
        unsigned short* CW0 = (unsigned short*)(ws + oCW0);
        unsigned short* CW1 = (unsigned short*)(ws + oCW1);
        unsigned short* CW2 = (unsigned short*)(ws + oCW2);
        unsigned short* WZC = (unsigned short*)(ws + oWZC);
        unsigned short* NPW = (unsigned short*)(ws + oNPW);
        unsigned short* ZS  = (unsigned short*)(ws + oZS);
        unsigned short* CDW = (unsigned short*)(ws + oCDW);
        unsigned short* D0R = (unsigned short*)(ws + oD0R);
        float* CG  = (float*)(ws + oCG);
        float* CC  = (float*)(ws + oCC);
        unsigned short* HCa = (unsigned short*)(ws + oHCa);
        unsigned short* HCb = (unsigned short*)(ws + oHCb);
        unsigned short* CND = (unsigned short*)(ws + oCND);
        unsigned short* PRV = (unsigned short*)(ws + oDG);   // alias: dead before DG live
        unsigned short* EMB = (unsigned short*)(ws + oEMB);
        float* BRP = (float*)(ws + oBRP);
        float* DG  = (float*)(ws + oDG);
        unsigned short* HD0a = (unsigned short*)(ws + oHD0a);
        unsigned short* HD0b = (unsigned short*)(ws + oHD0b);
        unsigned short* HD1a = (unsigned short*)(ws + oHD1a);
        unsigned short* HD1b = (unsigned short*)(ws + oHD1b);
        float* CD0 = (float*)(ws + oCD0);
        float* CD1 = (float*)(ws + oCD1);
        float* BSC0 = (float*)(ws + oBS);
        float* BSC1 = BSC0 + 4096;
        float* BSB0 = BSC1 + 4096;
        float* BSD1 = BSB0 + 4096;
        unsigned short* H1S  = (unsigned short*)(ws + oH1S);
        unsigned short* H1Sl = H1S + (size_t)16*1048576;
        unsigned short* DWHH0 = CW0;      // aliases, filled after conductor
        unsigned short* DWIH1 = CW1;
        unsigned short* DWHH1 = CW2;
        unsigned short* D0E   = WZC;
        unsigned short* OPW   = WZC + (size_t)2*4096*128;

        auto split = [&](const float* src, int ldsrc, int c0, long R, long C, unsigned short* dst) {
            long total = R * C;
            split_pack<<<(unsigned)((total/4 + 255) / 256), 256, 0, stream>>>(
                src, ldsrc, c0, total, (int)C, dst, dst + total);
        };
        auto splitP = [&](const float* src, int ldsrc, int c0, long C, unsigned short* dst) {
            long total = 4096 * C;
            split_pack_perm<<<(unsigned)((total/4 + 255) / 256), 256, 0, stream>>>(
                src, ldsrc, c0, total, (int)C, dst, dst + total);
        };
        auto gemm2 = [&](int M, int N,
                         const unsigned short* A1h, const unsigned short* A1l, int K1, int lda1,
                         const unsigned short* W1, int ldw1,
                         const unsigned short* A2h, const unsigned short* A2l, int K2, int lda2,
                         const unsigned short* W2, int ldw2,
                         const float* Addp, int ldadd, const float* bb1, const float* bb2,
                         float* Cp, int ldc, unsigned short* Chi, unsigned short* Clo,
                         unsigned short* cpyh, unsigned short* cpyl,
                         int mode, int ss) {
            dim3 grid(M / 64, N / 128);
            gemm_mfma<<<grid, 256, 0, stream>>>(M, N, A1h, A1l, K1, lda1, W1, ldw1,
                                                A2h, A2l, K2, lda2, W2, ldw2,
                                                Addp, ldadd, bb1, bb2, Cp, ldc, Chi, Clo,
                                                cpyh, cpyl, mode, ss);
        };
        auto gemmN64 = [&](int M, int N,
                           const unsigned short* A1h, const unsigned short* A1l, int K1, int lda1,
                           const unsigned short* W1, int ldw1,
                           const unsigned short* A2h, const unsigned short* A2l, int K2, int lda2,
                           const unsigned short* W2, int ldw2,
                           const float* bb1, float* Cp, int ldc,
                           unsigned short* Chi, unsigned short* Clo,
                           unsigned short* cpyh, unsigned short* cpyl, int mode) {
            dim3 grid(M / 64, N / 64);
            gemm_mfma_n64<<<grid, 256, 0, stream>>>(M, N, A1h, A1l, K1, lda1, W1, ldw1,
                                                    A2h, A2l, K2, lda2, W2, ldw2,
                                                    bb1, Cp, ldc, Chi, Clo, cpyh, cpyl, mode);
        };

        // h-state pointer helpers (hi at base, lo at +count)
        auto hc0h = [&](int b){ return (b ? HCb : HCa); };
        auto hc0l = [&](int b){ return (b ? HCb : HCa) + 131072; };
        auto hc1h = [&](int b){ return (b ? HCb : HCa) + 65536; };
        auto hc1l = [&](int b){ return (b ? HCb : HCa) + 131072 + 65536; };
        auto hd0h = [&](int b){ return (b ? HD0b : HD0a); };
        auto hd0l = [&](int b){ return (b ? HD0b : HD0a) + 1048576; };
        auto hd1h = [&](int b){ return (b ? HD1b : HD1a); };
        auto hd1l = [&](int b){ return (b ? HD1b : HD1a) + 1048576; };

        // 0) conversions (conductor weights gate-permuted) + permuted bias sums
        split(z, 512, 0, 64, 512, ZS);
        split(w_zc, 512, 0, 4096, 512, WZC);
        splitP(c_whh0, 1024, 0, 1024, CW0);
        splitP(c_wih1, 1024, 0, 1024, CW1);
        splitP(c_whh1, 1024, 0, 1024, CW2);
        split(np_w, 128, 0, 128, 128, NPW);
        split(cd_w, 1024, 0, 4096, 1024, CDW);
        splitP(d_wih0, 1152, 128, 1024, D0R);
        bias_perm<<<16, 256, 0, stream>>>(c_bih0, c_bhh0, BSC0);
        bias_perm<<<16, 256, 0, stream>>>(c_bih1, c_bhh1, BSC1);
        bias_perm<<<16, 256, 0, stream>>>(d_bih0, d_bhh0, BSB0);
        bias_perm<<<16, 256, 0, stream>>>(d_bih1, d_bhh1, BSD1);
        build_prev_b<<<8192, 256, 0, stream>>>(tp, PRV, PRV + 2097152);

        // 1) ini = z @ w_zc.T + b_zc -> CG -> split-scatter into HCa (ping 0)
        gemmN64(64, 4096, ZS, ZS + 32768, 512, 512, WZC, 512,
                nullptr, nullptr, 0, 0, nullptr, 0,
                b_zc, CG, 4096, nullptr, nullptr, nullptr, nullptr, 0);
        scatter_ini_split<<<512, 256, 0, stream>>>(CG, HCa, HCa + 131072, CC);

        // 2) emb = prev @ np_w.T + np_b (split out); PRV aliases DG
        gemm2(16384, 128, PRV, PRV + 2097152, 128, 128, NPW, 128,
              nullptr, nullptr, 0, 0, nullptr, 0,
              nullptr, 0, np_b, nullptr, nullptr, 128, EMB, EMB + 2097152, nullptr, nullptr, 1, -1);

        // 3) conductor: fused-cell N64 GEMMs, h ping-pong
        for (int t = 0; t < 16; ++t) {
            const int p = t & 1;
            gemmN64(64, 4096, hc0h(p), hc0l(p), 1024, 1024, CW0, 1024,
                    nullptr, nullptr, 0, 0, nullptr, 0,
                    BSC0, CC, 0, hc0h(p ^ 1), hc0l(p ^ 1), nullptr, nullptr, 4);
            gemmN64(64, 4096, hc0h(p ^ 1), hc0l(p ^ 1), 1024, 1024, CW1, 1024,
                    hc1h(p), hc1l(p), 1024, 1024, CW2, 1024,
                    BSC1, CC + 65536, 0, hc1h(p ^ 1), hc1l(p ^ 1),
                    CND + t * 65536, CND + 1048576 + t * 65536, 4);
        }

        // 4) decoder weights (aliases, stream-ordered after conductor)
        splitP(d_whh0, 1024, 0, 1024, DWHH0);
        splitP(d_wih1, 1024, 0, 1024, DWIH1);
        splitP(d_whh1, 1024, 0, 1024, DWHH1);
        splitP(d_wih0, 1152, 0, 128, D0E);
        split(op_w, 1024, 0, 384, 1024, OPW);

        // 5) di = cond @ cd_w.T + cd_b -> DG -> split scatter into ping 0
        gemm2(1024, 4096, CND, CND + 1048576, 1024, 1024, CDW, 1024,
              nullptr, nullptr, 0, 0, nullptr, 0,
              nullptr, 0, cd_b, nullptr, DG, 4096, nullptr, nullptr, nullptr, nullptr, 0, -1);
        scatter_di_split<<<4096, 256, 0, stream>>>(DG, HD0a, HD0a + 1048576,
                                                   HD1a, HD1a + 1048576, CD0, CD1);

        // 6) barpart = cond @ d_wih0[:,128:].T + (bih0+bhh0), permuted cols
        gemm2(1024, 4096, CND, CND + 1048576, 1024, 1024, D0R, 1024,
              nullptr, nullptr, 0, 0, nullptr, 0,
              nullptr, 0, BSB0, nullptr, BRP, 4096, nullptr, nullptr, nullptr, nullptr, 0, -1);

        // 7) decoder: fused-cell GEMMs, h ping-pong
        for (int s = 0; s < 16; ++s) {
            const int p = s & 1;
            gemm2(1024, 4096, EMB + (size_t)s * 131072, EMB + 2097152 + (size_t)s * 131072, 128, 128,
                  D0E, 128,
                  hd0h(p), hd0l(p), 1024, 1024, DWHH0, 1024,
                  BRP, 4096, nullptr, nullptr, CD0, 0, hd0h(p ^ 1), hd0l(p ^ 1),
                  nullptr, nullptr, 4, -1);
            gemm2(1024, 4096, hd0h(p ^ 1), hd0l(p ^ 1), 1024, 1024, DWIH1, 1024,
                  hd1h(p), hd1l(p), 1024, 1024, DWHH1, 1024,
                  nullptr, 0, BSD1, nullptr, CD1, 0, hd1h(p ^ 1), hd1l(p ^ 1),
                  batched ? H1S + (size_t)s * 1048576 : nullptr,
                  batched ? H1Sl + (size_t)s * 1048576 : nullptr, 4, -1);
            if (!batched) {
                gemm2(1024, 384, hd1h(p ^ 1), hd1l(p ^ 1), 1024, 1024, OPW, 1024,
                      nullptr, nullptr, 0, 0, nullptr, 0,
                      nullptr, 0, op_b, nullptr, out, 384, nullptr, nullptr, nullptr, nullptr, 2, s);
            }
        }
        if (batched) {
            gemm2(16384, 384, H1S, H1Sl, 1024, 1024, OPW, 1024,
                  nullptr, nullptr, 0, 0, nullptr, 0,
                  nullptr, 0, op_b, nullptr, out, 384, nullptr, nullptr, nullptr, nullptr, 3, -1);
        }
        return;
    }

    // ================= fallback: proven fp32 path =================
    float* wsf     = (float*)d_ws;
    float* hc      = wsf;
    float* cc      = hc + 131072;
    float* cond    = cc + 131072;
    float* cg      = cond + 1048576;
    float* barpart = cg + 262144;
    float* emb     = barpart + 4194304;
    float* prevf   = emb + 2097152;
    float* hd0     = prevf + 2097152;
    float* cd0     = hd0 + 1048576;
    float* hd1     = cd0 + 1048576;
    float* cd1     = hd1 + 1048576;
    float* dg      = cd1 + 1048576;

    auto gemmf = [&](int M, int N,
                     const float* A1, int K1, int lda1, const float* W1, int ldw1,
                     const float* A2, int K2, int lda2, const float* W2, int ldw2,
                     const float* Addp, int ldadd, const float* bb1, const float* bb2,
                     float* Cp, int ldc, int ss) {
        dim3 grid(M / BM, N / BN);
        gemm_f32<<<grid, dim3(256), 0, stream>>>(M, N, A1, K1, lda1, W1, ldw1,
                                                 A2, K2, lda2, W2, ldw2,
                                                 Addp, ldadd, bb1, bb2, Cp, ldc, ss);
    };

    gemmf(64, 4096, z, 512, 512, w_zc, 512, nullptr, 0, 0, nullptr, 0,
          nullptr, 0, b_zc, nullptr, cg, 4096, -1);
    scatter_ini<<<512, 256, 0, stream>>>(cg, hc, cc);

    build_prev<<<8192, 256, 0, stream>>>(tp, prevf);
    gemmf(16384, 128, prevf, 128, 128, np_w, 128, nullptr, 0, 0, nullptr, 0,
          nullptr, 0, np_b, nullptr, emb, 128, -1);

    for (int t = 0; t < 16; ++t) {
        gemmf(64, 4096, hc, 1024, 1024, c_whh0, 1024, nullptr, 0, 0, nullptr, 0,
              nullptr, 0, c_bih0, c_bhh0, cg, 4096, -1);
        lstm_cell<<<256, 256, 0, stream>>>(cg, cc, hc, nullptr, 64);
        gemmf(64, 4096, hc, 1024, 1024, c_wih1, 1024,
              hc + 65536, 1024, 1024, c_whh1, 1024,
              nullptr, 0, c_bih1, c_bhh1, cg, 4096, -1);
        lstm_cell<<<256, 256, 0, stream>>>(cg, cc + 65536, hc + 65536, cond + t * 65536, 64);
    }

    gemmf(1024, 4096, cond, 1024, 1024, cd_w, 1024, nullptr, 0, 0, nullptr, 0,
          nullptr, 0, cd_b, nullptr, dg, 4096, -1);
    scatter_di<<<4096, 256, 0, stream>>>(dg, hd0, cd0, hd1, cd1);

    gemmf(1024, 4096, cond, 1024, 1024, d_wih0 + 128, 1152, nullptr, 0, 0, nullptr, 0,
          nullptr, 0, d_bih0, d_bhh0, barpart, 4096, -1);

    for (int s = 0; s < 16; ++s) {
        gemmf(1024, 4096, emb + (size_t)s * 131072, 128, 128, d_wih0, 1152,
              hd0, 1024, 1024, d_whh0, 1024,
              barpart, 4096, nullptr, nullptr, dg, 4096, -1);
        lstm_cell<<<4096, 256, 0, stream>>>(dg, cd0, hd0, nullptr, 1024);
        gemmf(1024, 4096, hd0, 1024, 1024, d_wih1, 1024,
              hd1, 1024, 1024, d_whh1, 1024,
              nullptr, 0, d_bih1, d_bhh1, dg, 4096, -1);
        lstm_cell<<<4096, 256, 0, stream>>>(dg, cd1, hd1, nullptr, 1024);
        gemmf(1024, 384, hd1, 1024, 1024, op_w, 1024, nullptr, 0, 0, nullptr, 0,
              nullptr, 0, op_b, nullptr, out, 384, s);
    }
}

// Round 19
// 2436.629 us; speedup vs baseline: 1.4186x; 1.0042x over previous
//
#include <hip/hip_runtime.h>
#include <math.h>

// B=64, LAT=512, HC=HD=1024, NB=16, S=16, E=128, NOTES=128, OUT=384, L=2
// Round 19: 2x2 wave arrangement in decoder gemm_mfma (each wave 32 rows x
// 64 cols): LDS frag reads 10 -> 8 per wave per K-iter (-20%). fp16 2-term
// split (A ~= Ah+Al, W ~= Wh) as round 18. Per-output MFMA order unchanged.

typedef __attribute__((ext_vector_type(8))) short s16x8;
typedef __attribute__((ext_vector_type(8))) _Float16 f16x8;
typedef __attribute__((ext_vector_type(4))) float f32x4;

__device__ inline unsigned short f2h(float f) {
    _Float16 h = (_Float16)f;
    return __builtin_bit_cast(unsigned short, h);
}
__device__ inline float h2f(unsigned short u) {
    _Float16 h = __builtin_bit_cast(_Float16, u);
    return (float)h;
}

// async global->LDS, 16B per lane; LDS dest = wave-uniform base + lane*16
__device__ __forceinline__ void gload16(const unsigned short* g, char* l) {
    const unsigned int* gu = (const unsigned int*)g;
    unsigned int* lu = (unsigned int*)l;
    __builtin_amdgcn_global_load_lds(
        (const __attribute__((address_space(1))) unsigned int*)gu,
        (__attribute__((address_space(3))) unsigned int*)lu, 16, 0, 0);
}

// ---------------------------------------------------------------------------
// 64x128 tile, BK=32, 256 thr = 4 waves in 2x2 (wave tile 32 rows x 64 cols).
// 3-buffer pipeline, counted vmcnt(4). LDS buffer 16KB: A 64x128B at 0 (hi|lo),
// B 128x64B (hi) at 8192.
// mode: 0 = fp32 C; 1 = split store Chi/Clo; 2 = per-step decoder scatter;
//       3 = batched-proj scatter; 4 = fused LSTM cell (gate-interleaved cols).
__global__ __launch_bounds__(256) void gemm_mfma(
    int M, int N,
    const unsigned short* __restrict__ A1h, const unsigned short* __restrict__ A1l, int K1, int lda1,
    const unsigned short* __restrict__ W1h, int ldw1,
    const unsigned short* __restrict__ A2h, const unsigned short* __restrict__ A2l, int K2, int lda2,
    const unsigned short* __restrict__ W2h, int ldw2,
    const float* __restrict__ Add, int ldadd,
    const float* __restrict__ b1, const float* __restrict__ b2,
    float* __restrict__ C, int ldc,
    unsigned short* __restrict__ Chi, unsigned short* __restrict__ Clo,
    unsigned short* __restrict__ cpyh, unsigned short* __restrict__ cpyl,
    int mode, int scatter_s)
{
    __shared__ __align__(16) char ldsb[49152];   // 3 buffers x 16384 B

    const int tid = threadIdx.x;
    const int lane = tid & 63;
    const int wv = tid >> 6;
    const int wm = wv >> 1;          // wave row-half 0/1 (rows wm*32..+32)
    const int wn = wv & 1;           // wave col-half 0/1 (cols wn*64..+64)

    // XCD-aware bijective swizzle (all grids used here have nwg % 8 == 0)
    const int gx = gridDim.x;
    const int l = blockIdx.y * gx + blockIdx.x;
    const int nwg = gx * gridDim.y;
    const int l2 = (l & 7) * (nwg >> 3) + (l >> 3);
    const int bm = (l2 % gx) * 64;
    const int bn = (l2 / gx) * 128;

    // A staging (hi|lo 128B rows, slot swizzle (row&7)): per-lane constants
    const int j = (lane & 7) ^ (lane >> 3);
    const bool isLo = j >= 4;
    const int koff = (j & 3) * 8;
    const int rsub = lane >> 3;
    const int aR0 = bm + wv * 8 + rsub;
    // B staging (hi-only 64B rows, slot swizzle (row>>1)&3): per-lane constants
    const int brs = lane >> 2;                       // row within 16-row window
    const int j2 = (lane & 3) ^ ((lane >> 3) & 3);   // logical k-chunk
    const int koffB = j2 * 8;

    f32x4 acc[2][4];
#pragma unroll
    for (int m = 0; m < 2; ++m)
#pragma unroll
        for (int n = 0; n < 4; ++n) acc[m][n] = (f32x4)0.0f;

    const int fr = lane & 15;
    const int kc = lane >> 4;

    const int NT = (K1 + K2) >> 5;

#define STAGE(dstp, t) {                                                        \
        const int k0_ = (t) << 5;                                               \
        const bool ph2_ = (k0_ >= K1);                                          \
        const unsigned short* Ab_ = ph2_ ? (isLo ? A2l : A2h)                   \
                                         : (isLo ? A1l : A1h);                  \
        const unsigned short* Wb_ = ph2_ ? W2h : W1h;                           \
        const int lda_ = ph2_ ? lda2 : lda1;                                    \
        const int ldw_ = ph2_ ? ldw2 : ldw1;                                    \
        const int kb_ = ph2_ ? (k0_ - K1) : k0_;                                \
        char* dst_ = (dstp);                                                    \
        gload16(Ab_ + (size_t)aR0 * lda_ + kb_ + koff,        dst_ + (wv    ) * 1024); \
        gload16(Ab_ + (size_t)(aR0 + 32) * lda_ + kb_ + koff, dst_ + (wv + 4) * 1024); \
        gload16(Wb_ + (size_t)(bn + wv * 16 + brs) * ldw_ + kb_ + koffB,        \
                dst_ + 8192 + wv * 1024);                                       \
        gload16(Wb_ + (size_t)(bn + 64 + wv * 16 + brs) * ldw_ + kb_ + koffB,   \
                dst_ + 8192 + 4096 + wv * 1024);                                \
    }

    char* bcur  = ldsb;
    char* bnext = ldsb + 16384;
    char* bfar  = ldsb + 32768;

    STAGE(bcur, 0);
    STAGE(bnext, 1);
    asm volatile("s_waitcnt vmcnt(4)" ::: "memory");
    __builtin_amdgcn_s_barrier();

    for (int t = 0; t < NT; ++t) {
        const bool more = (t + 2 < NT);
        if (more) STAGE(bfar, t + 2);
        {
            f16x8 ah[2], al[2], bh[4];
#pragma unroll
            for (int m = 0; m < 2; ++m) {
                const int row = wm * 32 + m * 16 + fr;
                const int sw = (row & 7) << 4;
                char* base = bcur + row * 128;
                ah[m] = *(const f16x8*)(base + ((kc * 16) ^ sw));
                al[m] = *(const f16x8*)(base + (((kc + 4) * 16) ^ sw));
            }
#pragma unroll
            for (int n = 0; n < 4; ++n) {
                const int brow = wn * 64 + n * 16 + fr;
                bh[n] = *(const f16x8*)(bcur + 8192 + brow * 64 +
                                        ((kc ^ ((brow >> 1) & 3)) << 4));
            }
            __builtin_amdgcn_s_setprio(1);
#pragma unroll
            for (int m = 0; m < 2; ++m)
#pragma unroll
                for (int n = 0; n < 4; ++n) {
                    acc[m][n] = __builtin_amdgcn_mfma_f32_16x16x32_f16(ah[m], bh[n], acc[m][n], 0, 0, 0);
                    acc[m][n] = __builtin_amdgcn_mfma_f32_16x16x32_f16(al[m], bh[n], acc[m][n], 0, 0, 0);
                }
            __builtin_amdgcn_s_setprio(0);
        }
        if (more) { asm volatile("s_waitcnt vmcnt(4)" ::: "memory"); }
        else      { asm volatile("s_waitcnt vmcnt(0)" ::: "memory"); }
        __builtin_amdgcn_s_barrier();
        char* tmp = bcur; bcur = bnext; bnext = bfar; bfar = tmp;
    }
#undef STAGE

    if (mode == 4) {
        float* ldsf = (float*)ldsb;
#pragma unroll
        for (int m = 0; m < 2; ++m)
#pragma unroll
            for (int n = 0; n < 4; ++n) {
                f32x4 v4 = acc[m][n];
#pragma unroll
                for (int q = 0; q < 4; ++q) {
                    const int rl = wm * 32 + m * 16 + kc * 4 + q;
                    const int cl = wn * 64 + n * 16 + fr;
                    const int col = bn + cl;
                    float v = v4[q];
                    if (b1) v += b1[col];
                    if (Add) v += Add[(size_t)(bm + rl) * ldadd + col];
                    ldsf[rl * 132 + cl] = v;
                }
            }
        __syncthreads();
        const int kb = bn >> 2;
#pragma unroll
        for (int e = 0; e < 8; ++e) {
            const int idx2 = tid * 8 + e;
            const int row = idx2 >> 5, kk = idx2 & 31;
            const float4 g4 = *(const float4*)(ldsf + row * 132 + kk * 4);
            const size_t ci = (((size_t)(bm + row)) << 10) + kb + kk;
            const float si = 1.f / (1.f + expf(-g4.x));
            const float sf = 1.f / (1.f + expf(-g4.y));
            const float so = 1.f / (1.f + expf(-g4.w));
            const float cn = sf * C[ci] + si * tanhf(g4.z);
            const float hn = so * tanhf(cn);
            C[ci] = cn;
            const unsigned short hh = f2h(hn);
            const unsigned short hl = f2h(hn - h2f(hh));
            Chi[ci] = hh; Clo[ci] = hl;
            if (cpyh) { cpyh[ci] = hh; cpyl[ci] = hl; }
        }
        return;
    }

#pragma unroll
    for (int m = 0; m < 2; ++m)
#pragma unroll
        for (int n = 0; n < 4; ++n) {
            f32x4 v4 = acc[m][n];
#pragma unroll
            for (int q = 0; q < 4; ++q) {
                const int rl = wm * 32 + m * 16 + kc * 4 + q;
                const int cl = wn * 64 + n * 16 + fr;
                const int r = bm + rl, col = bn + cl;
                float v = v4[q];
                if (b1) v += b1[col];
                if (b2) v += b2[col];
                if (Add) v += Add[(size_t)r * ldadd + col];
                if (mode == 0) {
                    C[(size_t)r * ldc + col] = v;
                } else if (mode == 1) {
                    unsigned short h = f2h(v);
                    Chi[(size_t)r * ldc + col] = h;
                    Clo[(size_t)r * ldc + col] = f2h(v - h2f(h));
                } else if (mode == 2) {
                    const int bb = r & 63, nb = r >> 6;
                    C[(size_t)(((bb * 16 + nb) * 16 + scatter_s)) * 384 + col] = v;
                } else {
                    const int bb = r & 63, nb = (r >> 6) & 15, s = r >> 10;
                    C[(size_t)(((bb * 16 + nb) * 16 + s)) * 384 + col] = v;
                }
            }
        }
}

// ---------------------------------------------------------------------------
// BN=64 variant for M=64 GEMMs (ini + conductor). Buffer 12KB: A 8KB, B 4KB.
// 3 loads/wave, vmcnt(3). modes: 0 (fp32 C + b1) and 4 (fused cell).
__global__ __launch_bounds__(256) void gemm_mfma_n64(
    int M, int N,
    const unsigned short* __restrict__ A1h, const unsigned short* __restrict__ A1l, int K1, int lda1,
    const unsigned short* __restrict__ W1h, int ldw1,
    const unsigned short* __restrict__ A2h, const unsigned short* __restrict__ A2l, int K2, int lda2,
    const unsigned short* __restrict__ W2h, int ldw2,
    const float* __restrict__ b1,
    float* __restrict__ C, int ldc,
    unsigned short* __restrict__ Chi, unsigned short* __restrict__ Clo,
    unsigned short* __restrict__ cpyh, unsigned short* __restrict__ cpyl,
    int mode)
{
    __shared__ __align__(16) char ldsb[36864];   // 3 buffers x 12288 B

    const int tid = threadIdx.x;
    const int lane = tid & 63;
    const int wv = tid >> 6;

    const int gx = gridDim.x;
    const int l = blockIdx.y * gx + blockIdx.x;
    const int nwg = gx * gridDim.y;
    const int l2 = (l & 7) * (nwg >> 3) + (l >> 3);
    const int bm = (l2 % gx) * 64;
    const int bn = (l2 / gx) * 64;

    const int j = (lane & 7) ^ (lane >> 3);
    const bool isLo = j >= 4;
    const int koff = (j & 3) * 8;
    const int rsub = lane >> 3;
    const int aR0 = bm + wv * 8 + rsub;
    const int brs = lane >> 2;
    const int j2 = (lane & 3) ^ ((lane >> 3) & 3);
    const int koffB = j2 * 8;

    f32x4 acc[4];
#pragma unroll
    for (int m = 0; m < 4; ++m) acc[m] = (f32x4)0.0f;

    const int fr = lane & 15;
    const int kc = lane >> 4;

    const int NT = (K1 + K2) >> 5;

#define STAGE64(dstp, t) {                                                      \
        const int k0_ = (t) << 5;                                               \
        const bool ph2_ = (k0_ >= K1);                                          \
        const unsigned short* Ab_ = ph2_ ? (isLo ? A2l : A2h)                   \
                                         : (isLo ? A1l : A1h);                  \
        const unsigned short* Wb_ = ph2_ ? W2h : W1h;                           \
        const int lda_ = ph2_ ? lda2 : lda1;                                    \
        const int ldw_ = ph2_ ? ldw2 : ldw1;                                    \
        const int kb_ = ph2_ ? (k0_ - K1) : k0_;                                \
        char* dst_ = (dstp);                                                    \
        gload16(Ab_ + (size_t)aR0 * lda_ + kb_ + koff,        dst_ + (wv    ) * 1024); \
        gload16(Ab_ + (size_t)(aR0 + 32) * lda_ + kb_ + koff, dst_ + (wv + 4) * 1024); \
        gload16(Wb_ + (size_t)(bn + wv * 16 + brs) * ldw_ + kb_ + koffB,        \
                dst_ + 8192 + wv * 1024);                                       \
    }

    char* bcur  = ldsb;
    char* bnext = ldsb + 12288;
    char* bfar  = ldsb + 24576;

    STAGE64(bcur, 0);
    STAGE64(bnext, 1);
    asm volatile("s_waitcnt vmcnt(3)" ::: "memory");
    __builtin_amdgcn_s_barrier();

    for (int t = 0; t < NT; ++t) {
        const bool more = (t + 2 < NT);
        if (more) STAGE64(bfar, t + 2);
        {
            f16x8 ah[4], al[4], bh;
#pragma unroll
            for (int m = 0; m < 4; ++m) {
                const int row = m * 16 + fr;
                const int sw = (row & 7) << 4;
                char* base = bcur + row * 128;
                ah[m] = *(const f16x8*)(base + ((kc * 16) ^ sw));
                al[m] = *(const f16x8*)(base + (((kc + 4) * 16) ^ sw));
            }
            {
                const int brow = wv * 16 + fr;
                bh = *(const f16x8*)(bcur + 8192 + brow * 64 +
                                     ((kc ^ ((brow >> 1) & 3)) << 4));
            }
            __builtin_amdgcn_s_setprio(1);
#pragma unroll
            for (int m = 0; m < 4; ++m) {
                acc[m] = __builtin_amdgcn_mfma_f32_16x16x32_f16(ah[m], bh, acc[m], 0, 0, 0);
                acc[m] = __builtin_amdgcn_mfma_f32_16x16x32_f16(al[m], bh, acc[m], 0, 0, 0);
            }
            __builtin_amdgcn_s_setprio(0);
        }
        if (more) { asm volatile("s_waitcnt vmcnt(3)" ::: "memory"); }
        else      { asm volatile("s_waitcnt vmcnt(0)" ::: "memory"); }
        __builtin_amdgcn_s_barrier();
        char* tmp = bcur; bcur = bnext; bnext = bfar; bfar = tmp;
    }
#undef STAGE64

    if (mode == 4) {
        float* ldsf = (float*)ldsb;
#pragma unroll
        for (int m = 0; m < 4; ++m) {
            f32x4 v4 = acc[m];
#pragma unroll
            for (int q = 0; q < 4; ++q) {
                const int rl = m * 16 + kc * 4 + q;
                const int cl = wv * 16 + fr;
                float v = v4[q];
                if (b1) v += b1[bn + cl];
                ldsf[rl * 68 + cl] = v;
            }
        }
        __syncthreads();
        const int kb = bn >> 2;
#pragma unroll
        for (int e = 0; e < 4; ++e) {
            const int idx2 = tid * 4 + e;          // 0..1023
            const int row = idx2 >> 4, kk = idx2 & 15;
            const float4 g4 = *(const float4*)(ldsf + row * 68 + kk * 4);
            const size_t ci = (((size_t)(bm + row)) << 10) + kb + kk;
            const float si = 1.f / (1.f + expf(-g4.x));
            const float sf = 1.f / (1.f + expf(-g4.y));
            const float so = 1.f / (1.f + expf(-g4.w));
            const float cn = sf * C[ci] + si * tanhf(g4.z);
            const float hn = so * tanhf(cn);
            C[ci] = cn;
            const unsigned short hh = f2h(hn);
            const unsigned short hl = f2h(hn - h2f(hh));
            Chi[ci] = hh; Clo[ci] = hl;
            if (cpyh) { cpyh[ci] = hh; cpyl[ci] = hl; }
        }
        return;
    }

    // mode 0: fp32 C + b1
#pragma unroll
    for (int m = 0; m < 4; ++m) {
        f32x4 v4 = acc[m];
#pragma unroll
        for (int q = 0; q < 4; ++q) {
            const int rl = m * 16 + kc * 4 + q;
            const int cl = wv * 16 + fr;
            const int r = bm + rl, col = bn + cl;
            float v = v4[q];
            if (b1) v += b1[col];
            C[(size_t)r * ldc + col] = v;
        }
    }
}

// ---------------------------------------------------------------------------
__global__ __launch_bounds__(256) void split_pack(
    const float* __restrict__ src, int ldsrc, int c0, long total, int C,
    unsigned short* __restrict__ hi, unsigned short* __restrict__ lo)
{
    long i = ((long)blockIdx.x * 256 + threadIdx.x) * 4;
    if (i >= total) return;
    int r = (int)(i / C), c = (int)(i % C);
    float4 v = *(const float4*)(src + (size_t)r * ldsrc + c0 + c);
#pragma unroll
    for (int j = 0; j < 4; ++j) {
        float x = (&v.x)[j];
        unsigned short h = f2h(x);
        hi[i + j] = h;
        lo[i + j] = f2h(x - h2f(h));
    }
}

// gate-permuted split: dst row j (0..4095) <- src row (j&3)*1024 + (j>>2)
__global__ __launch_bounds__(256) void split_pack_perm(
    const float* __restrict__ src, int ldsrc, int c0, long total, int C,
    unsigned short* __restrict__ hi, unsigned short* __restrict__ lo)
{
    long i = ((long)blockIdx.x * 256 + threadIdx.x) * 4;
    if (i >= total) return;
    int r = (int)(i / C), c = (int)(i % C);
    int sr = (r & 3) * 1024 + (r >> 2);
    float4 v = *(const float4*)(src + (size_t)sr * ldsrc + c0 + c);
#pragma unroll
    for (int j = 0; j < 4; ++j) {
        float x = (&v.x)[j];
        unsigned short h = f2h(x);
        hi[i + j] = h;
        lo[i + j] = f2h(x - h2f(h));
    }
}

// dst[j] = a[old(j)] + b[old(j)], old(j) = (j&3)*1024 + (j>>2)
__global__ __launch_bounds__(256) void bias_perm(
    const float* __restrict__ a, const float* __restrict__ b, float* __restrict__ dst)
{
    const int j = blockIdx.x * 256 + threadIdx.x;
    if (j >= 4096) return;
    const int o = (j & 3) * 1024 + (j >> 2);
    dst[j] = a[o] + b[o];
}

__global__ __launch_bounds__(256) void scatter_ini_split(
    const float* __restrict__ I, unsigned short* __restrict__ hchi,
    unsigned short* __restrict__ hclo, float* __restrict__ cc)
{
    const int idx = blockIdx.x * blockDim.x + threadIdx.x;
    if (idx >= 131072) return;
    const int k = idx & 1023, b = (idx >> 10) & 63, l = idx >> 16;
    const float* row = I + (size_t)b * 4096;
    float hv = row[(l << 10) + k];
    unsigned short h = f2h(hv);
    hchi[idx] = h; hclo[idx] = f2h(hv - h2f(h));
    cc[idx] = row[2048 + (l << 10) + k];
}

__global__ __launch_bounds__(256) void scatter_di_split(
    const float* __restrict__ D,
    unsigned short* __restrict__ h0h, unsigned short* __restrict__ h0l,
    unsigned short* __restrict__ h1h, unsigned short* __restrict__ h1l,
    float* __restrict__ cd0, float* __restrict__ cd1)
{
    const int idx = blockIdx.x * blockDim.x + threadIdx.x;
    if (idx >= 1048576) return;
    const int k = idx & 1023, r = idx >> 10;
    const float* row = D + ((size_t)r << 12);
    float v0 = row[k], v1 = row[1024 + k];
    unsigned short a = f2h(v0); h0h[idx] = a; h0l[idx] = f2h(v0 - h2f(a));
    unsigned short b = f2h(v1); h1h[idx] = b; h1l[idx] = f2h(v1 - h2f(b));
    cd0[idx] = row[2048 + k];
    cd1[idx] = row[3072 + k];
}

__global__ __launch_bounds__(256) void build_prev_b(
    const int* __restrict__ tp, unsigned short* __restrict__ ph, unsigned short* __restrict__ pl)
{
    const int idx = blockIdx.x * blockDim.x + threadIdx.x;
    if (idx >= 2097152) return;
    const int n = idx & 127;
    const int r = (idx >> 7) & 1023;
    const int s = idx >> 17;
    const int nb = r >> 6, bb = r & 63;
    const int t = nb * 16 + s;
    float v = 0.f;
    if (t > 0) v = (float)tp[(size_t)bb * 32768 + (size_t)(t - 1) * 128 + n];
    ph[idx] = f2h(v);
    pl[idx] = 0;
}

// ===========================================================================
// Fallback fp32 path (proven baseline)
#define BM 64
#define BN 64
#define BK 16

__global__ __launch_bounds__(256) void gemm_f32(
    int M, int N,
    const float* __restrict__ A1, int K1, int lda1,
    const float* __restrict__ W1, int ldw1,
    const float* __restrict__ A2, int K2, int lda2,
    const float* __restrict__ W2, int ldw2,
    const float* __restrict__ Add, int ldadd,
    const float* __restrict__ bias1, const float* __restrict__ bias2,
    float* __restrict__ C, int ldc, int scatter_s)
{
    __shared__ float As[BK][BM];
    __shared__ float Ws[BK][BN];
    const int bm = blockIdx.x * BM;
    const int bn = blockIdx.y * BN;
    const int tid = threadIdx.x;
    const int ty = tid >> 4;
    const int tx = tid & 15;
    const int lr = tid >> 2;
    const int lc = (tid & 3) << 2;

    float acc[4][4] = {{0.f,0.f,0.f,0.f},{0.f,0.f,0.f,0.f},{0.f,0.f,0.f,0.f},{0.f,0.f,0.f,0.f}};

    for (int phase = 0; phase < 2; ++phase) {
        const float* Ap = phase ? A2 : A1;
        const float* Wp = phase ? W2 : W1;
        const int K   = phase ? K2 : K1;
        const int lda = phase ? lda2 : lda1;
        const int ldw = phase ? ldw2 : ldw1;
        if (Ap == nullptr || K <= 0) continue;
        for (int k0 = 0; k0 < K; k0 += BK) {
            float4 av = *(const float4*)(Ap + (size_t)(bm + lr) * lda + k0 + lc);
            float4 wv = *(const float4*)(Wp + (size_t)(bn + lr) * ldw + k0 + lc);
            __syncthreads();
            As[lc+0][lr] = av.x; As[lc+1][lr] = av.y; As[lc+2][lr] = av.z; As[lc+3][lr] = av.w;
            Ws[lc+0][lr] = wv.x; Ws[lc+1][lr] = wv.y; Ws[lc+2][lr] = wv.z; Ws[lc+3][lr] = wv.w;
            __syncthreads();
            #pragma unroll
            for (int k = 0; k < BK; ++k) {
                float4 a = *(const float4*)&As[k][ty << 2];
                float4 w = *(const float4*)&Ws[k][tx << 2];
                acc[0][0] = fmaf(a.x, w.x, acc[0][0]);
                acc[0][1] = fmaf(a.x, w.y, acc[0][1]);
                acc[0][2] = fmaf(a.x, w.z, acc[0][2]);
                acc[0][3] = fmaf(a.x, w.w, acc[0][3]);
                acc[1][0] = fmaf(a.y, w.x, acc[1][0]);
                acc[1][1] = fmaf(a.y, w.y, acc[1][1]);
                acc[1][2] = fmaf(a.y, w.z, acc[1][2]);
                acc[1][3] = fmaf(a.y, w.w, acc[1][3]);
                acc[2][0] = fmaf(a.z, w.x, acc[2][0]);
                acc[2][1] = fmaf(a.z, w.y, acc[2][1]);
                acc[2][2] = fmaf(a.z, w.z, acc[2][2]);
                acc[2][3] = fmaf(a.z, w.w, acc[2][3]);
                acc[3][0] = fmaf(a.w, w.x, acc[3][0]);
                acc[3][1] = fmaf(a.w, w.y, acc[3][1]);
                acc[3][2] = fmaf(a.w, w.z, acc[3][2]);
                acc[3][3] = fmaf(a.w, w.w, acc[3][3]);
            }
        }
    }

    #pragma unroll
    for (int i = 0; i < 4; ++i) {
        const int row = bm + (ty << 2) + i;
        #pragma unroll
        for (int j = 0; j < 4; ++j) {
            const int col = bn + (tx << 2) + j;
            float v = acc[i][j];
            if (bias1) v += bias1[col];
            if (bias2) v += bias2[col];
            if (Add)   v += Add[(size_t)row * ldadd + col];
            if (scatter_s >= 0) {
                const int bb = row & 63, nb = row >> 6;
                C[(size_t)(((bb * 16 + nb) * 16 + scatter_s)) * 384 + col] = v;
            } else {
                C[(size_t)row * ldc + col] = v;
            }
        }
    }
}

__global__ __launch_bounds__(256) void lstm_cell(
    const float* __restrict__ g, float* __restrict__ c,
    float* __restrict__ h, float* __restrict__ hcopy, int M)
{
    const int idx = blockIdx.x * blockDim.x + threadIdx.x;
    if (idx >= (M << 10)) return;
    const int r = idx >> 10, k = idx & 1023;
    const float* gr = g + ((size_t)r << 12);
    const float gi = gr[k], gf = gr[k + 1024], gg = gr[k + 2048], go = gr[k + 3072];
    const float si = 1.f / (1.f + expf(-gi));
    const float sf = 1.f / (1.f + expf(-gf));
    const float so = 1.f / (1.f + expf(-go));
    const float cn = sf * c[idx] + si * tanhf(gg);
    const float hn = so * tanhf(cn);
    c[idx] = cn;
    h[idx] = hn;
    if (hcopy) hcopy[idx] = hn;
}

__global__ __launch_bounds__(256) void scatter_ini(
    const float* __restrict__ I, float* __restrict__ hc, float* __restrict__ cc)
{
    const int idx = blockIdx.x * blockDim.x + threadIdx.x;
    if (idx >= 131072) return;
    const int k = idx & 1023, b = (idx >> 10) & 63, l = idx >> 16;
    const float* row = I + (size_t)b * 4096;
    hc[idx] = row[(l << 10) + k];
    cc[idx] = row[2048 + (l << 10) + k];
}

__global__ __launch_bounds__(256) void scatter_di(
    const float* __restrict__ D, float* __restrict__ hd0, float* __restrict__ cd0,
    float* __restrict__ hd1, float* __restrict__ cd1)
{
    const int idx = blockIdx.x * blockDim.x + threadIdx.x;
    if (idx >= 1048576) return;
    const int k = idx & 1023, r = idx >> 10;
    const float* row = D + ((size_t)r << 12);
    hd0[idx] = row[k];
    hd1[idx] = row[1024 + k];
    cd0[idx] = row[2048 + k];
    cd1[idx] = row[3072 + k];
}

__global__ __launch_bounds__(256) void build_prev(
    const int* __restrict__ tp, float* __restrict__ prevf)
{
    const int idx = blockIdx.x * blockDim.x + threadIdx.x;
    if (idx >= 2097152) return;
    const int n = idx & 127;
    const int r = (idx >> 7) & 1023;
    const int s = idx >> 17;
    const int nb = r >> 6, bb = r & 63;
    const int t = nb * 16 + s;
    float v = 0.f;
    if (t > 0) v = (float)tp[(size_t)bb * 32768 + (size_t)(t - 1) * 128 + n];
    prevf[idx] = v;
}

// ===========================================================================
extern "C" void kernel_launch(void* const* d_in, const int* in_sizes, int n_in,
                              void* d_out, int out_size, void* d_ws, size_t ws_size,
                              hipStream_t stream)
{
    (void)in_sizes; (void)n_in; (void)out_size;
    const float* z      = (const float*)d_in[0];
    const int*   tp     = (const int*)  d_in[1];
    const float* w_zc   = (const float*)d_in[2];
    const float* b_zc   = (const float*)d_in[3];
    const float* c_whh0 = (const float*)d_in[5];
    const float* c_bih0 = (const float*)d_in[6];
    const float* c_bhh0 = (const float*)d_in[7];
    const float* c_wih1 = (const float*)d_in[8];
    const float* c_whh1 = (const float*)d_in[9];
    const float* c_bih1 = (const float*)d_in[10];
    const float* c_bhh1 = (const float*)d_in[11];
    const float* np_w   = (const float*)d_in[12];
    const float* np_b   = (const float*)d_in[13];
    const float* cd_w   = (const float*)d_in[14];
    const float* cd_b   = (const float*)d_in[15];
    const float* d_wih0 = (const float*)d_in[16];
    const float* d_whh0 = (const float*)d_in[17];
    const float* d_bih0 = (const float*)d_in[18];
    const float* d_bhh0 = (const float*)d_in[19];
    const float* d_wih1 = (const float*)d_in[20];
    const float* d_whh1 = (const float*)d_in[21];
    const float* d_bih1 = (const float*)d_in[22];
    const float* d_bhh1 = (const float*)d_in[23];
    const float* op_w   = (const float*)d_in[24];
    const float* op_b   = (const float*)d_in[25];
    float* out = (float*)d_out;

    // ---- workspace layout for MFMA path (bytes) ----
    size_t o = 0;
    auto alloc = [&](size_t bytes) { size_t r = o; o = (o + bytes + 255) & ~(size_t)255; return r; };
    const size_t oCW0 = alloc((size_t)4096*1024*4);
    const size_t oCW1 = alloc((size_t)4096*1024*4);
    const size_t oCW2 = alloc((size_t)4096*1024*4);
    const size_t oWZC = alloc((size_t)4096*512*4);     // later reused: D0E + OPW
    const size_t oNPW = alloc((size_t)128*128*4);
    const size_t oZS  = alloc((size_t)64*512*4);
    const size_t oCDW = alloc((size_t)4096*1024*4);
    const size_t oD0R = alloc((size_t)4096*1024*4);
    const size_t oCG  = alloc((size_t)64*4096*4);
    const size_t oCC  = alloc((size_t)2*64*1024*4);
    const size_t oHCa = alloc((size_t)2*64*1024*4);    // h ping (hi[2][64][1024], lo)
    const size_t oHCb = alloc((size_t)2*64*1024*4);    // h pong
    const size_t oCND = alloc((size_t)1024*1024*4);
    const size_t oEMB = alloc((size_t)16*1024*128*4);
    const size_t oBRP = alloc((size_t)1024*4096*4);
    const size_t oDG  = alloc((size_t)1024*4096*4);    // PRV aliases this
    const size_t oHD0a= alloc((size_t)1024*1024*4);
    const size_t oHD0b= alloc((size_t)1024*1024*4);
    const size_t oHD1a= alloc((size_t)1024*1024*4);
    const size_t oHD1b= alloc((size_t)1024*1024*4);
    const size_t oCD0 = alloc((size_t)1024*1024*4);
    const size_t oCD1 = alloc((size_t)1024*1024*4);
    const size_t oBS  = alloc((size_t)4*4096*4);
    const size_t need = o;
    const size_t oH1S = alloc((size_t)16*1024*1024*4);
    const size_t need_batched = o;

    if (ws_size >= need) {
        const bool batched = (ws_size >= need_batched);
        char* ws = (char*)d_ws;
        unsigned short* CW0 = (unsigned short*)(ws + oCW0);
        unsigned short* CW1 = (unsigned short*)(ws + oCW1);
        unsigned short* CW2 = (unsigned short*)(ws + oCW2);
        unsigned short* WZC = (unsigned short*)(ws + oWZC);
        unsigned short* NPW = (unsigned short*)(ws + oNPW);
        unsigned short* ZS  = (unsigned short*)(ws + oZS);
        unsigned short* CDW = (unsigned short*)(ws + oCDW);
        unsigned short* D0R = (unsigned short*)(ws + oD0R);
        float* CG  = (float*)(ws + oCG);
        float* CC  = (float*)(ws + oCC);
        unsigned short* HCa = (unsigned short*)(ws + oHCa);
        unsigned short* HCb = (unsigned short*)(ws + oHCb);
        unsigned short* CND = (unsigned short*)(ws + oCND);
        unsigned short* PRV = (unsigned short*)(ws + oDG);   // alias: dead before DG live
        unsigned short* EMB = (unsigned short*)(ws + oEMB);
        float* BRP = (float*)(ws + oBRP);
        float* DG  = (float*)(ws + oDG);
        unsigned short* HD0a = (unsigned short*)(ws + oHD0a);
        unsigned short* HD0b = (unsigned short*)(ws + oHD0b);
        unsigned short* HD1a = (unsigned short*)(ws + oHD1a);
        unsigned short* HD1b = (unsigned short*)(ws + oHD1b);
        float* CD0 = (float*)(ws + oCD0);
        float* CD1 = (float*)(ws + oCD1);
        float* BSC0 = (float*)(ws + oBS);
        float* BSC1 = BSC0 + 4096;
        float* BSB0 = BSC1 + 4096;
        float* BSD1 = BSB0 + 4096;
        unsigned short* H1S  = (unsigned short*)(ws + oH1S);
        unsigned short* H1Sl = H1S + (size_t)16*1048576;
        unsigned short* DWHH0 = CW0;      // aliases, filled after conductor
        unsigned short* DWIH1 = CW1;
        unsigned short* DWHH1 = CW2;
        unsigned short* D0E   = WZC;
        unsigned short* OPW   = WZC + (size_t)2*4096*128;

        auto split = [&](const float* src, int ldsrc, int c0, long R, long C, unsigned short* dst) {
            long total = R * C;
            split_pack<<<(unsigned)((total/4 + 255) / 256), 256, 0, stream>>>(
                src, ldsrc, c0, total, (int)C, dst, dst + total);
        };
        auto splitP = [&](const float* src, int ldsrc, int c0, long C, unsigned short* dst) {
            long total = 4096 * C;
            split_pack_perm<<<(unsigned)((total/4 + 255) / 256), 256, 0, stream>>>(
                src, ldsrc, c0, total, (int)C, dst, dst + total);
        };
        auto gemm2 = [&](int M, int N,
                         const unsigned short* A1h, const unsigned short* A1l, int K1, int lda1,
                         const unsigned short* W1, int ldw1,
                         const unsigned short* A2h, const unsigned short* A2l, int K2, int lda2,
                         const unsigned short* W2, int ldw2,
                         const float* Addp, int ldadd, const float* bb1, const float* bb2,
                         float* Cp, int ldc, unsigned short* Chi, unsigned short* Clo,
                         unsigned short* cpyh, unsigned short* cpyl,
                         int mode, int ss) {
            dim3 grid(M / 64, N / 128);
            gemm_mfma<<<grid, 256, 0, stream>>>(M, N, A1h, A1l, K1, lda1, W1, ldw1,
                                                A2h, A2l, K2, lda2, W2, ldw2,
                                                Addp, ldadd, bb1, bb2, Cp, ldc, Chi, Clo,
                                                cpyh, cpyl, mode, ss);
        };
        auto gemmN64 = [&](int M, int N,
                           const unsigned short* A1h, const unsigned short* A1l, int K1, int lda1,
                           const unsigned short* W1, int ldw1,
                           const unsigned short* A2h, const unsigned short* A2l, int K2, int lda2,
                           const unsigned short* W2, int ldw2,
                           const float* bb1, float* Cp, int ldc,
                           unsigned short* Chi, unsigned short* Clo,
                           unsigned short* cpyh, unsigned short* cpyl, int mode) {
            dim3 grid(M / 64, N / 64);
            gemm_mfma_n64<<<grid, 256, 0, stream>>>(M, N, A1h, A1l, K1, lda1, W1, ldw1,
                                                    A2h, A2l, K2, lda2, W2, ldw2,
                                                    bb1, Cp, ldc, Chi, Clo, cpyh, cpyl, mode);
        };

        // h-state pointer helpers (hi at base, lo at +count)
        auto hc0h = [&](int b){ return (b ? HCb : HCa); };
        auto hc0l = [&](int b){ return (b ? HCb : HCa) + 131072; };
        auto hc1h = [&](int b){ return (b ? HCb : HCa) + 65536; };
        auto hc1l = [&](int b){ return (b ? HCb : HCa) + 131072 + 65536; };
        auto hd0h = [&](int b){ return (b ? HD0b : HD0a); };
        auto hd0l = [&](int b){ return (b ? HD0b : HD0a) + 1048576; };
        auto hd1h = [&](int b){ return (b ? HD1b : HD1a); };
        auto hd1l = [&](int b){ return (b ? HD1b : HD1a) + 1048576; };

        // 0) conversions (conductor weights gate-permuted) + permuted bias sums
        split(z, 512, 0, 64, 512, ZS);
        split(w_zc, 512, 0, 4096, 512, WZC);
        splitP(c_whh0, 1024, 0, 1024, CW0);
        splitP(c_wih1, 1024, 0, 1024, CW1);
        splitP(c_whh1, 1024, 0, 1024, CW2);
        split(np_w, 128, 0, 128, 128, NPW);
        split(cd_w, 1024, 0, 4096, 1024, CDW);
        splitP(d_wih0, 1152, 128, 1024, D0R);
        bias_perm<<<16, 256, 0, stream>>>(c_bih0, c_bhh0, BSC0);
        bias_perm<<<16, 256, 0, stream>>>(c_bih1, c_bhh1, BSC1);
        bias_perm<<<16, 256, 0, stream>>>(d_bih0, d_bhh0, BSB0);
        bias_perm<<<16, 256, 0, stream>>>(d_bih1, d_bhh1, BSD1);
        build_prev_b<<<8192, 256, 0, stream>>>(tp, PRV, PRV + 2097152);

        // 1) ini = z @ w_zc.T + b_zc -> CG -> split-scatter into HCa (ping 0)
        gemmN64(64, 4096, ZS, ZS + 32768, 512, 512, WZC, 512,
                nullptr, nullptr, 0, 0, nullptr, 0,
                b_zc, CG, 4096, nullptr, nullptr, nullptr, nullptr, 0);
        scatter_ini_split<<<512, 256, 0, stream>>>(CG, HCa, HCa + 131072, CC);

        // 2) emb = prev @ np_w.T + np_b (split out); PRV aliases DG
        gemm2(16384, 128, PRV, PRV + 2097152, 128, 128, NPW, 128,
              nullptr, nullptr, 0, 0, nullptr, 0,
              nullptr, 0, np_b, nullptr, nullptr, 128, EMB, EMB + 2097152, nullptr, nullptr, 1, -1);

        // 3) conductor: fused-cell N64 GEMMs, h ping-pong
        for (int t = 0; t < 16; ++t) {
            const int p = t & 1;
            gemmN64(64, 4096, hc0h(p), hc0l(p), 1024, 1024, CW0, 1024,
                    nullptr, nullptr, 0, 0, nullptr, 0,
                    BSC0, CC, 0, hc0h(p ^ 1), hc0l(p ^ 1), nullptr, nullptr, 4);
            gemmN64(64, 4096, hc0h(p ^ 1), hc0l(p ^ 1), 1024, 1024, CW1, 1024,
                    hc1h(p), hc1l(p), 1024, 1024, CW2, 1024,
                    BSC1, CC + 65536, 0, hc1h(p ^ 1), hc1l(p ^ 1),
                    CND + t * 65536, CND + 1048576 + t * 65536, 4);
        }

        // 4) decoder weights (aliases, stream-ordered after conductor)
        splitP(d_whh0, 1024, 0, 1024, DWHH0);
        splitP(d_wih1, 1024, 0, 1024, DWIH1);
        splitP(d_whh1, 1024, 0, 1024, DWHH1);
        splitP(d_wih0, 1152, 0, 128, D0E);
        split(op_w, 1024, 0, 384, 1024, OPW);

        // 5) di = cond @ cd_w.T + cd_b -> DG -> split scatter into ping 0
        gemm2(1024, 4096, CND, CND + 1048576, 1024, 1024, CDW, 1024,
              nullptr, nullptr, 0, 0, nullptr, 0,
              nullptr, 0, cd_b, nullptr, DG, 4096, nullptr, nullptr, nullptr, nullptr, 0, -1);
        scatter_di_split<<<4096, 256, 0, stream>>>(DG, HD0a, HD0a + 1048576,
                                                   HD1a, HD1a + 1048576, CD0, CD1);

        // 6) barpart = cond @ d_wih0[:,128:].T + (bih0+bhh0), permuted cols
        gemm2(1024, 4096, CND, CND + 1048576, 1024, 1024, D0R, 1024,
              nullptr, nullptr, 0, 0, nullptr, 0,
              nullptr, 0, BSB0, nullptr, BRP, 4096, nullptr, nullptr, nullptr, nullptr, 0, -1);

        // 7) decoder: fused-cell GEMMs, h ping-pong
        for (int s = 0; s < 16; ++s) {
            const int p = s & 1;
            gemm2(1024, 4096, EMB + (size_t)s * 131072, EMB + 2097152 + (size_t)s * 131072, 128, 128,
                  D0E, 128,
                  hd0h(p), hd0l(p), 1024, 1024, DWHH0, 1024,
                  BRP, 4096, nullptr, nullptr, CD0, 0, hd0h(p ^ 1), hd0l(p ^ 1),
                  nullptr, nullptr, 4, -1);
            gemm2(1024, 4096, hd0h(p ^ 1), hd0l(p ^ 1), 1024, 1024, DWIH1, 1024,
                  hd1h(p), hd1l(p), 1024, 1024, DWHH1, 1024,
                  nullptr, 0, BSD1, nullptr, CD1, 0, hd1h(p ^ 1), hd1l(p ^ 1),
                  batched ? H1S + (size_t)s * 1048576 : nullptr,
                  batched ? H1Sl + (size_t)s * 1048576 : nullptr, 4, -1);
            if (!batched) {
                gemm2(1024, 384, hd1h(p ^ 1), hd1l(p ^ 1), 1024, 1024, OPW, 1024,
                      nullptr, nullptr, 0, 0, nullptr, 0,
                      nullptr, 0, op_b, nullptr, out, 384, nullptr, nullptr, nullptr, nullptr, 2, s);
            }
        }
        if (batched) {
            gemm2(16384, 384, H1S, H1Sl, 1024, 1024, OPW, 1024,
                  nullptr, nullptr, 0, 0, nullptr, 0,
                  nullptr, 0, op_b, nullptr, out, 384, nullptr, nullptr, nullptr, nullptr, 3, -1);
        }
        return;
    }

    // ================= fallback: proven fp32 path =================
    float* wsf     = (float*)d_ws;
    float* hc      = wsf;
    float* cc      = hc + 131072;
    float* cond    = cc + 131072;
    float* cg      = cond + 1048576;
    float* barpart = cg + 262144;
    float* emb     = barpart + 4194304;
    float* prevf   = emb + 2097152;
    float* hd0     = prevf + 2097152;
    float* cd0     = hd0 + 1048576;
    float* hd1     = cd0 + 1048576;
    float* cd1     = hd1 + 1048576;
    float* dg      = cd1 + 1048576;

    auto gemmf = [&](int M, int N,
                     const float* A1, int K1, int lda1, const float* W1, int ldw1,
                     const float* A2, int K2, int lda2, const float* W2, int ldw2,
                     const float* Addp, int ldadd, const float* bb1, const float* bb2,
                     float* Cp, int ldc, int ss) {
        dim3 grid(M / BM, N / BN);
        gemm_f32<<<grid, dim3(256), 0, stream>>>(M, N, A1, K1, lda1, W1, ldw1,
                                                 A2, K2, lda2, W2, ldw2,
                                                 Addp, ldadd, bb1, bb2, Cp, ldc, ss);
    };

    gemmf(64, 4096, z, 512, 512, w_zc, 512, nullptr, 0, 0, nullptr, 0,
          nullptr, 0, b_zc, nullptr, cg, 4096, -1);
    scatter_ini<<<512, 256, 0, stream>>>(cg, hc, cc);

    build_prev<<<8192, 256, 0, stream>>>(tp, prevf);
    gemmf(16384, 128, prevf, 128, 128, np_w, 128, nullptr, 0, 0, nullptr, 0,
          nullptr, 0, np_b, nullptr, emb, 128, -1);

    for (int t = 0; t < 16; ++t) {
        gemmf(64, 4096, hc, 1024, 1024, c_whh0, 1024, nullptr, 0, 0, nullptr, 0,
              nullptr, 0, c_bih0, c_bhh0, cg, 4096, -1);
        lstm_cell<<<256, 256, 0, stream>>>(cg, cc, hc, nullptr, 64);
        gemmf(64, 4096, hc, 1024, 1024, c_wih1, 1024,
              hc + 65536, 1024, 1024, c_whh1, 1024,
              nullptr, 0, c_bih1, c_bhh1, cg, 4096, -1);
        lstm_cell<<<256, 256, 0, stream>>>(cg, cc + 65536, hc + 65536, cond + t * 65536, 64);
    }

    gemmf(1024, 4096, cond, 1024, 1024, cd_w, 1024, nullptr, 0, 0, nullptr, 0,
          nullptr, 0, cd_b, nullptr, dg, 4096, -1);
    scatter_di<<<4096, 256, 0, stream>>>(dg, hd0, cd0, hd1, cd1);

    gemmf(1024, 4096, cond, 1024, 1024, d_wih0 + 128, 1152, nullptr, 0, 0, nullptr, 0,
          nullptr, 0, d_bih0, d_bhh0, barpart, 4096, -1);

    for (int s = 0; s < 16; ++s) {
        gemmf(1024, 4096, emb + (size_t)s * 131072, 128, 128, d_wih0, 1152,
              hd0, 1024, 1024, d_whh0, 1024,
              barpart, 4096, nullptr, nullptr, dg, 4096, -1);
        lstm_cell<<<4096, 256, 0, stream>>>(dg, cd0, hd0, nullptr, 1024);
        gemmf(1024, 4096, hd0, 1024, 1024, d_wih1, 1024,
              hd1, 1024, 1024, d_whh1, 1024,
              nullptr, 0, d_bih1, d_bhh1, dg, 4096, -1);
        lstm_cell<<<4096, 256, 0, stream>>>(dg, cd1, hd1, nullptr, 1024);
        gemmf(1024, 384, hd1, 1024, 1024, op_w, 1024, nullptr, 0, 0, nullptr, 0,
              nullptr, 0, op_b, nullptr, out, 384, s);
    }
}

// Round 20
// 2423.239 us; speedup vs baseline: 1.4265x; 1.0055x over previous
//
#include <hip/hip_runtime.h>
#include <math.h>

// B=64, LAT=512, HC=HD=1024, NB=16, S=16, E=128, NOTES=128, OUT=384, L=2
// Round 20: BK=64 per barrier in decoder gemm_mfma (two K-32 sub-tiles per
// iteration, 2x32KB double buffer) -- halves barrier-synchronized iteration
// count. fp16 2-term split (A ~= Ah+Al, W ~= Wh). Per-output MFMA order
// unchanged -> bit-identical.

typedef __attribute__((ext_vector_type(8))) short s16x8;
typedef __attribute__((ext_vector_type(8))) _Float16 f16x8;
typedef __attribute__((ext_vector_type(4))) float f32x4;

__device__ inline unsigned short f2h(float f) {
    _Float16 h = (_Float16)f;
    return __builtin_bit_cast(unsigned short, h);
}
__device__ inline float h2f(unsigned short u) {
    _Float16 h = __builtin_bit_cast(_Float16, u);
    return (float)h;
}

// async global->LDS, 16B per lane; LDS dest = wave-uniform base + lane*16
__device__ __forceinline__ void gload16(const unsigned short* g, char* l) {
    const unsigned int* gu = (const unsigned int*)g;
    unsigned int* lu = (unsigned int*)l;
    __builtin_amdgcn_global_load_lds(
        (const __attribute__((address_space(1))) unsigned int*)gu,
        (__attribute__((address_space(3))) unsigned int*)lu, 16, 0, 0);
}

// ---------------------------------------------------------------------------
// 64x128 tile, BK=64 (2 x K-32 sub-tiles) per barrier, 256 thr = 4 waves in
// 2x2. Double buffer 2x32KB. Sub-tile layout: A 64x128B (hi|lo fp16) at 0,
// B 128x64B (hi) at 8192. Swizzles as before.
// mode: 0 = fp32 C; 1 = split store Chi/Clo; 2 = per-step decoder scatter;
//       3 = batched-proj scatter; 4 = fused LSTM cell (gate-interleaved cols).
__global__ __launch_bounds__(256) void gemm_mfma(
    int M, int N,
    const unsigned short* __restrict__ A1h, const unsigned short* __restrict__ A1l, int K1, int lda1,
    const unsigned short* __restrict__ W1h, int ldw1,
    const unsigned short* __restrict__ A2h, const unsigned short* __restrict__ A2l, int K2, int lda2,
    const unsigned short* __restrict__ W2h, int ldw2,
    const float* __restrict__ Add, int ldadd,
    const float* __restrict__ b1, const float* __restrict__ b2,
    float* __restrict__ C, int ldc,
    unsigned short* __restrict__ Chi, unsigned short* __restrict__ Clo,
    unsigned short* __restrict__ cpyh, unsigned short* __restrict__ cpyl,
    int mode, int scatter_s)
{
    __shared__ __align__(16) char ldsb[65536];   // 2 buffers x 32768 B

    const int tid = threadIdx.x;
    const int lane = tid & 63;
    const int wv = tid >> 6;
    const int wm = wv >> 1;          // wave row-half 0/1 (rows wm*32..+32)
    const int wn = wv & 1;           // wave col-half 0/1 (cols wn*64..+64)

    // XCD-aware bijective swizzle (all grids used here have nwg % 8 == 0)
    const int gx = gridDim.x;
    const int l = blockIdx.y * gx + blockIdx.x;
    const int nwg = gx * gridDim.y;
    const int l2 = (l & 7) * (nwg >> 3) + (l >> 3);
    const int bm = (l2 % gx) * 64;
    const int bn = (l2 / gx) * 128;

    // A staging (hi|lo 128B rows, slot swizzle (row&7)): per-lane constants
    const int j = (lane & 7) ^ (lane >> 3);
    const bool isLo = j >= 4;
    const int koff = (j & 3) * 8;
    const int rsub = lane >> 3;
    const int aR0 = bm + wv * 8 + rsub;
    // B staging (hi-only 64B rows, slot swizzle (row>>1)&3): per-lane constants
    const int brs = lane >> 2;                       // row within 16-row window
    const int j2 = (lane & 3) ^ ((lane >> 3) & 3);   // logical k-chunk
    const int koffB = j2 * 8;

    f32x4 acc[2][4];
#pragma unroll
    for (int m = 0; m < 2; ++m)
#pragma unroll
        for (int n = 0; n < 4; ++n) acc[m][n] = (f32x4)0.0f;

    const int fr = lane & 15;
    const int kc = lane >> 4;

    const int NT = (K1 + K2) >> 6;   // K-64 iterations (all K sums % 64 == 0)

    // kt = global K-32 tile index
#define STAGE(dstp, kt) {                                                       \
        const int k0_ = (kt) << 5;                                              \
        const bool ph2_ = (k0_ >= K1);                                          \
        const unsigned short* Ab_ = ph2_ ? (isLo ? A2l : A2h)                   \
                                         : (isLo ? A1l : A1h);                  \
        const unsigned short* Wb_ = ph2_ ? W2h : W1h;                           \
        const int lda_ = ph2_ ? lda2 : lda1;                                    \
        const int ldw_ = ph2_ ? ldw2 : ldw1;                                    \
        const int kb_ = ph2_ ? (k0_ - K1) : k0_;                                \
        char* dst_ = (dstp);                                                    \
        gload16(Ab_ + (size_t)aR0 * lda_ + kb_ + koff,        dst_ + (wv    ) * 1024); \
        gload16(Ab_ + (size_t)(aR0 + 32) * lda_ + kb_ + koff, dst_ + (wv + 4) * 1024); \
        gload16(Wb_ + (size_t)(bn + wv * 16 + brs) * ldw_ + kb_ + koffB,        \
                dst_ + 8192 + wv * 1024);                                       \
        gload16(Wb_ + (size_t)(bn + 64 + wv * 16 + brs) * ldw_ + kb_ + koffB,   \
                dst_ + 8192 + 4096 + wv * 1024);                                \
    }

    // compute one K-32 sub-tile from sub-buffer base sb
#define COMPUTE32(sb) {                                                         \
        char* sbp = (sb);                                                       \
        f16x8 ah[2], al[2], bh[4];                                              \
        _Pragma("unroll")                                                       \
        for (int m = 0; m < 2; ++m) {                                           \
            const int row = wm * 32 + m * 16 + fr;                              \
            const int sw = (row & 7) << 4;                                      \
            char* base = sbp + row * 128;                                       \
            ah[m] = *(const f16x8*)(base + ((kc * 16) ^ sw));                   \
            al[m] = *(const f16x8*)(base + (((kc + 4) * 16) ^ sw));             \
        }                                                                       \
        _Pragma("unroll")                                                       \
        for (int n = 0; n < 4; ++n) {                                           \
            const int brow = wn * 64 + n * 16 + fr;                             \
            bh[n] = *(const f16x8*)(sbp + 8192 + brow * 64 +                    \
                                    ((kc ^ ((brow >> 1) & 3)) << 4));           \
        }                                                                       \
        __builtin_amdgcn_s_setprio(1);                                          \
        _Pragma("unroll")                                                       \
        for (int m = 0; m < 2; ++m)                                             \
            _Pragma("unroll")                                                   \
            for (int n = 0; n < 4; ++n) {                                       \
                acc[m][n] = __builtin_amdgcn_mfma_f32_16x16x32_f16(ah[m], bh[n], acc[m][n], 0, 0, 0); \
                acc[m][n] = __builtin_amdgcn_mfma_f32_16x16x32_f16(al[m], bh[n], acc[m][n], 0, 0, 0); \
            }                                                                   \
        __builtin_amdgcn_s_setprio(0);                                          \
    }

    char* bcur  = ldsb;
    char* bnext = ldsb + 32768;

    STAGE(bcur, 0);
    STAGE(bcur + 16384, 1);
    asm volatile("s_waitcnt vmcnt(0)" ::: "memory");
    __builtin_amdgcn_s_barrier();

    for (int t = 0; t < NT; ++t) {
        const bool more = (t + 1 < NT);
        if (more) {
            STAGE(bnext, 2 * (t + 1));
            STAGE(bnext + 16384, 2 * (t + 1) + 1);
        }
        COMPUTE32(bcur);
        COMPUTE32(bcur + 16384);
        asm volatile("s_waitcnt vmcnt(0)" ::: "memory");
        __builtin_amdgcn_s_barrier();
        char* tmp = bcur; bcur = bnext; bnext = tmp;
    }
#undef STAGE
#undef COMPUTE32

    if (mode == 4) {
        float* ldsf = (float*)ldsb;
#pragma unroll
        for (int m = 0; m < 2; ++m)
#pragma unroll
            for (int n = 0; n < 4; ++n) {
                f32x4 v4 = acc[m][n];
#pragma unroll
                for (int q = 0; q < 4; ++q) {
                    const int rl = wm * 32 + m * 16 + kc * 4 + q;
                    const int cl = wn * 64 + n * 16 + fr;
                    const int col = bn + cl;
                    float v = v4[q];
                    if (b1) v += b1[col];
                    if (Add) v += Add[(size_t)(bm + rl) * ldadd + col];
                    ldsf[rl * 132 + cl] = v;
                }
            }
        __syncthreads();
        const int kb = bn >> 2;
#pragma unroll
        for (int e = 0; e < 8; ++e) {
            const int idx2 = tid * 8 + e;
            const int row = idx2 >> 5, kk = idx2 & 31;
            const float4 g4 = *(const float4*)(ldsf + row * 132 + kk * 4);
            const size_t ci = (((size_t)(bm + row)) << 10) + kb + kk;
            const float si = 1.f / (1.f + expf(-g4.x));
            const float sf = 1.f / (1.f + expf(-g4.y));
            const float so = 1.f / (1.f + expf(-g4.w));
            const float cn = sf * C[ci] + si * tanhf(g4.z);
            const float hn = so * tanhf(cn);
            C[ci] = cn;
            const unsigned short hh = f2h(hn);
            const unsigned short hl = f2h(hn - h2f(hh));
            Chi[ci] = hh; Clo[ci] = hl;
            if (cpyh) { cpyh[ci] = hh; cpyl[ci] = hl; }
        }
        return;
    }

#pragma unroll
    for (int m = 0; m < 2; ++m)
#pragma unroll
        for (int n = 0; n < 4; ++n) {
            f32x4 v4 = acc[m][n];
#pragma unroll
            for (int q = 0; q < 4; ++q) {
                const int rl = wm * 32 + m * 16 + kc * 4 + q;
                const int cl = wn * 64 + n * 16 + fr;
                const int r = bm + rl, col = bn + cl;
                float v = v4[q];
                if (b1) v += b1[col];
                if (b2) v += b2[col];
                if (Add) v += Add[(size_t)r * ldadd + col];
                if (mode == 0) {
                    C[(size_t)r * ldc + col] = v;
                } else if (mode == 1) {
                    unsigned short h = f2h(v);
                    Chi[(size_t)r * ldc + col] = h;
                    Clo[(size_t)r * ldc + col] = f2h(v - h2f(h));
                } else if (mode == 2) {
                    const int bb = r & 63, nb = r >> 6;
                    C[(size_t)(((bb * 16 + nb) * 16 + scatter_s)) * 384 + col] = v;
                } else {
                    const int bb = r & 63, nb = (r >> 6) & 15, s = r >> 10;
                    C[(size_t)(((bb * 16 + nb) * 16 + s)) * 384 + col] = v;
                }
            }
        }
}

// ---------------------------------------------------------------------------
// BN=64 variant for M=64 GEMMs (ini + conductor). Buffer 12KB: A 8KB, B 4KB.
// 3 loads/wave, vmcnt(3), 3-buffer pipeline (unchanged from round 18/19).
__global__ __launch_bounds__(256) void gemm_mfma_n64(
    int M, int N,
    const unsigned short* __restrict__ A1h, const unsigned short* __restrict__ A1l, int K1, int lda1,
    const unsigned short* __restrict__ W1h, int ldw1,
    const unsigned short* __restrict__ A2h, const unsigned short* __restrict__ A2l, int K2, int lda2,
    const unsigned short* __restrict__ W2h, int ldw2,
    const float* __restrict__ b1,
    float* __restrict__ C, int ldc,
    unsigned short* __restrict__ Chi, unsigned short* __restrict__ Clo,
    unsigned short* __restrict__ cpyh, unsigned short* __restrict__ cpyl,
    int mode)
{
    __shared__ __align__(16) char ldsb[36864];   // 3 buffers x 12288 B

    const int tid = threadIdx.x;
    const int lane = tid & 63;
    const int wv = tid >> 6;

    const int gx = gridDim.x;
    const int l = blockIdx.y * gx + blockIdx.x;
    const int nwg = gx * gridDim.y;
    const int l2 = (l & 7) * (nwg >> 3) + (l >> 3);
    const int bm = (l2 % gx) * 64;
    const int bn = (l2 / gx) * 64;

    const int j = (lane & 7) ^ (lane >> 3);
    const bool isLo = j >= 4;
    const int koff = (j & 3) * 8;
    const int rsub = lane >> 3;
    const int aR0 = bm + wv * 8 + rsub;
    const int brs = lane >> 2;
    const int j2 = (lane & 3) ^ ((lane >> 3) & 3);
    const int koffB = j2 * 8;

    f32x4 acc[4];
#pragma unroll
    for (int m = 0; m < 4; ++m) acc[m] = (f32x4)0.0f;

    const int fr = lane & 15;
    const int kc = lane >> 4;

    const int NT = (K1 + K2) >> 5;

#define STAGE64(dstp, t) {                                                      \
        const int k0_ = (t) << 5;                                               \
        const bool ph2_ = (k0_ >= K1);                                          \
        const unsigned short* Ab_ = ph2_ ? (isLo ? A2l : A2h)                   \
                                         : (isLo ? A1l : A1h);                  \
        const unsigned short* Wb_ = ph2_ ? W2h : W1h;                           \
        const int lda_ = ph2_ ? lda2 : lda1;                                    \
        const int ldw_ = ph2_ ? ldw2 : ldw1;                                    \
        const int kb_ = ph2_ ? (k0_ - K1) : k0_;                                \
        char* dst_ = (dstp);                                                    \
        gload16(Ab_ + (size_t)aR0 * lda_ + kb_ + koff,        dst_ + (wv    ) * 1024); \
        gload16(Ab_ + (size_t)(aR0 + 32) * lda_ + kb_ + koff, dst_ + (wv + 4) * 1024); \
        gload16(Wb_ + (size_t)(bn + wv * 16 + brs) * ldw_ + kb_ + koffB,        \
                dst_ + 8192 + wv * 1024);                                       \
    }

    char* bcur  = ldsb;
    char* bnext = ldsb + 12288;
    char* bfar  = ldsb + 24576;

    STAGE64(bcur, 0);
    STAGE64(bnext, 1);
    asm volatile("s_waitcnt vmcnt(3)" ::: "memory");
    __builtin_amdgcn_s_barrier();

    for (int t = 0; t < NT; ++t) {
        const bool more = (t + 2 < NT);
        if (more) STAGE64(bfar, t + 2);
        {
            f16x8 ah[4], al[4], bh;
#pragma unroll
            for (int m = 0; m < 4; ++m) {
                const int row = m * 16 + fr;
                const int sw = (row & 7) << 4;
                char* base = bcur + row * 128;
                ah[m] = *(const f16x8*)(base + ((kc * 16) ^ sw));
                al[m] = *(const f16x8*)(base + (((kc + 4) * 16) ^ sw));
            }
            {
                const int brow = wv * 16 + fr;
                bh = *(const f16x8*)(bcur + 8192 + brow * 64 +
                                     ((kc ^ ((brow >> 1) & 3)) << 4));
            }
            __builtin_amdgcn_s_setprio(1);
#pragma unroll
            for (int m = 0; m < 4; ++m) {
                acc[m] = __builtin_amdgcn_mfma_f32_16x16x32_f16(ah[m], bh, acc[m], 0, 0, 0);
                acc[m] = __builtin_amdgcn_mfma_f32_16x16x32_f16(al[m], bh, acc[m], 0, 0, 0);
            }
            __builtin_amdgcn_s_setprio(0);
        }
        if (more) { asm volatile("s_waitcnt vmcnt(3)" ::: "memory"); }
        else      { asm volatile("s_waitcnt vmcnt(0)" ::: "memory"); }
        __builtin_amdgcn_s_barrier();
        char* tmp = bcur; bcur = bnext; bnext = bfar; bfar = tmp;
    }
#undef STAGE64

    if (mode == 4) {
        float* ldsf = (float*)ldsb;
#pragma unroll
        for (int m = 0; m < 4; ++m) {
            f32x4 v4 = acc[m];
#pragma unroll
            for (int q = 0; q < 4; ++q) {
                const int rl = m * 16 + kc * 4 + q;
                const int cl = wv * 16 + fr;
                float v = v4[q];
                if (b1) v += b1[bn + cl];
                ldsf[rl * 68 + cl] = v;
            }
        }
        __syncthreads();
        const int kb = bn >> 2;
#pragma unroll
        for (int e = 0; e < 4; ++e) {
            const int idx2 = tid * 4 + e;          // 0..1023
            const int row = idx2 >> 4, kk = idx2 & 15;
            const float4 g4 = *(const float4*)(ldsf + row * 68 + kk * 4);
            const size_t ci = (((size_t)(bm + row)) << 10) + kb + kk;
            const float si = 1.f / (1.f + expf(-g4.x));
            const float sf = 1.f / (1.f + expf(-g4.y));
            const float so = 1.f / (1.f + expf(-g4.w));
            const float cn = sf * C[ci] + si * tanhf(g4.z);
            const float hn = so * tanhf(cn);
            C[ci] = cn;
            const unsigned short hh = f2h(hn);
            const unsigned short hl = f2h(hn - h2f(hh));
            Chi[ci] = hh; Clo[ci] = hl;
            if (cpyh) { cpyh[ci] = hh; cpyl[ci] = hl; }
        }
        return;
    }

    // mode 0: fp32 C + b1
#pragma unroll
    for (int m = 0; m < 4; ++m) {
        f32x4 v4 = acc[m];
#pragma unroll
        for (int q = 0; q < 4; ++q) {
            const int rl = m * 16 + kc * 4 + q;
            const int cl = wv * 16 + fr;
            const int r = bm + rl, col = bn + cl;
            float v = v4[q];
            if (b1) v += b1[col];
            C[(size_t)r * ldc + col] = v;
        }
    }
}

// ---------------------------------------------------------------------------
__global__ __launch_bounds__(256) void split_pack(
    const float* __restrict__ src, int ldsrc, int c0, long total, int C,
    unsigned short* __restrict__ hi, unsigned short* __restrict__ lo)
{
    long i = ((long)blockIdx.x * 256 + threadIdx.x) * 4;
    if (i >= total) return;
    int r = (int)(i / C), c = (int)(i % C);
    float4 v = *(const float4*)(src + (size_t)r * ldsrc + c0 + c);
#pragma unroll
    for (int j = 0; j < 4; ++j) {
        float x = (&v.x)[j];
        unsigned short h = f2h(x);
        hi[i + j] = h;
        lo[i + j] = f2h(x - h2f(h));
    }
}

// gate-permuted split: dst row j (0..4095) <- src row (j&3)*1024 + (j>>2)
__global__ __launch_bounds__(256) void split_pack_perm(
    const float* __restrict__ src, int ldsrc, int c0, long total, int C,
    unsigned short* __restrict__ hi, unsigned short* __restrict__ lo)
{
    long i = ((long)blockIdx.x * 256 + threadIdx.x) * 4;
    if (i >= total) return;
    int r = (int)(i / C), c = (int)(i % C);
    int sr = (r & 3) * 1024 + (r >> 2);
    float4 v = *(const float4*)(src + (size_t)sr * ldsrc + c0 + c);
#pragma unroll
    for (int j = 0; j < 4; ++j) {
        float x = (&v.x)[j];
        unsigned short h = f2h(x);
        hi[i + j] = h;
        lo[i + j] = f2h(x - h2f(h));
    }
}

// dst[j] = a[old(j)] + b[old(j)], old(j) = (j&3)*1024 + (j>>2)
__global__ __launch_bounds__(256) void bias_perm(
    const float* __restrict__ a, const float* __restrict__ b, float* __restrict__ dst)
{
    const int j = blockIdx.x * 256 + threadIdx.x;
    if (j >= 4096) return;
    const int o = (j & 3) * 1024 + (j >> 2);
    dst[j] = a[o] + b[o];
}

__global__ __launch_bounds__(256) void scatter_ini_split(
    const float* __restrict__ I, unsigned short* __restrict__ hchi,
    unsigned short* __restrict__ hclo, float* __restrict__ cc)
{
    const int idx = blockIdx.x * blockDim.x + threadIdx.x;
    if (idx >= 131072) return;
    const int k = idx & 1023, b = (idx >> 10) & 63, l = idx >> 16;
    const float* row = I + (size_t)b * 4096;
    float hv = row[(l << 10) + k];
    unsigned short h = f2h(hv);
    hchi[idx] = h; hclo[idx] = f2h(hv - h2f(h));
    cc[idx] = row[2048 + (l << 10) + k];
}

__global__ __launch_bounds__(256) void scatter_di_split(
    const float* __restrict__ D,
    unsigned short* __restrict__ h0h, unsigned short* __restrict__ h0l,
    unsigned short* __restrict__ h1h, unsigned short* __restrict__ h1l,
    float* __restrict__ cd0, float* __restrict__ cd1)
{
    const int idx = blockIdx.x * blockDim.x + threadIdx.x;
    if (idx >= 1048576) return;
    const int k = idx & 1023, r = idx >> 10;
    const float* row = D + ((size_t)r << 12);
    float v0 = row[k], v1 = row[1024 + k];
    unsigned short a = f2h(v0); h0h[idx] = a; h0l[idx] = f2h(v0 - h2f(a));
    unsigned short b = f2h(v1); h1h[idx] = b; h1l[idx] = f2h(v1 - h2f(b));
    cd0[idx] = row[2048 + k];
    cd1[idx] = row[3072 + k];
}

__global__ __launch_bounds__(256) void build_prev_b(
    const int* __restrict__ tp, unsigned short* __restrict__ ph, unsigned short* __restrict__ pl)
{
    const int idx = blockIdx.x * blockDim.x + threadIdx.x;
    if (idx >= 2097152) return;
    const int n = idx & 127;
    const int r = (idx >> 7) & 1023;
    const int s = idx >> 17;
    const int nb = r >> 6, bb = r & 63;
    const int t = nb * 16 + s;
    float v = 0.f;
    if (t > 0) v = (float)tp[(size_t)bb * 32768 + (size_t)(t - 1) * 128 + n];
    ph[idx] = f2h(v);
    pl[idx] = 0;
}

// ===========================================================================
// Fallback fp32 path (proven baseline)
#define BM 64
#define BN 64
#define BK 16

__global__ __launch_bounds__(256) void gemm_f32(
    int M, int N,
    const float* __restrict__ A1, int K1, int lda1,
    const float* __restrict__ W1, int ldw1,
    const float* __restrict__ A2, int K2, int lda2,
    const float* __restrict__ W2, int ldw2,
    const float* __restrict__ Add, int ldadd,
    const float* __restrict__ bias1, const float* __restrict__ bias2,
    float* __restrict__ C, int ldc, int scatter_s)
{
    __shared__ float As[BK][BM];
    __shared__ float Ws[BK][BN];
    const int bm = blockIdx.x * BM;
    const int bn = blockIdx.y * BN;
    const int tid = threadIdx.x;
    const int ty = tid >> 4;
    const int tx = tid & 15;
    const int lr = tid >> 2;
    const int lc = (tid & 3) << 2;

    float acc[4][4] = {{0.f,0.f,0.f,0.f},{0.f,0.f,0.f,0.f},{0.f,0.f,0.f,0.f},{0.f,0.f,0.f,0.f}};

    for (int phase = 0; phase < 2; ++phase) {
        const float* Ap = phase ? A2 : A1;
        const float* Wp = phase ? W2 : W1;
        const int K   = phase ? K2 : K1;
        const int lda = phase ? lda2 : lda1;
        const int ldw = phase ? ldw2 : ldw1;
        if (Ap == nullptr || K <= 0) continue;
        for (int k0 = 0; k0 < K; k0 += BK) {
            float4 av = *(const float4*)(Ap + (size_t)(bm + lr) * lda + k0 + lc);
            float4 wv = *(const float4*)(Wp + (size_t)(bn + lr) * ldw + k0 + lc);
            __syncthreads();
            As[lc+0][lr] = av.x; As[lc+1][lr] = av.y; As[lc+2][lr] = av.z; As[lc+3][lr] = av.w;
            Ws[lc+0][lr] = wv.x; Ws[lc+1][lr] = wv.y; Ws[lc+2][lr] = wv.z; Ws[lc+3][lr] = wv.w;
            __syncthreads();
            #pragma unroll
            for (int k = 0; k < BK; ++k) {
                float4 a = *(const float4*)&As[k][ty << 2];
                float4 w = *(const float4*)&Ws[k][tx << 2];
                acc[0][0] = fmaf(a.x, w.x, acc[0][0]);
                acc[0][1] = fmaf(a.x, w.y, acc[0][1]);
                acc[0][2] = fmaf(a.x, w.z, acc[0][2]);
                acc[0][3] = fmaf(a.x, w.w, acc[0][3]);
                acc[1][0] = fmaf(a.y, w.x, acc[1][0]);
                acc[1][1] = fmaf(a.y, w.y, acc[1][1]);
                acc[1][2] = fmaf(a.y, w.z, acc[1][2]);
                acc[1][3] = fmaf(a.y, w.w, acc[1][3]);
                acc[2][0] = fmaf(a.z, w.x, acc[2][0]);
                acc[2][1] = fmaf(a.z, w.y, acc[2][1]);
                acc[2][2] = fmaf(a.z, w.z, acc[2][2]);
                acc[2][3] = fmaf(a.z, w.w, acc[2][3]);
                acc[3][0] = fmaf(a.w, w.x, acc[3][0]);
                acc[3][1] = fmaf(a.w, w.y, acc[3][1]);
                acc[3][2] = fmaf(a.w, w.z, acc[3][2]);
                acc[3][3] = fmaf(a.w, w.w, acc[3][3]);
            }
        }
    }

    #pragma unroll
    for (int i = 0; i < 4; ++i) {
        const int row = bm + (ty << 2) + i;
        #pragma unroll
        for (int j = 0; j < 4; ++j) {
            const int col = bn + (tx << 2) + j;
            float v = acc[i][j];
            if (bias1) v += bias1[col];
            if (bias2) v += bias2[col];
            if (Add)   v += Add[(size_t)row * ldadd + col];
            if (scatter_s >= 0) {
                const int bb = row & 63, nb = row >> 6;
                C[(size_t)(((bb * 16 + nb) * 16 + scatter_s)) * 384 + col] = v;
            } else {
                C[(size_t)row * ldc + col] = v;
            }
        }
    }
}

__global__ __launch_bounds__(256) void lstm_cell(
    const float* __restrict__ g, float* __restrict__ c,
    float* __restrict__ h, float* __restrict__ hcopy, int M)
{
    const int idx = blockIdx.x * blockDim.x + threadIdx.x;
    if (idx >= (M << 10)) return;
    const int r = idx >> 10, k = idx & 1023;
    const float* gr = g + ((size_t)r << 12);
    const float gi = gr[k], gf = gr[k + 1024], gg = gr[k + 2048], go = gr[k + 3072];
    const float si = 1.f / (1.f + expf(-gi));
    const float sf = 1.f / (1.f + expf(-gf));
    const float so = 1.f / (1.f + expf(-go));
    const float cn = sf * c[idx] + si * tanhf(gg);
    const float hn = so * tanhf(cn);
    c[idx] = cn;
    h[idx] = hn;
    if (hcopy) hcopy[idx] = hn;
}

__global__ __launch_bounds__(256) void scatter_ini(
    const float* __restrict__ I, float* __restrict__ hc, float* __restrict__ cc)
{
    const int idx = blockIdx.x * blockDim.x + threadIdx.x;
    if (idx >= 131072) return;
    const int k = idx & 1023, b = (idx >> 10) & 63, l = idx >> 16;
    const float* row = I + (size_t)b * 4096;
    hc[idx] = row[(l << 10) + k];
    cc[idx] = row[2048 + (l << 10) + k];
}

__global__ __launch_bounds__(256) void scatter_di(
    const float* __restrict__ D, float* __restrict__ hd0, float* __restrict__ cd0,
    float* __restrict__ hd1, float* __restrict__ cd1)
{
    const int idx = blockIdx.x * blockDim.x + threadIdx.x;
    if (idx >= 1048576) return;
    const int k = idx & 1023, r = idx >> 10;
    const float* row = D + ((size_t)r << 12);
    hd0[idx] = row[k];
    hd1[idx] = row[1024 + k];
    cd0[idx] = row[2048 + k];
    cd1[idx] = row[3072 + k];
}

__global__ __launch_bounds__(256) void build_prev(
    const int* __restrict__ tp, float* __restrict__ prevf)
{
    const int idx = blockIdx.x * blockDim.x + threadIdx.x;
    if (idx >= 2097152) return;
    const int n = idx & 127;
    const int r = (idx >> 7) & 1023;
    const int s = idx >> 17;
    const int nb = r >> 6, bb = r & 63;
    const int t = nb * 16 + s;
    float v = 0.f;
    if (t > 0) v = (float)tp[(size_t)bb * 32768 + (size_t)(t - 1) * 128 + n];
    prevf[idx] = v;
}

// ===========================================================================
extern "C" void kernel_launch(void* const* d_in, const int* in_sizes, int n_in,
                              void* d_out, int out_size, void* d_ws, size_t ws_size,
                              hipStream_t stream)
{
    (void)in_sizes; (void)n_in; (void)out_size;
    const float* z      = (const float*)d_in[0];
    const int*   tp     = (const int*)  d_in[1];
    const float* w_zc   = (const float*)d_in[2];
    const float* b_zc   = (const float*)d_in[3];
    const float* c_whh0 = (const float*)d_in[5];
    const float* c_bih0 = (const float*)d_in[6];
    const float* c_bhh0 = (const float*)d_in[7];
    const float* c_wih1 = (const float*)d_in[8];
    const float* c_whh1 = (const float*)d_in[9];
    const float* c_bih1 = (const float*)d_in[10];
    const float* c_bhh1 = (const float*)d_in[11];
    const float* np_w   = (const float*)d_in[12];
    const float* np_b   = (const float*)d_in[13];
    const float* cd_w   = (const float*)d_in[14];
    const float* cd_b   = (const float*)d_in[15];
    const float* d_wih0 = (const float*)d_in[16];
    const float* d_whh0 = (const float*)d_in[17];
    const float* d_bih0 = (const float*)d_in[18];
    const float* d_bhh0 = (const float*)d_in[19];
    const float* d_wih1 = (const float*)d_in[20];
    const float* d_whh1 = (const float*)d_in[21];
    const float* d_bih1 = (const float*)d_in[22];
    const float* d_bhh1 = (const float*)d_in[23];
    const float* op_w   = (const float*)d_in[24];
    const float* op_b   = (const float*)d_in[25];
    float* out = (float*)d_out;

    // ---- workspace layout for MFMA path (bytes) ----
    size_t o = 0;
    auto alloc = [&](size_t bytes) { size_t r = o; o = (o + bytes + 255) & ~(size_t)255; return r; };
    const size_t oCW0 = alloc((size_t)4096*1024*4);
    const size_t oCW1 = alloc((size_t)4096*1024*4);
    const size_t oCW2 = alloc((size_t)4096*1024*4);
    const size_t oWZC = alloc((size_t)4096*512*4);     // later reused: D0E + OPW
    const size_t oNPW = alloc((size_t)128*128*4);
    const size_t oZS  = alloc((size_t)64*512*4);
    const size_t oCDW = alloc((size_t)4096*1024*4);
    const size_t oD0R = alloc((size_t)4096*1024*4);
    const size_t oCG  = alloc((size_t)64*4096*4);
    const size_t oCC  = alloc((size_t)2*64*1024*4);
    const size_t oHCa = alloc((size_t)2*64*1024*4);    // h ping (hi[2][64][1024], lo)
    const size_t oHCb = alloc((size_t)2*64*1024*4);    // h pong
    const size_t oCND = alloc((size_t)1024*1024*4);
    const size_t oEMB = alloc((size_t)16*1024*128*4);
    const size_t oBRP = alloc((size_t)1024*4096*4);
    const size_t oDG  = alloc((size_t)1024*4096*4);    // PRV aliases this
    const size_t oHD0a= alloc((size_t)1024*1024*4);
    const size_t oHD0b= alloc((size_t)1024*1024*4);
    const size_t oHD1a= alloc((size_t)1024*1024*4);
    const size_t oHD1b= alloc((size_t)1024*1024*4);
    const size_t oCD0 = alloc((size_t)1024*1024*4);
    const size_t oCD1 = alloc((size_t)1024*1024*4);
    const size_t oBS  = alloc((size_t)4*4096*4);
    const size_t need = o;
    const size_t oH1S = alloc((size_t)16*1024*1024*4);
    const size_t need_batched = o;

    if (ws_size >= need) {
        const bool batched = (ws_size >= need_batched);
        char* ws = (char*)d_ws;
        unsigned short* CW0 = (unsigned short*)(ws + oCW0);
        unsigned short* CW1 = (unsigned short*)(ws + oCW1);
        unsigned short* CW2 = (unsigned short*)(ws + oCW2);
        unsigned short* WZC = (unsigned short*)(ws + oWZC);
        unsigned short* NPW = (unsigned short*)(ws + oNPW);
        unsigned short* ZS  = (unsigned short*)(ws + oZS);
        unsigned short* CDW = (unsigned short*)(ws + oCDW);
        unsigned short* D0R = (unsigned short*)(ws + oD0R);
        float* CG  = (float*)(ws + oCG);
        float* CC  = (float*)(ws + oCC);
        unsigned short* HCa = (unsigned short*)(ws + oHCa);
        unsigned short* HCb = (unsigned short*)(ws + oHCb);
        unsigned short* CND = (unsigned short*)(ws + oCND);
        unsigned short* PRV = (unsigned short*)(ws + oDG);   // alias: dead before DG live
        unsigned short* EMB = (unsigned short*)(ws + oEMB);
        float* BRP = (float*)(ws + oBRP);
        float* DG  = (float*)(ws + oDG);
        unsigned short* HD0a = (unsigned short*)(ws + oHD0a);
        unsigned short* HD0b = (unsigned short*)(ws + oHD0b);
        unsigned short* HD1a = (unsigned short*)(ws + oHD1a);
        unsigned short* HD1b = (unsigned short*)(ws + oHD1b);
        float* CD0 = (float*)(ws + oCD0);
        float* CD1 = (float*)(ws + oCD1);
        float* BSC0 = (float*)(ws + oBS);
        float* BSC1 = BSC0 + 4096;
        float* BSB0 = BSC1 + 4096;
        float* BSD1 = BSB0 + 4096;
        unsigned short* H1S  = (unsigned short*)(ws + oH1S);
        unsigned short* H1Sl = H1S + (size_t)16*1048576;
        unsigned short* DWHH0 = CW0;      // aliases, filled after conductor
        unsigned short* DWIH1 = CW1;
        unsigned short* DWHH1 = CW2;
        unsigned short* D0E   = WZC;
        unsigned short* OPW   = WZC + (size_t)2*4096*128;

        auto split = [&](const float* src, int ldsrc, int c0, long R, long C, unsigned short* dst) {
            long total = R * C;
            split_pack<<<(unsigned)((total/4 + 255) / 256), 256, 0, stream>>>(
                src, ldsrc, c0, total, (int)C, dst, dst + total);
        };
        auto splitP = [&](const float* src, int ldsrc, int c0, long C, unsigned short* dst) {
            long total = 4096 * C;
            split_pack_perm<<<(unsigned)((total/4 + 255) / 256), 256, 0, stream>>>(
                src, ldsrc, c0, total, (int)C, dst, dst + total);
        };
        auto gemm2 = [&](int M, int N,
                         const unsigned short* A1h, const unsigned short* A1l, int K1, int lda1,
                         const unsigned short* W1, int ldw1,
                         const unsigned short* A2h, const unsigned short* A2l, int K2, int lda2,
                         const unsigned short* W2, int ldw2,
                         const float* Addp, int ldadd, const float* bb1, const float* bb2,
                         float* Cp, int ldc, unsigned short* Chi, unsigned short* Clo,
                         unsigned short* cpyh, unsigned short* cpyl,
                         int mode, int ss) {
            dim3 grid(M / 64, N / 128);
            gemm_mfma<<<grid, 256, 0, stream>>>(M, N, A1h, A1l, K1, lda1, W1, ldw1,
                                                A2h, A2l, K2, lda2, W2, ldw2,
                                                Addp, ldadd, bb1, bb2, Cp, ldc, Chi, Clo,
                                                cpyh, cpyl, mode, ss);
        };
        auto gemmN64 = [&](int M, int N,
                           const unsigned short* A1h, const unsigned short* A1l, int K1, int lda1,
                           const unsigned short* W1, int ldw1,
                           const unsigned short* A2h, const unsigned short* A2l, int K2, int lda2,
                           const unsigned short* W2, int ldw2,
                           const float* bb1, float* Cp, int ldc,
                           unsigned short* Chi, unsigned short* Clo,
                           unsigned short* cpyh, unsigned short* cpyl, int mode) {
            dim3 grid(M / 64, N / 64);
            gemm_mfma_n64<<<grid, 256, 0, stream>>>(M, N, A1h, A1l, K1, lda1, W1, ldw1,
                                                    A2h, A2l, K2, lda2, W2, ldw2,
                                                    bb1, Cp, ldc, Chi, Clo, cpyh, cpyl, mode);
        };

        // h-state pointer helpers (hi at base, lo at +count)
        auto hc0h = [&](int b){ return (b ? HCb : HCa); };
        auto hc0l = [&](int b){ return (b ? HCb : HCa) + 131072; };
        auto hc1h = [&](int b){ return (b ? HCb : HCa) + 65536; };
        auto hc1l = [&](int b){ return (b ? HCb : HCa) + 131072 + 65536; };
        auto hd0h = [&](int b){ return (b ? HD0b : HD0a); };
        auto hd0l = [&](int b){ return (b ? HD0b : HD0a) + 1048576; };
        auto hd1h = [&](int b){ return (b ? HD1b : HD1a); };
        auto hd1l = [&](int b){ return (b ? HD1b : HD1a) + 1048576; };

        // 0) conversions (conductor weights gate-permuted) + permuted bias sums
        split(z, 512, 0, 64, 512, ZS);
        split(w_zc, 512, 0, 4096, 512, WZC);
        splitP(c_whh0, 1024, 0, 1024, CW0);
        splitP(c_wih1, 1024, 0, 1024, CW1);
        splitP(c_whh1, 1024, 0, 1024, CW2);
        split(np_w, 128, 0, 128, 128, NPW);
        split(cd_w, 1024, 0, 4096, 1024, CDW);
        splitP(d_wih0, 1152, 128, 1024, D0R);
        bias_perm<<<16, 256, 0, stream>>>(c_bih0, c_bhh0, BSC0);
        bias_perm<<<16, 256, 0, stream>>>(c_bih1, c_bhh1, BSC1);
        bias_perm<<<16, 256, 0, stream>>>(d_bih0, d_bhh0, BSB0);
        bias_perm<<<16, 256, 0, stream>>>(d_bih1, d_bhh1, BSD1);
        build_prev_b<<<8192, 256, 0, stream>>>(tp, PRV, PRV + 2097152);

        // 1) ini = z @ w_zc.T + b_zc -> CG -> split-scatter into HCa (ping 0)
        gemmN64(64, 4096, ZS, ZS + 32768, 512, 512, WZC, 512,
                nullptr, nullptr, 0, 0, nullptr, 0,
                b_zc, CG, 4096, nullptr, nullptr, nullptr, nullptr, 0);
        scatter_ini_split<<<512, 256, 0, stream>>>(CG, HCa, HCa + 131072, CC);

        // 2) emb = prev @ np_w.T + np_b (split out); PRV aliases DG
        gemm2(16384, 128, PRV, PRV + 2097152, 128, 128, NPW, 128,
              nullptr, nullptr, 0, 0, nullptr, 0,
              nullptr, 0, np_b, nullptr, nullptr, 128, EMB, EMB + 2097152, nullptr, nullptr, 1, -1);

        // 3) conductor: fused-cell N64 GEMMs, h ping-pong
        for (int t = 0; t < 16; ++t) {
            const int p = t & 1;
            gemmN64(64, 4096, hc0h(p), hc0l(p), 1024, 1024, CW0, 1024,
                    nullptr, nullptr, 0, 0, nullptr, 0,
                    BSC0, CC, 0, hc0h(p ^ 1), hc0l(p ^ 1), nullptr, nullptr, 4);
            gemmN64(64, 4096, hc0h(p ^ 1), hc0l(p ^ 1), 1024, 1024, CW1, 1024,
                    hc1h(p), hc1l(p), 1024, 1024, CW2, 1024,
                    BSC1, CC + 65536, 0, hc1h(p ^ 1), hc1l(p ^ 1),
                    CND + t * 65536, CND + 1048576 + t * 65536, 4);
        }

        // 4) decoder weights (aliases, stream-ordered after conductor)
        splitP(d_whh0, 1024, 0, 1024, DWHH0);
        splitP(d_wih1, 1024, 0, 1024, DWIH1);
        splitP(d_whh1, 1024, 0, 1024, DWHH1);
        splitP(d_wih0, 1152, 0, 128, D0E);
        split(op_w, 1024, 0, 384, 1024, OPW);

        // 5) di = cond @ cd_w.T + cd_b -> DG -> split scatter into ping 0
        gemm2(1024, 4096, CND, CND + 1048576, 1024, 1024, CDW, 1024,
              nullptr, nullptr, 0, 0, nullptr, 0,
              nullptr, 0, cd_b, nullptr, DG, 4096, nullptr, nullptr, nullptr, nullptr, 0, -1);
        scatter_di_split<<<4096, 256, 0, stream>>>(DG, HD0a, HD0a + 1048576,
                                                   HD1a, HD1a + 1048576, CD0, CD1);

        // 6) barpart = cond @ d_wih0[:,128:].T + (bih0+bhh0), permuted cols
        gemm2(1024, 4096, CND, CND + 1048576, 1024, 1024, D0R, 1024,
              nullptr, nullptr, 0, 0, nullptr, 0,
              nullptr, 0, BSB0, nullptr, BRP, 4096, nullptr, nullptr, nullptr, nullptr, 0, -1);

        // 7) decoder: fused-cell GEMMs, h ping-pong
        for (int s = 0; s < 16; ++s) {
            const int p = s & 1;
            gemm2(1024, 4096, EMB + (size_t)s * 131072, EMB + 2097152 + (size_t)s * 131072, 128, 128,
                  D0E, 128,
                  hd0h(p), hd0l(p), 1024, 1024, DWHH0, 1024,
                  BRP, 4096, nullptr, nullptr, CD0, 0, hd0h(p ^ 1), hd0l(p ^ 1),
                  nullptr, nullptr, 4, -1);
            gemm2(1024, 4096, hd0h(p ^ 1), hd0l(p ^ 1), 1024, 1024, DWIH1, 1024,
                  hd1h(p), hd1l(p), 1024, 1024, DWHH1, 1024,
                  nullptr, 0, BSD1, nullptr, CD1, 0, hd1h(p ^ 1), hd1l(p ^ 1),
                  batched ? H1S + (size_t)s * 1048576 : nullptr,
                  batched ? H1Sl + (size_t)s * 1048576 : nullptr, 4, -1);
            if (!batched) {
                gemm2(1024, 384, hd1h(p ^ 1), hd1l(p ^ 1), 1024, 1024, OPW, 1024,
                      nullptr, nullptr, 0, 0, nullptr, 0,
                      nullptr, 0, op_b, nullptr, out, 384, nullptr, nullptr, nullptr, nullptr, 2, s);
            }
        }
        if (batched) {
            gemm2(16384, 384, H1S, H1Sl, 1024, 1024, OPW, 1024,
                  nullptr, nullptr, 0, 0, nullptr, 0,
                  nullptr, 0, op_b, nullptr, out, 384, nullptr, nullptr, nullptr, nullptr, 3, -1);
        }
        return;
    }

    // ================= fallback: proven fp32 path =================
    float* wsf     = (float*)d_ws;
    float* hc      = wsf;
    float* cc      = hc + 131072;
    float* cond    = cc + 131072;
    float* cg      = cond + 1048576;
    float* barpart = cg + 262144;
    float* emb     = barpart + 4194304;
    float* prevf   = emb + 2097152;
    float* hd0     = prevf + 2097152;
    float* cd0     = hd0 + 1048576;
    float* hd1     = cd0 + 1048576;
    float* cd1     = hd1 + 1048576;
    float* dg      = cd1 + 1048576;

    auto gemmf = [&](int M, int N,
                     const float* A1, int K1, int lda1, const float* W1, int ldw1,
                     const float* A2, int K2, int lda2, const float* W2, int ldw2,
                     const float* Addp, int ldadd, const float* bb1, const float* bb2,
                     float* Cp, int ldc, int ss) {
        dim3 grid(M / BM, N / BN);
        gemm_f32<<<grid, dim3(256), 0, stream>>>(M, N, A1, K1, lda1, W1, ldw1,
                                                 A2, K2, lda2, W2, ldw2,
                                                 Addp, ldadd, bb1, bb2, Cp, ldc, ss);
    };

    gemmf(64, 4096, z, 512, 512, w_zc, 512, nullptr, 0, 0, nullptr, 0,
          nullptr, 0, b_zc, nullptr, cg, 4096, -1);
    scatter_ini<<<512, 256, 0, stream>>>(cg, hc, cc);

    build_prev<<<8192, 256, 0, stream>>>(tp, prevf);
    gemmf(16384, 128, prevf, 128, 128, np_w, 128, nullptr, 0, 0, nullptr, 0,
          nullptr, 0, np_b, nullptr, emb, 128, -1);

    for (int t = 0; t < 16; ++t) {
        gemmf(64, 4096, hc, 1024, 1024, c_whh0, 1024, nullptr, 0, 0, nullptr, 0,
              nullptr, 0, c_bih0, c_bhh0, cg, 4096, -1);
        lstm_cell<<<256, 256, 0, stream>>>(cg, cc, hc, nullptr, 64);
        gemmf(64, 4096, hc, 1024, 1024, c_wih1, 1024,
              hc + 65536, 1024, 1024, c_whh1, 1024,
              nullptr, 0, c_bih1, c_bhh1, cg, 4096, -1);
        lstm_cell<<<256, 256, 0, stream>>>(cg, cc + 65536, hc + 65536, cond + t * 65536, 64);
    }

    gemmf(1024, 4096, cond, 1024, 1024, cd_w, 1024, nullptr, 0, 0, nullptr, 0,
          nullptr, 0, cd_b, nullptr, dg, 4096, -1);
    scatter_di<<<4096, 256, 0, stream>>>(dg, hd0, cd0, hd1, cd1);

    gemmf(1024, 4096, cond, 1024, 1024, d_wih0 + 128, 1152, nullptr, 0, 0, nullptr, 0,
          nullptr, 0, d_bih0, d_bhh0, barpart, 4096, -1);

    for (int s = 0; s < 16; ++s) {
        gemmf(1024, 4096, emb + (size_t)s * 131072, 128, 128, d_wih0, 1152,
              hd0, 1024, 1024, d_whh0, 1024,
              barpart, 4096, nullptr, nullptr, dg, 4096, -1);
        lstm_cell<<<4096, 256, 0, stream>>>(dg, cd0, hd0, nullptr, 1024);
        gemmf(1024, 4096, hd0, 1024, 1024, d_wih1, 1024,
              hd1, 1024, 1024, d_whh1, 1024,
              nullptr, 0, d_bih1, d_bhh1, dg, 4096, -1);
        lstm_cell<<<4096, 256, 0, stream>>>(dg, cd1, hd1, nullptr, 1024);
        gemmf(1024, 384, hd1, 1024, 1024, op_w, 1024, nullptr, 0, 0, nullptr, 0,
              nullptr, 0, op_b, nullptr, out, 384, s);
    }
}